// Round 11
// baseline (720.969 us; speedup 1.0000x reference)
//
#include <hip/hip_runtime.h>
#include <hip/hip_bf16.h>
#include <math.h>

// ---- model constants ----
#define B_SZ    8
#define SEQ     4096
#define DMODEL  256
#define DIN     512     // d_inner
#define DSTATE  64
#define NH      8
#define HD      64
#define CONVDIM 640
#define DPROJ   1160
#define NPAD    1280    // DPROJ padded to 10*128
#define NCHUNK  32      // scan chunks per (b,h)
#define CLEN    128     // SEQ / NCHUNK
#define STR64   68      // LDS row stride (shorts) for K=64 tiles
#define STR128  132     // LDS row stride (shorts) for K=128 tiles

typedef unsigned long long u64;
typedef unsigned int u32;
typedef unsigned short u16;
typedef __attribute__((ext_vector_type(8))) short bf16x8;
typedef __attribute__((ext_vector_type(4))) float f32x4;

__device__ __forceinline__ float siluf(float v){ return v / (1.f + expf(-v)); }
__device__ __forceinline__ u16 f2bf(float f){ __hip_bfloat16 h = __float2bfloat16(f); return *(u16*)&h; }
__device__ __forceinline__ float bf2f(u16 u){ union{u32 i; float f;} t; t.i = ((u32)u)<<16; return t.f; }
__device__ __forceinline__ bf16x8 ldfrag(const u16* base){
  union { u64 u[2]; bf16x8 v; } t;
  const u64* p = (const u64*)base;
  t.u[0] = p[0]; t.u[1] = p[1];
  return t.v;
}

// ---------------- weight conversion (once per launch) ----------------
__global__ __launch_bounds__(256) void cvt_inw(const float* __restrict__ W, u16* __restrict__ Wt)
{
  const int blk = blockIdx.x;
  const int l = blk / NPAD, n = blk % NPAD;
  const int k = threadIdx.x;
  float v = 0.f;
  if (n < DPROJ) v = W[((long)l*DMODEL + k)*DPROJ + n];
  Wt[((long)l*NPAD + n)*DMODEL + k] = f2bf(v);
}

__global__ __launch_bounds__(256) void cvt_outw(const float* __restrict__ W, u16* __restrict__ Wt)
{
  const int blk = blockIdx.x;
  const int l = blk / DMODEL, n = blk % DMODEL;
  #pragma unroll
  for (int q = 0; q < 2; ++q) {
    const int k = threadIdx.x + q*256;
    const float v = W[((long)l*DIN + k)*DMODEL + n];
    Wt[((long)l*DMODEL + n)*DIN + k] = f2bf(v);
  }
}

// ---------------- encoder GEMM; writes h fp32 + hb bf16 ----------------
__global__ __launch_bounds__(256) void enc_kernel(const float* __restrict__ x,
    const float* __restrict__ W, const float* __restrict__ bias,
    float* __restrict__ h, u16* __restrict__ hb)
{
  __shared__ float xl[32*64];
  const int tid = threadIdx.x;
  const long t0 = (long)blockIdx.x * 32;
  for (int i = tid; i < 32*64; i += 256) xl[i] = x[t0*64 + i];
  __syncthreads();
  float acc[32];
  const float bv = bias[tid];
  #pragma unroll
  for (int tok = 0; tok < 32; ++tok) acc[tok] = bv;
  for (int k = 0; k < 64; ++k) {
    const float wv = W[k*DMODEL + tid];
    #pragma unroll
    for (int tok = 0; tok < 32; ++tok) acc[tok] += xl[tok*64 + k] * wv;
  }
  #pragma unroll
  for (int tok = 0; tok < 32; ++tok) {
    h [(t0 + tok)*DMODEL + tid] = acc[tok];
    hb[(t0 + tok)*DMODEL + tid] = f2bf(acc[tok]);
  }
}

// ---------------- in_proj MFMA GEMM 128x128 tile; direct-global fragment loads, no K-loop LDS ----------------
__global__ __launch_bounds__(256) void inproj_mfma(const u16* __restrict__ hb,
    const u16* __restrict__ Wt, u16* __restrict__ zbuf, u16* __restrict__ xbc,
    float* __restrict__ dtb, float* __restrict__ lab,
    const float* __restrict__ dt_bias, const float* __restrict__ A_log)
{
  __shared__ __align__(16) u16 Ep[64*136];   // epilogue bounce only
  const int tid = threadIdx.x;
  const long m0 = (long)blockIdx.x * 128;
  const int n0 = blockIdx.y * 128;
  const int w = tid >> 6, lane = tid & 63;
  const int q = lane >> 4, l16 = lane & 15;
  // MFMA A fragment = 16 contiguous bytes of row (m0+w*32+mi*16+l16) at k offset q*8
  const u16* a0p = hb + (m0 + w*32 + l16)*DMODEL + q*8;
  const u16* a1p = a0p + 16*DMODEL;
  const u16* bp  = Wt + ((long)(n0 + l16))*DMODEL + q*8;
  f32x4 acc[2][8] = {{{0.f,0.f,0.f,0.f}}};
  #pragma unroll
  for (int kk = 0; kk < 8; ++kk) {
    const int ko = kk*32;
    const bf16x8 af0 = *(const bf16x8*)(a0p + ko);
    const bf16x8 af1 = *(const bf16x8*)(a1p + ko);
    bf16x8 bf[8];
    #pragma unroll
    for (int nj=0;nj<8;nj++) bf[nj] = *(const bf16x8*)(bp + (long)nj*16*DMODEL + ko);
    #pragma unroll
    for (int nj=0;nj<8;nj++){
      acc[0][nj] = __builtin_amdgcn_mfma_f32_16x16x32_bf16(af0, bf[nj], acc[0][nj], 0,0,0);
      acc[1][nj] = __builtin_amdgcn_mfma_f32_16x16x32_bf16(af1, bf[nj], acc[1][nj], 0,0,0);
    }
  }
  if (n0 < DIN + CONVDIM) {
    // bounce each 64-row half through LDS, then full-line stores (4 thr/row x 32 shorts = 128)
    #pragma unroll
    for (int mi=0;mi<2;mi++){
      if (mi) __syncthreads();
      #pragma unroll
      for (int nj=0;nj<8;nj++){
        const int col = nj*16 + l16;
        #pragma unroll
        for (int r=0;r<4;r++){
          const int er = w*16 + q*4 + r;
          Ep[er*136 + col] = f2bf(acc[mi][nj][r]);
        }
      }
      __syncthreads();
      {
        const int er2 = tid >> 2, seg = tid & 3;
        const long grow = m0 + (er2>>4)*32 + mi*16 + (er2&15);
        const u64* s = (const u64*)(Ep + er2*136 + seg*32);
        u64 v0=s[0], v1=s[1], v2=s[2], v3=s[3], v4=s[4], v5=s[5], v6=s[6], v7=s[7];
        u64* dptr;
        if (n0 < DIN) dptr = (u64*)(zbuf + grow*DIN + n0 + seg*32);
        else          dptr = (u64*)(xbc + grow*CONVDIM + (n0 - DIN) + seg*32);
        dptr[0]=v0; dptr[1]=v1; dptr[2]=v2; dptr[3]=v3;
        dptr[4]=v4; dptr[5]=v5; dptr[6]=v6; dptr[7]=v7;
      }
    }
  } else {
    // dt tile: only cols 1152..1159 valid
    #pragma unroll
    for (int mi=0;mi<2;mi++){
      #pragma unroll
      for (int nj=0;nj<8;nj++){
        const int col = n0 + nj*16 + l16;
        if (col < DPROJ) {
          const int hh = col - (DIN + CONVDIM);
          #pragma unroll
          for (int r=0;r<4;r++){
            const long row = m0 + w*32 + mi*16 + q*4 + r;
            const float dv = acc[mi][nj][r] + dt_bias[hh];
            const float sp = dv > 20.f ? dv : log1pf(expf(dv));
            dtb[row*NH + hh] = sp;
            lab[row*NH + hh] = sp * (-expf(A_log[hh]));   // log dA
          }
        }
      }
    }
  }
}

// ---------------- out_proj MFMA GEMM 128x128 tile + residual; direct-global fragments ----------------
__global__ __launch_bounds__(256) void outproj_mfma(const u16* __restrict__ gb,
    const u16* __restrict__ Wt, const float* __restrict__ resid, float* __restrict__ outb)
{
  const int tid = threadIdx.x;
  const long m0 = (long)blockIdx.x * 128;
  const int n0 = blockIdx.y * 128;
  const int w = tid >> 6, lane = tid & 63;
  const int q = lane >> 4, l16 = lane & 15;
  const u16* a0p = gb + (m0 + w*32 + l16)*DIN + q*8;
  const u16* a1p = a0p + 16*DIN;
  const u16* bp  = Wt + ((long)(n0 + l16))*DIN + q*8;
  f32x4 acc[2][8] = {{{0.f,0.f,0.f,0.f}}};
  #pragma unroll
  for (int kk = 0; kk < 16; ++kk) {
    const int ko = kk*32;
    const bf16x8 af0 = *(const bf16x8*)(a0p + ko);
    const bf16x8 af1 = *(const bf16x8*)(a1p + ko);
    bf16x8 bf[8];
    #pragma unroll
    for (int nj=0;nj<8;nj++) bf[nj] = *(const bf16x8*)(bp + (long)nj*16*DIN + ko);
    #pragma unroll
    for (int nj=0;nj<8;nj++){
      acc[0][nj] = __builtin_amdgcn_mfma_f32_16x16x32_bf16(af0, bf[nj], acc[0][nj], 0,0,0);
      acc[1][nj] = __builtin_amdgcn_mfma_f32_16x16x32_bf16(af1, bf[nj], acc[1][nj], 0,0,0);
    }
  }
  #pragma unroll
  for (int mi=0;mi<2;mi++){
    #pragma unroll
    for (int nj=0;nj<8;nj++){
      const int col = n0 + nj*16 + l16;
      #pragma unroll
      for (int r=0;r<4;r++){
        const long row = m0 + w*32 + mi*16 + q*4 + r;
        outb[row*DMODEL + col] = acc[mi][nj][r] + resid[row*DMODEL + col];
      }
    }
  }
}

// ---------------- depthwise causal conv + SiLU: strip kernel ----------------
__global__ __launch_bounds__(256) void conv_kernel(const u16* __restrict__ xbc,
    const float* __restrict__ cw, const float* __restrict__ cb,
    u16* __restrict__ xsx, u16* __restrict__ Bb, u16* __restrict__ Cb)
{
  const long idx = (long)blockIdx.x * 256 + threadIdx.x;   // Mb*20 threads
  const int c4 = (int)(idx % 160) * 4;
  const long bt0 = (idx / 160) * 8;          // strip start (strips never cross batch)
  const int tseq = (int)(bt0 & (SEQ-1));
  const float4 b4 = *(const float4*)(cb + c4);
  const float4 w0v = *(const float4*)(cw + (c4+0)*4);
  const float4 w1v = *(const float4*)(cw + (c4+1)*4);
  const float4 w2v = *(const float4*)(cw + (c4+2)*4);
  const float4 w3v = *(const float4*)(cw + (c4+3)*4);
  const float W0[4] = {w0v.x,w0v.y,w0v.z,w0v.w};
  const float W1[4] = {w1v.x,w1v.y,w1v.z,w1v.w};
  const float W2[4] = {w2v.x,w2v.y,w2v.z,w2v.w};
  const float W3[4] = {w3v.x,w3v.y,w3v.z,w3v.w};
  float i0[11], i1[11], i2[11], i3[11];
  #pragma unroll
  for (int k = 0; k < 11; ++k) {
    u64 v = 0;
    if (tseq - 3 + k >= 0) v = *(const u64*)(xbc + (bt0 - 3 + k)*CONVDIM + c4);
    i0[k]=bf2f((u16)v); i1[k]=bf2f((u16)(v>>16)); i2[k]=bf2f((u16)(v>>32)); i3[k]=bf2f((u16)(v>>48));
  }
  u16* dst; long base; int stride;
  if (c4 < DIN)              { dst = xsx; base = bt0*DIN + c4;              stride = DIN; }
  else if (c4 < DIN+DSTATE)  { dst = Bb;  base = bt0*DSTATE + (c4-DIN);     stride = DSTATE; }
  else                       { dst = Cb;  base = bt0*DSTATE + (c4-DIN-DSTATE); stride = DSTATE; }
  #pragma unroll
  for (int j = 0; j < 8; ++j) {
    float a0=b4.x, a1=b4.y, a2=b4.z, a3=b4.w;
    #pragma unroll
    for (int k = 0; k < 4; ++k) {
      a0 += W0[k]*i0[j+k]; a1 += W1[k]*i1[j+k];
      a2 += W2[k]*i2[j+k]; a3 += W3[k]*i3[j+k];
    }
    a0=siluf(a0); a1=siluf(a1); a2=siluf(a2); a3=siluf(a3);
    const u64 r = (u64)f2bf(a0) | ((u64)f2bf(a1)<<16) | ((u64)f2bf(a2)<<32) | ((u64)f2bf(a3)<<48);
    *(u64*)(dst + base + (long)j*stride) = r;
  }
}

// ---------------- SSD phase A: per chunk-head local state via MFMA ----------------
__global__ __launch_bounds__(256) void scanS_kernel(const u16* __restrict__ xsx,
    const u16* __restrict__ Bb, const float* __restrict__ lab, const float* __restrict__ dtb,
    float* __restrict__ Sloc, float* __restrict__ Pb)
{
  __shared__ __align__(16) u16 Btr[64*STR128];   // [n][s]
  __shared__ __align__(16) u16 Uw[64*STR128];    // [p][s]
  __shared__ float cexpL[128];
  const int wg = blockIdx.x;
  const int c = wg & (NCHUNK-1), bh = wg >> 5, hh = bh & (NH-1), b = bh >> 3;
  const int tid = threadIdx.x;
  const long bt0 = (long)b*SEQ + c*CLEN;
  if (tid < 64) {   // wave 0: inclusive prefix of log dA over 128 steps
    float a0 = lab[(bt0+tid)*NH + hh];
    float a1 = lab[(bt0+64+tid)*NH + hh];
    const float d0 = dtb[(bt0+tid)*NH + hh];
    const float d1 = dtb[(bt0+64+tid)*NH + hh];
    #pragma unroll
    for (int o=1;o<64;o<<=1){
      const float t0=__shfl_up(a0,o), t1=__shfl_up(a1,o);
      if (tid>=o){a0+=t0;a1+=t1;}
    }
    a1 += __shfl(a0,63);
    const float ctot = __shfl(a1,63);
    cexpL[tid]    = d0*__expf(ctot - a0);
    cexpL[tid+64] = d1*__expf(ctot - a1);
    if (tid==0) Pb[wg] = __expf(ctot);
  }
  __syncthreads();
  {
    const int v = tid & 63, r0 = tid >> 6;
    #pragma unroll 4
    for (int k=0;k<32;k++){
      const int s = r0 + k*4;
      Btr[v*STR128 + s] = Bb[(bt0+s)*DSTATE + v];
      Uw[v*STR128 + s]  = f2bf(cexpL[s]*bf2f(xsx[(bt0+s)*DIN + hh*HD + v]));
    }
  }
  __syncthreads();
  const int w = tid>>6, lane = tid&63, q = lane>>4, l16 = lane&15;
  f32x4 acc[4] = {};
  #pragma unroll
  for (int ks=0;ks<4;ks++){
    const bf16x8 af = ldfrag(&Uw[(w*16+l16)*STR128 + ks*32 + q*8]);
    #pragma unroll
    for (int nj=0;nj<4;nj++){
      const bf16x8 bf = ldfrag(&Btr[(nj*16+l16)*STR128 + ks*32 + q*8]);
      acc[nj] = __builtin_amdgcn_mfma_f32_16x16x32_bf16(af, bf, acc[nj], 0,0,0);
    }
  }
  const long sb = (long)wg*4096;   // [wg][p][n]
  #pragma unroll
  for (int nj=0;nj<4;nj++)
    #pragma unroll
    for (int r=0;r<4;r++)
      Sloc[sb + (w*16+q*4+r)*64 + nj*16 + l16] = acc[nj][r];
}

// Parallel combine: Sloc[c] := running; run = P[c]*run + tmp
__global__ __launch_bounds__(64) void scanMid_kernel(float* __restrict__ Sloc, const float* __restrict__ Pb)
{
  const int bh = blockIdx.x;
  const int rr = blockIdx.y;
  const int p  = threadIdx.x;
  float run = 0.f;
  for (int c = 0; c < NCHUNK; ++c) {
    const long base = ((long)(bh*NCHUNK + c))*4096 + rr*64 + p;
    const float Pc = Pb[bh*NCHUNK + c];
    const float tmp = Sloc[base];
    Sloc[base] = run;
    run = run*Pc + tmp;
  }
}

// ---------------- SSD phase C: Y = ((C Bt) o L) U + diag(exp(cum)) (C h0) + D*x ; coalesced y out ----------------
__global__ __launch_bounds__(512) void scanY_kernel(const u16* __restrict__ xsx,
    u16* __restrict__ yg, const u16* __restrict__ Bb, const u16* __restrict__ Cb,
    const float* __restrict__ lab, const float* __restrict__ dtb,
    const float* __restrict__ Sinit, const float* __restrict__ Dp)
{
  __shared__ __align__(16) u16 pool[2*128*STR64];  // Bs | Cs; overlaid by Ms[t][s]; then by y-bounce
  __shared__ __align__(16) u16 Ut[64*STR128];      // [p][s]
  __shared__ __align__(16) u16 h0t[64*STR64];      // [p][n]
  __shared__ float cumL[128];
  __shared__ float dtL[128];
  u16* Bs = pool;
  u16* Cs = pool + 128*STR64;
  u16* Ms = pool;

  const int wg = blockIdx.x;
  const int c = wg & (NCHUNK-1), bh = wg >> 5, hh = bh & (NH-1), b = bh >> 3;
  const int tid = threadIdx.x;
  const long bt0 = (long)b*SEQ + c*CLEN;

  if (tid < 64) {
    float a0 = lab[(bt0+tid)*NH + hh];
    float a1 = lab[(bt0+64+tid)*NH + hh];
    dtL[tid]    = dtb[(bt0+tid)*NH + hh];
    dtL[tid+64] = dtb[(bt0+64+tid)*NH + hh];
    #pragma unroll
    for (int o=1;o<64;o<<=1){
      const float t0=__shfl_up(a0,o), t1=__shfl_up(a1,o);
      if (tid>=o){a0+=t0;a1+=t1;}
    }
    a1 += __shfl(a0,63);
    cumL[tid]=a0; cumL[tid+64]=a1;
  }
  __syncthreads();
  {
    const int n = tid & 63, r0 = tid >> 6;   // 512 threads: r0 in 0..7
    #pragma unroll 4
    for (int k=0;k<16;k++){
      const int s = r0 + k*8;
      Bs[s*STR64 + n] = Bb[(bt0+s)*DSTATE + n];
      Cs[s*STR64 + n] = Cb[(bt0+s)*DSTATE + n];
      Ut[n*STR128 + s] = f2bf(dtL[s]*bf2f(xsx[(bt0+s)*DIN + hh*HD + n]));
    }
    const int n0 = r0*8;
    const float* hp = Sinit + (long)wg*4096 + n*64 + n0;
    #pragma unroll
    for (int j=0;j<8;j++) h0t[n*STR64 + n0 + j] = f2bf(hp[j]);
  }
  __syncthreads();

  const int w = tid>>6, lane = tid&63, q = lane>>4, l16 = lane&15;
  f32x4 accG[8] = {};
  f32x4 accI[4] = {};
  #pragma unroll
  for (int ks=0;ks<2;ks++){
    const bf16x8 af = ldfrag(&Cs[(w*16+l16)*STR64 + ks*32 + q*8]);
    #pragma unroll
    for (int nj=0;nj<8;nj++)
      accG[nj] = __builtin_amdgcn_mfma_f32_16x16x32_bf16(af, ldfrag(&Bs[(nj*16+l16)*STR64 + ks*32 + q*8]), accG[nj], 0,0,0);
    #pragma unroll
    for (int nj=0;nj<4;nj++)
      accI[nj] = __builtin_amdgcn_mfma_f32_16x16x32_bf16(af, ldfrag(&h0t[(nj*16+l16)*STR64 + ks*32 + q*8]), accI[nj], 0,0,0);
  }
  __syncthreads();
  #pragma unroll
  for (int nj=0;nj<8;nj++){
    const int s = nj*16 + l16;
    #pragma unroll
    for (int r=0;r<4;r++){
      const int t = w*16 + q*4 + r;
      const float v = (s<=t) ? accG[nj][r]*__expf(cumL[t]-cumL[s]) : 0.f;
      Ms[t*STR128 + s] = f2bf(v);
    }
  }
  __syncthreads();
  f32x4 accY[4] = {};
  #pragma unroll
  for (int ks=0;ks<4;ks++){
    const bf16x8 af = ldfrag(&Ms[(w*16+l16)*STR128 + ks*32 + q*8]);
    #pragma unroll
    for (int nj=0;nj<4;nj++)
      accY[nj] = __builtin_amdgcn_mfma_f32_16x16x32_bf16(af, ldfrag(&Ut[(nj*16+l16)*STR128 + ks*32 + q*8]), accY[nj], 0,0,0);
  }
  const float Dv = Dp[hh];
  __syncthreads();   // Ms reads done; reuse pool as y-bounce [128][68]
  #pragma unroll
  for (int nj=0;nj<4;nj++){
    const int p = nj*16 + l16;
    #pragma unroll
    for (int r=0;r<4;r++){
      const int t = w*16 + q*4 + r;
      const float xv = bf2f(xsx[(bt0+t)*DIN + hh*HD + p]);
      pool[t*STR64 + p] = f2bf(accY[nj][r] + __expf(cumL[t])*accI[nj][r] + Dv*xv);
    }
  }
  __syncthreads();
  {
    const int row = tid >> 2, seg = tid & 3;
    const u64* s = (const u64*)(pool + row*STR64 + seg*16);
    u64 a=s[0], b2=s[1], c2=s[2], d=s[3];
    u64* dptr = (u64*)(yg + (bt0+row)*DIN + hh*HD + seg*16);
    dptr[0]=a; dptr[1]=b2; dptr[2]=c2; dptr[3]=d;
  }
}

// ---------------- y*silu(z) + RMSNorm; bf16 in, bf16 out in place ----------------
__global__ __launch_bounds__(256) void gnorm_kernel(u16* __restrict__ y_io,
    const u16* __restrict__ zb, const float* __restrict__ nw)
{
  const long row = blockIdx.x;
  const int tid = threadIdx.x;
  float g[2];
  #pragma unroll
  for (int q=0;q<2;q++){
    const int cc = tid + q*256;
    const float yv = bf2f(y_io[row*DIN + cc]);
    const float zv = bf2f(zb[row*DIN + cc]);
    g[q] = yv * siluf(zv);
  }
  float ss = g[0]*g[0] + g[1]*g[1];
  #pragma unroll
  for (int o=32;o;o>>=1) ss += __shfl_down(ss, o);
  __shared__ float red[4];
  if ((tid & 63) == 0) red[tid>>6] = ss;
  __syncthreads();
  const float tot = red[0]+red[1]+red[2]+red[3];
  const float scale = rsqrtf(tot * (1.f/512.f) + 1e-5f);
  #pragma unroll
  for (int q=0;q<2;q++){
    const int cc = tid + q*256;
    y_io[row*DIN + cc] = f2bf(g[q] * scale * nw[cc]);
  }
}

// ---------------- LayerNorm; writes h fp32 + hb bf16 ----------------
__global__ __launch_bounds__(256) void ln_kernel(const float* __restrict__ in,
    float* __restrict__ h, u16* __restrict__ hb,
    const float* __restrict__ w, const float* __restrict__ bb)
{
  const int lane = threadIdx.x & 63;
  const int wid  = threadIdx.x >> 6;
  const long row = (long)blockIdx.x * 4 + wid;
  const float* r = in + row*DMODEL;
  float v[4]; float sum = 0.f, sq = 0.f;
  #pragma unroll
  for (int q=0;q<4;q++){ v[q] = r[lane + q*64]; sum += v[q]; sq += v[q]*v[q]; }
  #pragma unroll
  for (int o=32;o;o>>=1){ sum += __shfl_xor(sum,o); sq += __shfl_xor(sq,o); }
  const float mu = sum * (1.f/256.f);
  const float var = sq * (1.f/256.f) - mu*mu;
  const float rs = rsqrtf(var + 1e-5f);
  #pragma unroll
  for (int q=0;q<4;q++){
    const int cc = lane + q*64;
    const float o = (v[q]-mu)*rs*w[cc] + bb[cc];
    h [row*DMODEL + cc] = o;
    hb[row*DMODEL + cc] = f2bf(o);
  }
}

// ---------------- decoder (fp32 output) ----------------
__global__ __launch_bounds__(64) void dec_kernel(const float* __restrict__ h,
    const float* __restrict__ W, const float* __restrict__ bias, float* __restrict__ out)
{
  const int wg = blockIdx.x;
  const int b = wg / 10, o = wg % 10;
  const int lane = threadIdx.x;
  const float* r = h + ((long)b*SEQ + SEQ-1)*DMODEL;
  float s = 0.f;
  #pragma unroll
  for (int q=0;q<4;q++){ const int k = lane + q*64; s += r[k]*W[k*10+o]; }
  #pragma unroll
  for (int o2=32;o2;o2>>=1) s += __shfl_down(s, o2);
  if (lane == 0) out[wg] = s + bias[o];
}

extern "C" void kernel_launch(void* const* d_in, const int* in_sizes, int n_in,
                              void* d_out, int out_size, void* d_ws, size_t ws_size,
                              hipStream_t stream) {
  const float* x        = (const float*)d_in[0];
  const float* enc_w    = (const float*)d_in[1];
  const float* enc_b    = (const float*)d_in[2];
  const float* in_proj  = (const float*)d_in[3];
  const float* conv_w   = (const float*)d_in[4];
  const float* conv_b   = (const float*)d_in[5];
  const float* dt_bias  = (const float*)d_in[6];
  const float* A_log    = (const float*)d_in[7];
  const float* Dp       = (const float*)d_in[8];
  const float* norm_w   = (const float*)d_in[9];
  const float* out_proj = (const float*)d_in[10];
  const float* ln_w     = (const float*)d_in[11];
  const float* ln_b     = (const float*)d_in[12];
  const float* dec_w    = (const float*)d_in[13];
  const float* dec_b    = (const float*)d_in[14];
  float* out = (float*)d_out;

  float* ws = (float*)d_ws;
  u16* WtIn  = (u16*)ws;                       // 2*NPAD*256 shorts = 655360
  u16* WtOut = WtIn + (long)2*NPAD*DMODEL;     // 2*256*512 shorts = 262144
  float* gbase = ws + 327680 + 131072;         // = ws + 458752 floats

  // Per-token fp32-equivalents: h 256 + hb 128 + z 256 + xbc 320 + xsx 256 + yg 256
  //                             + Bb 32 + Cb 32 + dtb 8 + lab 8 = 1552
  int NB = 8;
  while (NB > 1) {
    const long Mb = (long)NB * SEQ;
    const long bytes = (458752L + Mb * 1552L + 4096) * 4;
    if ((size_t)bytes <= ws_size) break;
    NB >>= 1;
  }
  const long Mb = (long)NB * SEQ;

  float* h    = gbase;                    // Mb*256 f
  u16*   hb   = (u16*)(h + Mb*DMODEL);    // Mb*256 u16
  u16*   zbuf = hb + Mb*DMODEL;           // Mb*512 u16
  u16*   xbc  = zbuf + Mb*DIN;            // Mb*640 u16 ; aliased by Sloc/tmp256 (Mb*256 f)
  u16*   xsx  = xbc + Mb*CONVDIM;         // Mb*512 u16
  u16*   yg   = xsx + Mb*DIN;             // Mb*512 u16 (y, then g in place)
  u16*   Bb   = yg + Mb*DIN;              // Mb*64 u16
  u16*   Cb   = Bb + Mb*DSTATE;           // Mb*64 u16
  float* dtb  = (float*)(Cb + Mb*DSTATE); // Mb*8 f
  float* lab  = dtb + Mb*NH;              // Mb*8 f (log dA)
  float* Pb   = lab + Mb*NH;              // <= 2048
  float* Sloc   = (float*)xbc;            // alias: xbc dead after conv
  float* tmp256 = (float*)xbc;            // alias: Sloc dead after scanY

  cvt_inw <<<dim3(2*NPAD),   dim3(256), 0, stream>>>(in_proj,  WtIn);
  cvt_outw<<<dim3(2*DMODEL), dim3(256), 0, stream>>>(out_proj, WtOut);

  const int ngroups = B_SZ / NB;
  for (int g = 0; g < ngroups; ++g) {
    const float* xg = x + (long)g*NB*SEQ*64;

    enc_kernel<<<dim3((int)(Mb/32)), dim3(256), 0, stream>>>(xg, enc_w, enc_b, h, hb);

    for (int l = 0; l < 2; ++l) {
      inproj_mfma<<<dim3((int)(Mb/128), NPAD/128), dim3(256), 0, stream>>>(
          hb, WtIn + (long)l*NPAD*DMODEL, zbuf, xbc, dtb, lab,
          dt_bias + l*NH, A_log + l*NH);
      conv_kernel<<<dim3((int)(Mb*20/256)), dim3(256), 0, stream>>>(
          xbc, conv_w + (long)l*CONVDIM*4, conv_b + (long)l*CONVDIM, xsx, Bb, Cb);
      scanS_kernel<<<dim3(NB*8*NCHUNK), dim3(256), 0, stream>>>(xsx, Bb, lab, dtb, Sloc, Pb);
      scanMid_kernel<<<dim3(NB*8, 64), dim3(64), 0, stream>>>(Sloc, Pb);
      scanY_kernel<<<dim3(NB*8*NCHUNK), dim3(512), 0, stream>>>(xsx, yg, Bb, Cb, lab, dtb, Sloc, Dp + l*NH);
      gnorm_kernel<<<dim3((int)Mb), dim3(256), 0, stream>>>(yg, zbuf, norm_w + (long)l*DIN);
      outproj_mfma<<<dim3((int)(Mb/128), 2), dim3(256), 0, stream>>>(
          yg, WtOut + (long)l*DMODEL*DIN, h, tmp256);
      ln_kernel<<<dim3((int)(Mb/4)), dim3(256), 0, stream>>>(tmp256, h, hb, ln_w + l*DMODEL, ln_b + l*DMODEL);
    }

    dec_kernel<<<dim3(NB*10), dim3(64), 0, stream>>>(h, dec_w, dec_b, out + (long)g*NB*10);
  }
}

// Round 13
// 568.359 us; speedup vs baseline: 1.2685x; 1.2685x over previous
//
#include <hip/hip_runtime.h>
#include <hip/hip_bf16.h>
#include <math.h>

// ---- model constants ----
#define B_SZ    8
#define SEQ     4096
#define DMODEL  256
#define DIN     512     // d_inner
#define DSTATE  64
#define NH      8
#define HD      64
#define CONVDIM 640
#define DPROJ   1160
#define NPAD    1280    // DPROJ padded to 10*128
#define NCHUNK  32      // scan chunks per (b,h)
#define CLEN    128     // SEQ / NCHUNK
#define STR64   68      // LDS row stride (shorts) for K=64 tiles
#define STR128  132     // LDS row stride (shorts) for K=128 tiles
#define GBUF    9216    // one staging buffer: (128*36 A) + (128*36 B) shorts

typedef unsigned long long u64;
typedef unsigned int u32;
typedef unsigned short u16;
typedef __attribute__((ext_vector_type(8))) short bf16x8;
typedef __attribute__((ext_vector_type(4))) float f32x4;

__device__ __forceinline__ float siluf(float v){ return v / (1.f + expf(-v)); }
__device__ __forceinline__ u16 f2bf(float f){ __hip_bfloat16 h = __float2bfloat16(f); return *(u16*)&h; }
__device__ __forceinline__ float bf2f(u16 u){ union{u32 i; float f;} t; t.i = ((u32)u)<<16; return t.f; }
__device__ __forceinline__ bf16x8 ldfrag(const u16* base){
  union { u64 u[2]; bf16x8 v; } t;
  const u64* p = (const u64*)base;
  t.u[0] = p[0]; t.u[1] = p[1];
  return t.v;
}

// ---------------- weight conversion (once per launch) ----------------
__global__ __launch_bounds__(256) void cvt_inw(const float* __restrict__ W, u16* __restrict__ Wt)
{
  const int blk = blockIdx.x;
  const int l = blk / NPAD, n = blk % NPAD;
  const int k = threadIdx.x;
  float v = 0.f;
  if (n < DPROJ) v = W[((long)l*DMODEL + k)*DPROJ + n];
  Wt[((long)l*NPAD + n)*DMODEL + k] = f2bf(v);
}

__global__ __launch_bounds__(256) void cvt_outw(const float* __restrict__ W, u16* __restrict__ Wt)
{
  const int blk = blockIdx.x;
  const int l = blk / DMODEL, n = blk % DMODEL;
  #pragma unroll
  for (int q = 0; q < 2; ++q) {
    const int k = threadIdx.x + q*256;
    const float v = W[((long)l*DIN + k)*DMODEL + n];
    Wt[((long)l*DMODEL + n)*DIN + k] = f2bf(v);
  }
}

// ---------------- encoder GEMM; writes h fp32 + hb bf16 ----------------
__global__ __launch_bounds__(256) void enc_kernel(const float* __restrict__ x,
    const float* __restrict__ W, const float* __restrict__ bias,
    float* __restrict__ h, u16* __restrict__ hb)
{
  __shared__ float xl[32*64];
  const int tid = threadIdx.x;
  const long t0 = (long)blockIdx.x * 32;
  for (int i = tid; i < 32*64; i += 256) xl[i] = x[t0*64 + i];
  __syncthreads();
  float acc[32];
  const float bv = bias[tid];
  #pragma unroll
  for (int tok = 0; tok < 32; ++tok) acc[tok] = bv;
  for (int k = 0; k < 64; ++k) {
    const float wv = W[k*DMODEL + tid];
    #pragma unroll
    for (int tok = 0; tok < 32; ++tok) acc[tok] += xl[tok*64 + k] * wv;
  }
  #pragma unroll
  for (int tok = 0; tok < 32; ++tok) {
    h [(t0 + tok)*DMODEL + tid] = acc[tok];
    hb[(t0 + tok)*DMODEL + tid] = f2bf(acc[tok]);
  }
}

// ---------------- in_proj MFMA GEMM 128x128 tile, BK=32; double-buffered LDS staging ----------------
__global__ __launch_bounds__(256) void inproj_mfma(const u16* __restrict__ hb,
    const u16* __restrict__ Wt, u16* __restrict__ zbuf, u16* __restrict__ xbc,
    float* __restrict__ dtb, float* __restrict__ lab,
    const float* __restrict__ dt_bias, const float* __restrict__ A_log)
{
  __shared__ __align__(16) u16 pool[2*GBUF];   // ping-pong staging; epilogue Ep aliases buf0
  const int tid = threadIdx.x;
  const long m0 = (long)blockIdx.x * 128;
  const int n0 = blockIdx.y * 128;
  const int w = tid >> 6, lane = tid & 63;
  const int q = lane >> 4, l16 = lane & 15;
  const int srow = tid >> 1, sseg = tid & 1;   // 2 lanes/row, 16 shorts (32 B) each
  const u64* aSrc = (const u64*)(hb + (m0 + srow)*DMODEL + sseg*16);
  const u64* bSrc = (const u64*)(Wt + (long)(n0 + srow)*DMODEL + sseg*16);
  u64 ra0,ra1,ra2,ra3, rb0,rb1,rb2,rb3;
  ra0=aSrc[0];ra1=aSrc[1];ra2=aSrc[2];ra3=aSrc[3];
  rb0=bSrc[0];rb1=bSrc[1];rb2=bSrc[2];rb3=bSrc[3];
  {
    u64* da = (u64*)(pool + srow*36 + sseg*16);
    da[0]=ra0; da[1]=ra1; da[2]=ra2; da[3]=ra3;
    u64* db = (u64*)(pool + 128*36 + srow*36 + sseg*16);
    db[0]=rb0; db[1]=rb1; db[2]=rb2; db[3]=rb3;
  }
  f32x4 acc[2][8] = {{{0.f,0.f,0.f,0.f}}};
  #pragma unroll
  for (int kk = 0; kk < 8; ++kk) {
    __syncthreads();                          // buf[kk&1] staged & visible
    if (kk < 7) {                             // next K-step: 32 shorts = 8 u64 per row
      const u64* a2 = aSrc + (long)(kk+1)*8;
      const u64* b2 = bSrc + (long)(kk+1)*8;
      ra0=a2[0];ra1=a2[1];ra2=a2[2];ra3=a2[3];
      rb0=b2[0];rb1=b2[1];rb2=b2[2];rb3=b2[3];
    }
    const u16* cur = pool + (kk&1)*GBUF;
    bf16x8 af[2], bfr[8];
    #pragma unroll
    for (int mi=0;mi<2;mi++) af[mi] = ldfrag(&cur[(w*32 + mi*16 + l16)*36 + q*8]);
    #pragma unroll
    for (int nj=0;nj<8;nj++) bfr[nj] = ldfrag(&cur[128*36 + (nj*16 + l16)*36 + q*8]);
    #pragma unroll
    for (int mi=0;mi<2;mi++)
      #pragma unroll
      for (int nj=0;nj<8;nj++)
        acc[mi][nj] = __builtin_amdgcn_mfma_f32_16x16x32_bf16(af[mi], bfr[nj], acc[mi][nj], 0,0,0);
    if (kk < 7) {
      u16* nxt = pool + ((kk+1)&1)*GBUF;
      u64* da = (u64*)(nxt + srow*36 + sseg*16);
      da[0]=ra0; da[1]=ra1; da[2]=ra2; da[3]=ra3;
      u64* db = (u64*)(nxt + 128*36 + srow*36 + sseg*16);
      db[0]=rb0; db[1]=rb1; db[2]=rb2; db[3]=rb3;
    }
  }
  // last compute used buf1 (kk=7); Ep below aliases buf0 (8960 <= GBUF) -> disjoint, no barrier needed
  if (n0 < DIN + CONVDIM) {
    u16* Ep = pool;   // [64][140] u16; stride 140 (=6 mod 32 banks) kills quarter-set conflicts
    #pragma unroll
    for (int mi=0;mi<2;mi++){
      if (mi) __syncthreads();
      #pragma unroll
      for (int nj=0;nj<8;nj++){
        const int col = nj*16 + l16;
        #pragma unroll
        for (int r=0;r<4;r++){
          const int er = w*16 + q*4 + r;
          Ep[er*140 + col] = f2bf(acc[mi][nj][r]);
        }
      }
      __syncthreads();
      {
        const int er2 = tid >> 2, seg = tid & 3;
        const long grow = m0 + (er2>>4)*32 + mi*16 + (er2&15);
        const u64* s = (const u64*)(Ep + er2*140 + seg*32);
        u64 v0=s[0], v1=s[1], v2=s[2], v3=s[3], v4=s[4], v5=s[5], v6=s[6], v7=s[7];
        u64* dptr;
        if (n0 < DIN) dptr = (u64*)(zbuf + grow*DIN + n0 + seg*32);
        else          dptr = (u64*)(xbc + grow*CONVDIM + (n0 - DIN) + seg*32);
        dptr[0]=v0; dptr[1]=v1; dptr[2]=v2; dptr[3]=v3;
        dptr[4]=v4; dptr[5]=v5; dptr[6]=v6; dptr[7]=v7;
      }
    }
  } else {
    // dt tile: only cols 1152..1159 valid
    #pragma unroll
    for (int mi=0;mi<2;mi++){
      #pragma unroll
      for (int nj=0;nj<8;nj++){
        const int col = n0 + nj*16 + l16;
        if (col < DPROJ) {
          const int hh = col - (DIN + CONVDIM);
          #pragma unroll
          for (int r=0;r<4;r++){
            const long row = m0 + w*32 + mi*16 + q*4 + r;
            const float dv = acc[mi][nj][r] + dt_bias[hh];
            const float sp = dv > 20.f ? dv : log1pf(expf(dv));
            dtb[row*NH + hh] = sp;
            lab[row*NH + hh] = sp * (-expf(A_log[hh]));   // log dA
          }
        }
      }
    }
  }
}

// ---------------- out_proj MFMA GEMM 128x128 tile + residual; double-buffered LDS staging ----------------
__global__ __launch_bounds__(256) void outproj_mfma(const u16* __restrict__ gb,
    const u16* __restrict__ Wt, const float* __restrict__ resid, float* __restrict__ outb)
{
  __shared__ __align__(16) u16 pool[2*GBUF];
  const int tid = threadIdx.x;
  const long m0 = (long)blockIdx.x * 128;
  const int n0 = blockIdx.y * 128;
  const int w = tid >> 6, lane = tid & 63;
  const int q = lane >> 4, l16 = lane & 15;
  const int srow = tid >> 1, sseg = tid & 1;
  const u64* aSrc = (const u64*)(gb + (m0 + srow)*DIN + sseg*16);
  const u64* bSrc = (const u64*)(Wt + (long)(n0 + srow)*DIN + sseg*16);
  u64 ra0,ra1,ra2,ra3, rb0,rb1,rb2,rb3;
  ra0=aSrc[0];ra1=aSrc[1];ra2=aSrc[2];ra3=aSrc[3];
  rb0=bSrc[0];rb1=bSrc[1];rb2=bSrc[2];rb3=bSrc[3];
  {
    u64* da = (u64*)(pool + srow*36 + sseg*16);
    da[0]=ra0; da[1]=ra1; da[2]=ra2; da[3]=ra3;
    u64* db = (u64*)(pool + 128*36 + srow*36 + sseg*16);
    db[0]=rb0; db[1]=rb1; db[2]=rb2; db[3]=rb3;
  }
  f32x4 acc[2][8] = {{{0.f,0.f,0.f,0.f}}};
  #pragma unroll
  for (int kk = 0; kk < 16; ++kk) {
    __syncthreads();
    if (kk < 15) {                            // next K-step: 32 shorts = 8 u64 per row
      const u64* a2 = aSrc + (long)(kk+1)*8;
      const u64* b2 = bSrc + (long)(kk+1)*8;
      ra0=a2[0];ra1=a2[1];ra2=a2[2];ra3=a2[3];
      rb0=b2[0];rb1=b2[1];rb2=b2[2];rb3=b2[3];
    }
    const u16* cur = pool + (kk&1)*GBUF;
    bf16x8 af[2], bfr[8];
    #pragma unroll
    for (int mi=0;mi<2;mi++) af[mi] = ldfrag(&cur[(w*32 + mi*16 + l16)*36 + q*8]);
    #pragma unroll
    for (int nj=0;nj<8;nj++) bfr[nj] = ldfrag(&cur[128*36 + (nj*16 + l16)*36 + q*8]);
    #pragma unroll
    for (int mi=0;mi<2;mi++)
      #pragma unroll
      for (int nj=0;nj<8;nj++)
        acc[mi][nj] = __builtin_amdgcn_mfma_f32_16x16x32_bf16(af[mi], bfr[nj], acc[mi][nj], 0,0,0);
    if (kk < 15) {
      u16* nxt = pool + ((kk+1)&1)*GBUF;
      u64* da = (u64*)(nxt + srow*36 + sseg*16);
      da[0]=ra0; da[1]=ra1; da[2]=ra2; da[3]=ra3;
      u64* db = (u64*)(nxt + 128*36 + srow*36 + sseg*16);
      db[0]=rb0; db[1]=rb1; db[2]=rb2; db[3]=rb3;
    }
  }
  #pragma unroll
  for (int mi=0;mi<2;mi++){
    #pragma unroll
    for (int nj=0;nj<8;nj++){
      const int col = n0 + nj*16 + l16;
      #pragma unroll
      for (int r=0;r<4;r++){
        const long row = m0 + w*32 + mi*16 + q*4 + r;
        outb[row*DMODEL + col] = acc[mi][nj][r] + resid[row*DMODEL + col];
      }
    }
  }
}

// ---------------- depthwise causal conv + SiLU: strip kernel ----------------
__global__ __launch_bounds__(256) void conv_kernel(const u16* __restrict__ xbc,
    const float* __restrict__ cw, const float* __restrict__ cb,
    u16* __restrict__ xsx, u16* __restrict__ Bb, u16* __restrict__ Cb)
{
  const long idx = (long)blockIdx.x * 256 + threadIdx.x;   // Mb*20 threads
  const int c4 = (int)(idx % 160) * 4;
  const long bt0 = (idx / 160) * 8;          // strip start (strips never cross batch)
  const int tseq = (int)(bt0 & (SEQ-1));
  const float4 b4 = *(const float4*)(cb + c4);
  const float4 w0v = *(const float4*)(cw + (c4+0)*4);
  const float4 w1v = *(const float4*)(cw + (c4+1)*4);
  const float4 w2v = *(const float4*)(cw + (c4+2)*4);
  const float4 w3v = *(const float4*)(cw + (c4+3)*4);
  const float W0[4] = {w0v.x,w0v.y,w0v.z,w0v.w};
  const float W1[4] = {w1v.x,w1v.y,w1v.z,w1v.w};
  const float W2[4] = {w2v.x,w2v.y,w2v.z,w2v.w};
  const float W3[4] = {w3v.x,w3v.y,w3v.z,w3v.w};
  float i0[11], i1[11], i2[11], i3[11];
  #pragma unroll
  for (int k = 0; k < 11; ++k) {
    u64 v = 0;
    if (tseq - 3 + k >= 0) v = *(const u64*)(xbc + (bt0 - 3 + k)*CONVDIM + c4);
    i0[k]=bf2f((u16)v); i1[k]=bf2f((u16)(v>>16)); i2[k]=bf2f((u16)(v>>32)); i3[k]=bf2f((u16)(v>>48));
  }
  u16* dst; long base; int stride;
  if (c4 < DIN)              { dst = xsx; base = bt0*DIN + c4;              stride = DIN; }
  else if (c4 < DIN+DSTATE)  { dst = Bb;  base = bt0*DSTATE + (c4-DIN);     stride = DSTATE; }
  else                       { dst = Cb;  base = bt0*DSTATE + (c4-DIN-DSTATE); stride = DSTATE; }
  #pragma unroll
  for (int j = 0; j < 8; ++j) {
    float a0=b4.x, a1=b4.y, a2=b4.z, a3=b4.w;
    #pragma unroll
    for (int k = 0; k < 4; ++k) {
      a0 += W0[k]*i0[j+k]; a1 += W1[k]*i1[j+k];
      a2 += W2[k]*i2[j+k]; a3 += W3[k]*i3[j+k];
    }
    a0=siluf(a0); a1=siluf(a1); a2=siluf(a2); a3=siluf(a3);
    const u64 r = (u64)f2bf(a0) | ((u64)f2bf(a1)<<16) | ((u64)f2bf(a2)<<32) | ((u64)f2bf(a3)<<48);
    *(u64*)(dst + base + (long)j*stride) = r;
  }
}

// ---------------- SSD phase A: per chunk-head local state via MFMA ----------------
__global__ __launch_bounds__(256) void scanS_kernel(const u16* __restrict__ xsx,
    const u16* __restrict__ Bb, const float* __restrict__ lab, const float* __restrict__ dtb,
    float* __restrict__ Sloc, float* __restrict__ Pb)
{
  __shared__ __align__(16) u16 Btr[64*STR128];   // [n][s]
  __shared__ __align__(16) u16 Uw[64*STR128];    // [p][s]
  __shared__ float cexpL[128];
  const int wg = blockIdx.x;
  const int c = wg & (NCHUNK-1), bh = wg >> 5, hh = bh & (NH-1), b = bh >> 3;
  const int tid = threadIdx.x;
  const long bt0 = (long)b*SEQ + c*CLEN;
  if (tid < 64) {   // wave 0: inclusive prefix of log dA over 128 steps
    float a0 = lab[(bt0+tid)*NH + hh];
    float a1 = lab[(bt0+64+tid)*NH + hh];
    const float d0 = dtb[(bt0+tid)*NH + hh];
    const float d1 = dtb[(bt0+64+tid)*NH + hh];
    #pragma unroll
    for (int o=1;o<64;o<<=1){
      const float t0=__shfl_up(a0,o), t1=__shfl_up(a1,o);
      if (tid>=o){a0+=t0;a1+=t1;}
    }
    a1 += __shfl(a0,63);
    const float ctot = __shfl(a1,63);
    cexpL[tid]    = d0*__expf(ctot - a0);
    cexpL[tid+64] = d1*__expf(ctot - a1);
    if (tid==0) Pb[wg] = __expf(ctot);
  }
  __syncthreads();
  {
    const int v = tid & 63, r0 = tid >> 6;
    #pragma unroll 4
    for (int k=0;k<32;k++){
      const int s = r0 + k*4;
      Btr[v*STR128 + s] = Bb[(bt0+s)*DSTATE + v];
      Uw[v*STR128 + s]  = f2bf(cexpL[s]*bf2f(xsx[(bt0+s)*DIN + hh*HD + v]));
    }
  }
  __syncthreads();
  const int w = tid>>6, lane = tid&63, q = lane>>4, l16 = lane&15;
  f32x4 acc[4] = {};
  #pragma unroll
  for (int ks=0;ks<4;ks++){
    const bf16x8 af = ldfrag(&Uw[(w*16+l16)*STR128 + ks*32 + q*8]);
    #pragma unroll
    for (int nj=0;nj<4;nj++){
      const bf16x8 bf = ldfrag(&Btr[(nj*16+l16)*STR128 + ks*32 + q*8]);
      acc[nj] = __builtin_amdgcn_mfma_f32_16x16x32_bf16(af, bf, acc[nj], 0,0,0);
    }
  }
  const long sb = (long)wg*4096;   // [wg][p][n]
  #pragma unroll
  for (int nj=0;nj<4;nj++)
    #pragma unroll
    for (int r=0;r<4;r++)
      Sloc[sb + (w*16+q*4+r)*64 + nj*16 + l16] = acc[nj][r];
}

// Parallel combine: Sloc[c] := running; run = P[c]*run + tmp
__global__ __launch_bounds__(64) void scanMid_kernel(float* __restrict__ Sloc, const float* __restrict__ Pb)
{
  const int bh = blockIdx.x;
  const int rr = blockIdx.y;
  const int p  = threadIdx.x;
  float run = 0.f;
  for (int c = 0; c < NCHUNK; ++c) {
    const long base = ((long)(bh*NCHUNK + c))*4096 + rr*64 + p;
    const float Pc = Pb[bh*NCHUNK + c];
    const float tmp = Sloc[base];
    Sloc[base] = run;
    run = run*Pc + tmp;
  }
}

// ---------------- SSD phase C: Y = ((C Bt) o L) U + diag(exp(cum)) (C h0) + D*x ; coalesced y out ----------------
__global__ __launch_bounds__(512) void scanY_kernel(const u16* __restrict__ xsx,
    u16* __restrict__ yg, const u16* __restrict__ Bb, const u16* __restrict__ Cb,
    const float* __restrict__ lab, const float* __restrict__ dtb,
    const float* __restrict__ Sinit, const float* __restrict__ Dp)
{
  __shared__ __align__(16) u16 pool[2*128*STR64];  // Bs | Cs; overlaid by Ms[t][s]; then by y-bounce
  __shared__ __align__(16) u16 Ut[64*STR128];      // [p][s]
  __shared__ __align__(16) u16 h0t[64*STR64];      // [p][n]
  __shared__ float cumL[128];
  __shared__ float dtL[128];
  u16* Bs = pool;
  u16* Cs = pool + 128*STR64;
  u16* Ms = pool;

  const int wg = blockIdx.x;
  const int c = wg & (NCHUNK-1), bh = wg >> 5, hh = bh & (NH-1), b = bh >> 3;
  const int tid = threadIdx.x;
  const long bt0 = (long)b*SEQ + c*CLEN;

  if (tid < 64) {
    float a0 = lab[(bt0+tid)*NH + hh];
    float a1 = lab[(bt0+64+tid)*NH + hh];
    dtL[tid]    = dtb[(bt0+tid)*NH + hh];
    dtL[tid+64] = dtb[(bt0+64+tid)*NH + hh];
    #pragma unroll
    for (int o=1;o<64;o<<=1){
      const float t0=__shfl_up(a0,o), t1=__shfl_up(a1,o);
      if (tid>=o){a0+=t0;a1+=t1;}
    }
    a1 += __shfl(a0,63);
    cumL[tid]=a0; cumL[tid+64]=a1;
  }
  __syncthreads();
  {
    const int n = tid & 63, r0 = tid >> 6;   // 512 threads: r0 in 0..7
    #pragma unroll 4
    for (int k=0;k<16;k++){
      const int s = r0 + k*8;
      Bs[s*STR64 + n] = Bb[(bt0+s)*DSTATE + n];
      Cs[s*STR64 + n] = Cb[(bt0+s)*DSTATE + n];
      Ut[n*STR128 + s] = f2bf(dtL[s]*bf2f(xsx[(bt0+s)*DIN + hh*HD + n]));
    }
    const int n0 = r0*8;
    const float* hp = Sinit + (long)wg*4096 + n*64 + n0;
    #pragma unroll
    for (int j=0;j<8;j++) h0t[n*STR64 + n0 + j] = f2bf(hp[j]);
  }
  __syncthreads();

  const int w = tid>>6, lane = tid&63, q = lane>>4, l16 = lane&15;
  f32x4 accG[8] = {};
  f32x4 accI[4] = {};
  #pragma unroll
  for (int ks=0;ks<2;ks++){
    const bf16x8 af = ldfrag(&Cs[(w*16+l16)*STR64 + ks*32 + q*8]);
    #pragma unroll
    for (int nj=0;nj<8;nj++)
      accG[nj] = __builtin_amdgcn_mfma_f32_16x16x32_bf16(af, ldfrag(&Bs[(nj*16+l16)*STR64 + ks*32 + q*8]), accG[nj], 0,0,0);
    #pragma unroll
    for (int nj=0;nj<4;nj++)
      accI[nj] = __builtin_amdgcn_mfma_f32_16x16x32_bf16(af, ldfrag(&h0t[(nj*16+l16)*STR64 + ks*32 + q*8]), accI[nj], 0,0,0);
  }
  __syncthreads();
  #pragma unroll
  for (int nj=0;nj<8;nj++){
    const int s = nj*16 + l16;
    #pragma unroll
    for (int r=0;r<4;r++){
      const int t = w*16 + q*4 + r;
      const float v = (s<=t) ? accG[nj][r]*__expf(cumL[t]-cumL[s]) : 0.f;
      Ms[t*STR128 + s] = f2bf(v);
    }
  }
  __syncthreads();
  f32x4 accY[4] = {};
  #pragma unroll
  for (int ks=0;ks<4;ks++){
    const bf16x8 af = ldfrag(&Ms[(w*16+l16)*STR128 + ks*32 + q*8]);
    #pragma unroll
    for (int nj=0;nj<4;nj++)
      accY[nj] = __builtin_amdgcn_mfma_f32_16x16x32_bf16(af, ldfrag(&Ut[(nj*16+l16)*STR128 + ks*32 + q*8]), accY[nj], 0,0,0);
  }
  const float Dv = Dp[hh];
  __syncthreads();   // Ms reads done; reuse pool as y-bounce [128][68]
  #pragma unroll
  for (int nj=0;nj<4;nj++){
    const int p = nj*16 + l16;
    #pragma unroll
    for (int r=0;r<4;r++){
      const int t = w*16 + q*4 + r;
      const float xv = bf2f(xsx[(bt0+t)*DIN + hh*HD + p]);
      pool[t*STR64 + p] = f2bf(accY[nj][r] + __expf(cumL[t])*accI[nj][r] + Dv*xv);
    }
  }
  __syncthreads();
  {
    const int row = tid >> 2, seg = tid & 3;
    const u64* s = (const u64*)(pool + row*STR64 + seg*16);
    u64 a=s[0], b2=s[1], c2=s[2], d=s[3];
    u64* dptr = (u64*)(yg + (bt0+row)*DIN + hh*HD + seg*16);
    dptr[0]=a; dptr[1]=b2; dptr[2]=c2; dptr[3]=d;
  }
}

// ---------------- y*silu(z) + RMSNorm; bf16 in, bf16 out in place ----------------
__global__ __launch_bounds__(256) void gnorm_kernel(u16* __restrict__ y_io,
    const u16* __restrict__ zb, const float* __restrict__ nw)
{
  const long row = blockIdx.x;
  const int tid = threadIdx.x;
  float g[2];
  #pragma unroll
  for (int q=0;q<2;q++){
    const int cc = tid + q*256;
    const float yv = bf2f(y_io[row*DIN + cc]);
    const float zv = bf2f(zb[row*DIN + cc]);
    g[q] = yv * siluf(zv);
  }
  float ss = g[0]*g[0] + g[1]*g[1];
  #pragma unroll
  for (int o=32;o;o>>=1) ss += __shfl_down(ss, o);
  __shared__ float red[4];
  if ((tid & 63) == 0) red[tid>>6] = ss;
  __syncthreads();
  const float tot = red[0]+red[1]+red[2]+red[3];
  const float scale = rsqrtf(tot * (1.f/512.f) + 1e-5f);
  #pragma unroll
  for (int q=0;q<2;q++){
    const int cc = tid + q*256;
    y_io[row*DIN + cc] = f2bf(g[q] * scale * nw[cc]);
  }
}

// ---------------- LayerNorm; writes h fp32 + hb bf16 ----------------
__global__ __launch_bounds__(256) void ln_kernel(const float* __restrict__ in,
    float* __restrict__ h, u16* __restrict__ hb,
    const float* __restrict__ w, const float* __restrict__ bb)
{
  const int lane = threadIdx.x & 63;
  const int wid  = threadIdx.x >> 6;
  const long row = (long)blockIdx.x * 4 + wid;
  const float* r = in + row*DMODEL;
  float v[4]; float sum = 0.f, sq = 0.f;
  #pragma unroll
  for (int q=0;q<4;q++){ v[q] = r[lane + q*64]; sum += v[q]; sq += v[q]*v[q]; }
  #pragma unroll
  for (int o=32;o;o>>=1){ sum += __shfl_xor(sum,o); sq += __shfl_xor(sq,o); }
  const float mu = sum * (1.f/256.f);
  const float var = sq * (1.f/256.f) - mu*mu;
  const float rs = rsqrtf(var + 1e-5f);
  #pragma unroll
  for (int q=0;q<4;q++){
    const int cc = lane + q*64;
    const float o = (v[q]-mu)*rs*w[cc] + bb[cc];
    h [row*DMODEL + cc] = o;
    hb[row*DMODEL + cc] = f2bf(o);
  }
}

// ---------------- decoder (fp32 output) ----------------
__global__ __launch_bounds__(64) void dec_kernel(const float* __restrict__ h,
    const float* __restrict__ W, const float* __restrict__ bias, float* __restrict__ out)
{
  const int wg = blockIdx.x;
  const int b = wg / 10, o = wg % 10;
  const int lane = threadIdx.x;
  const float* r = h + ((long)b*SEQ + SEQ-1)*DMODEL;
  float s = 0.f;
  #pragma unroll
  for (int q=0;q<4;q++){ const int k = lane + q*64; s += r[k]*W[k*10+o]; }
  #pragma unroll
  for (int o2=32;o2;o2>>=1) s += __shfl_down(s, o2);
  if (lane == 0) out[wg] = s + bias[o];
}

extern "C" void kernel_launch(void* const* d_in, const int* in_sizes, int n_in,
                              void* d_out, int out_size, void* d_ws, size_t ws_size,
                              hipStream_t stream) {
  const float* x        = (const float*)d_in[0];
  const float* enc_w    = (const float*)d_in[1];
  const float* enc_b    = (const float*)d_in[2];
  const float* in_proj  = (const float*)d_in[3];
  const float* conv_w   = (const float*)d_in[4];
  const float* conv_b   = (const float*)d_in[5];
  const float* dt_bias  = (const float*)d_in[6];
  const float* A_log    = (const float*)d_in[7];
  const float* Dp       = (const float*)d_in[8];
  const float* norm_w   = (const float*)d_in[9];
  const float* out_proj = (const float*)d_in[10];
  const float* ln_w     = (const float*)d_in[11];
  const float* ln_b     = (const float*)d_in[12];
  const float* dec_w    = (const float*)d_in[13];
  const float* dec_b    = (const float*)d_in[14];
  float* out = (float*)d_out;

  float* ws = (float*)d_ws;
  u16* WtIn  = (u16*)ws;                       // 2*NPAD*256 shorts = 655360
  u16* WtOut = WtIn + (long)2*NPAD*DMODEL;     // 2*256*512 shorts = 262144
  float* gbase = ws + 327680 + 131072;         // = ws + 458752 floats

  // Per-token fp32-equivalents: h 256 + hb 128 + z 256 + xbc 320 + xsx 256 + yg 256
  //                             + Bb 32 + Cb 32 + dtb 8 + lab 8 = 1552
  int NB = 8;
  while (NB > 1) {
    const long Mb = (long)NB * SEQ;
    const long bytes = (458752L + Mb * 1552L + 4096) * 4;
    if ((size_t)bytes <= ws_size) break;
    NB >>= 1;
  }
  const long Mb = (long)NB * SEQ;

  float* h    = gbase;                    // Mb*256 f
  u16*   hb   = (u16*)(h + Mb*DMODEL);    // Mb*256 u16
  u16*   zbuf = hb + Mb*DMODEL;           // Mb*512 u16
  u16*   xbc  = zbuf + Mb*DIN;            // Mb*640 u16 ; aliased by Sloc/tmp256 (Mb*256 f)
  u16*   xsx  = xbc + Mb*CONVDIM;         // Mb*512 u16
  u16*   yg   = xsx + Mb*DIN;             // Mb*512 u16 (y, then g in place)
  u16*   Bb   = yg + Mb*DIN;              // Mb*64 u16
  u16*   Cb   = Bb + Mb*DSTATE;           // Mb*64 u16
  float* dtb  = (float*)(Cb + Mb*DSTATE); // Mb*8 f
  float* lab  = dtb + Mb*NH;              // Mb*8 f (log dA)
  float* Pb   = lab + Mb*NH;              // <= 2048
  float* Sloc   = (float*)xbc;            // alias: xbc dead after conv
  float* tmp256 = (float*)xbc;            // alias: Sloc dead after scanY

  cvt_inw <<<dim3(2*NPAD),   dim3(256), 0, stream>>>(in_proj,  WtIn);
  cvt_outw<<<dim3(2*DMODEL), dim3(256), 0, stream>>>(out_proj, WtOut);

  const int ngroups = B_SZ / NB;
  for (int g = 0; g < ngroups; ++g) {
    const float* xg = x + (long)g*NB*SEQ*64;

    enc_kernel<<<dim3((int)(Mb/32)), dim3(256), 0, stream>>>(xg, enc_w, enc_b, h, hb);

    for (int l = 0; l < 2; ++l) {
      inproj_mfma<<<dim3((int)(Mb/128), NPAD/128), dim3(256), 0, stream>>>(
          hb, WtIn + (long)l*NPAD*DMODEL, zbuf, xbc, dtb, lab,
          dt_bias + l*NH, A_log + l*NH);
      conv_kernel<<<dim3((int)(Mb*20/256)), dim3(256), 0, stream>>>(
          xbc, conv_w + (long)l*CONVDIM*4, conv_b + (long)l*CONVDIM, xsx, Bb, Cb);
      scanS_kernel<<<dim3(NB*8*NCHUNK), dim3(256), 0, stream>>>(xsx, Bb, lab, dtb, Sloc, Pb);
      scanMid_kernel<<<dim3(NB*8, 64), dim3(64), 0, stream>>>(Sloc, Pb);
      scanY_kernel<<<dim3(NB*8*NCHUNK), dim3(512), 0, stream>>>(xsx, yg, Bb, Cb, lab, dtb, Sloc, Dp + l*NH);
      gnorm_kernel<<<dim3((int)Mb), dim3(256), 0, stream>>>(yg, zbuf, norm_w + (long)l*DIN);
      outproj_mfma<<<dim3((int)(Mb/128), 2), dim3(256), 0, stream>>>(
          yg, WtOut + (long)l*DMODEL*DIN, h, tmp256);
      ln_kernel<<<dim3((int)(Mb/4)), dim3(256), 0, stream>>>(tmp256, h, hb, ln_w + l*DMODEL, ln_b + l*DMODEL);
    }

    dec_kernel<<<dim3(NB*10), dim3(64), 0, stream>>>(h, dec_w, dec_b, out + (long)g*NB*10);
  }
}

// Round 15
// 527.548 us; speedup vs baseline: 1.3666x; 1.0774x over previous
//
#include <hip/hip_runtime.h>
#include <hip/hip_bf16.h>
#include <math.h>

// ---- model constants ----
#define B_SZ    8
#define SEQ     4096
#define DMODEL  256
#define DIN     512     // d_inner
#define DSTATE  64
#define NH      8
#define HD      64
#define CONVDIM 640
#define DPROJ   1160
#define NPAD    1280    // DPROJ padded to 10*128
#define NCHUNK  32      // scan chunks per (b,h)
#define CLEN    128     // SEQ / NCHUNK
#define STR64   68      // LDS row stride (shorts) for K=64 tiles
#define STR128  132     // LDS row stride (shorts) for K=128 tiles

typedef unsigned long long u64;
typedef unsigned int u32;
typedef unsigned short u16;
typedef __attribute__((ext_vector_type(8))) short bf16x8;
typedef __attribute__((ext_vector_type(4))) float f32x4;

__device__ __forceinline__ float siluf(float v){ return v / (1.f + expf(-v)); }
__device__ __forceinline__ u16 f2bf(float f){ __hip_bfloat16 h = __float2bfloat16(f); return *(u16*)&h; }
__device__ __forceinline__ float bf2f(u16 u){ union{u32 i; float f;} t; t.i = ((u32)u)<<16; return t.f; }
__device__ __forceinline__ bf16x8 ldfrag(const u16* base){
  union { u64 u[2]; bf16x8 v; } t;
  const u64* p = (const u64*)base;
  t.u[0] = p[0]; t.u[1] = p[1];
  return t.v;
}

// ---------------- weight conversion (once per launch) ----------------
__global__ __launch_bounds__(256) void cvt_inw(const float* __restrict__ W, u16* __restrict__ Wt)
{
  const int blk = blockIdx.x;
  const int l = blk / NPAD, n = blk % NPAD;
  const int k = threadIdx.x;
  float v = 0.f;
  if (n < DPROJ) v = W[((long)l*DMODEL + k)*DPROJ + n];
  Wt[((long)l*NPAD + n)*DMODEL + k] = f2bf(v);
}

__global__ __launch_bounds__(256) void cvt_outw(const float* __restrict__ W, u16* __restrict__ Wt)
{
  const int blk = blockIdx.x;
  const int l = blk / DMODEL, n = blk % DMODEL;
  #pragma unroll
  for (int q = 0; q < 2; ++q) {
    const int k = threadIdx.x + q*256;
    const float v = W[((long)l*DIN + k)*DMODEL + n];
    Wt[((long)l*DMODEL + n)*DIN + k] = f2bf(v);
  }
}

// ---------------- encoder GEMM; writes h fp32 + hb bf16 ----------------
__global__ __launch_bounds__(256) void enc_kernel(const float* __restrict__ x,
    const float* __restrict__ W, const float* __restrict__ bias,
    float* __restrict__ h, u16* __restrict__ hb)
{
  __shared__ float xl[32*64];
  const int tid = threadIdx.x;
  const long t0 = (long)blockIdx.x * 32;
  for (int i = tid; i < 32*64; i += 256) xl[i] = x[t0*64 + i];
  __syncthreads();
  float acc[32];
  const float bv = bias[tid];
  #pragma unroll
  for (int tok = 0; tok < 32; ++tok) acc[tok] = bv;
  for (int k = 0; k < 64; ++k) {
    const float wv = W[k*DMODEL + tid];
    #pragma unroll
    for (int tok = 0; tok < 32; ++tok) acc[tok] += xl[tok*64 + k] * wv;
  }
  #pragma unroll
  for (int tok = 0; tok < 32; ++tok) {
    h [(t0 + tok)*DMODEL + tid] = acc[tok];
    hb[(t0 + tok)*DMODEL + tid] = f2bf(acc[tok]);
  }
}

// ---------------- in_proj MFMA GEMM 128x128 tile, BK=32 (R10 structure) ----------------
__global__ __launch_bounds__(256) void inproj_mfma(const u16* __restrict__ hb,
    const u16* __restrict__ Wt, u16* __restrict__ zbuf, u16* __restrict__ xbc,
    float* __restrict__ dtb, float* __restrict__ lab,
    const float* __restrict__ dt_bias, const float* __restrict__ A_log)
{
  __shared__ __align__(16) u16 pool[128*36*2];   // staging Asl|Bsl; epilogue bounce aliases it
  u16* Asl = pool;
  u16* Bsl = pool + 128*36;
  u16* Ep  = pool;                               // [64][136] u16 per mi-half
  const int tid = threadIdx.x;
  const long m0 = (long)blockIdx.x * 128;
  const int n0 = blockIdx.y * 128;
  const int w = tid >> 6, lane = tid & 63;
  const int q = lane >> 4, l16 = lane & 15;
  const int srow = tid >> 1, sseg = tid & 1;   // 2 lanes/row, 16 shorts (32 B) each
  f32x4 acc[2][8] = {{{0.f,0.f,0.f,0.f}}};
  for (int k0 = 0; k0 < DMODEL; k0 += 32) {
    {
      const u64* s = (const u64*)(hb + (m0 + srow)*DMODEL + k0 + sseg*16);
      u64 a=s[0], b=s[1], c=s[2], d=s[3];
      u64* dst = (u64*)(&Asl[srow*36 + sseg*16]);
      dst[0]=a; dst[1]=b; dst[2]=c; dst[3]=d;
    }
    {
      const u64* s = (const u64*)(Wt + (long)(n0 + srow)*DMODEL + k0 + sseg*16);
      u64 a=s[0], b=s[1], c=s[2], d=s[3];
      u64* dst = (u64*)(&Bsl[srow*36 + sseg*16]);
      dst[0]=a; dst[1]=b; dst[2]=c; dst[3]=d;
    }
    __syncthreads();
    bf16x8 af[2], bfr[8];
    #pragma unroll
    for (int mi=0;mi<2;mi++) af[mi] = ldfrag(&Asl[(w*32 + mi*16 + l16)*36 + q*8]);
    #pragma unroll
    for (int nj=0;nj<8;nj++) bfr[nj] = ldfrag(&Bsl[(nj*16 + l16)*36 + q*8]);
    #pragma unroll
    for (int mi=0;mi<2;mi++)
      #pragma unroll
      for (int nj=0;nj<8;nj++)
        acc[mi][nj] = __builtin_amdgcn_mfma_f32_16x16x32_bf16(af[mi], bfr[nj], acc[mi][nj], 0,0,0);
    __syncthreads();
  }
  if (n0 < DIN + CONVDIM) {
    // bounce each 64-row half through LDS, then full-line stores (4 thr/row x 32 shorts = 128)
    #pragma unroll
    for (int mi=0;mi<2;mi++){
      if (mi) __syncthreads();
      #pragma unroll
      for (int nj=0;nj<8;nj++){
        const int col = nj*16 + l16;
        #pragma unroll
        for (int r=0;r<4;r++){
          const int er = w*16 + q*4 + r;
          Ep[er*136 + col] = f2bf(acc[mi][nj][r]);
        }
      }
      __syncthreads();
      {
        const int er2 = tid >> 2, seg = tid & 3;
        const long grow = m0 + (er2>>4)*32 + mi*16 + (er2&15);
        const u64* s = (const u64*)(Ep + er2*136 + seg*32);
        u64 v0=s[0], v1=s[1], v2=s[2], v3=s[3], v4=s[4], v5=s[5], v6=s[6], v7=s[7];
        u64* dptr;
        if (n0 < DIN) dptr = (u64*)(zbuf + grow*DIN + n0 + seg*32);
        else          dptr = (u64*)(xbc + grow*CONVDIM + (n0 - DIN) + seg*32);
        dptr[0]=v0; dptr[1]=v1; dptr[2]=v2; dptr[3]=v3;
        dptr[4]=v4; dptr[5]=v5; dptr[6]=v6; dptr[7]=v7;
      }
    }
  } else {
    // dt tile: only cols 1152..1159 valid
    #pragma unroll
    for (int mi=0;mi<2;mi++){
      #pragma unroll
      for (int nj=0;nj<8;nj++){
        const int col = n0 + nj*16 + l16;
        if (col < DPROJ) {
          const int hh = col - (DIN + CONVDIM);
          #pragma unroll
          for (int r=0;r<4;r++){
            const long row = m0 + w*32 + mi*16 + q*4 + r;
            const float dv = acc[mi][nj][r] + dt_bias[hh];
            const float sp = dv > 20.f ? dv : log1pf(expf(dv));
            dtb[row*NH + hh] = sp;
            lab[row*NH + hh] = sp * (-expf(A_log[hh]));   // log dA
          }
        }
      }
    }
  }
}

// ---------------- out_proj 128x256 tile + residual + LayerNorm fused; writes h fp32 + hb bf16 ----------------
// 512 threads, 8 waves: wave row-group (w>>1)*32, col-group (w&1)*128.
__global__ __launch_bounds__(512) void outproj_fused(const u16* __restrict__ gb,
    const u16* __restrict__ Wt, float* __restrict__ h, u16* __restrict__ hb,
    const float* __restrict__ lnw, const float* __restrict__ lnb)
{
  __shared__ __align__(16) u16 Asl[128*36];
  __shared__ __align__(16) u16 Bsl[256*36];
  __shared__ float red[128][2][2];     // [row][colgroup][sum, sumsq]
  const int tid = threadIdx.x;
  const long m0 = (long)blockIdx.x * 128;
  const int w = tid >> 6, lane = tid & 63;
  const int q = lane >> 4, l16 = lane & 15;
  const int wr = (w >> 1) * 32;        // wave row base (0/32/64/96)
  const int wc = (w & 1) * 128;        // wave col base (0/128)
  const int srow = tid >> 1, sseg = tid & 1;   // B staging: 256 rows x 2 segs
  f32x4 acc[2][8] = {{{0.f,0.f,0.f,0.f}}};
  for (int kk = 0; kk < 16; ++kk) {
    const int k0 = kk*32;
    if (tid < 256) {   // A staging: 128 rows x 2 segs
      const u64* s = (const u64*)(gb + (m0 + srow)*DIN + k0 + sseg*16);
      u64 a=s[0], b=s[1], c=s[2], d=s[3];
      u64* dst = (u64*)(&Asl[srow*36 + sseg*16]);
      dst[0]=a; dst[1]=b; dst[2]=c; dst[3]=d;
    }
    {
      const u64* s = (const u64*)(Wt + (long)srow*DIN + k0 + sseg*16);
      u64 a=s[0], b=s[1], c=s[2], d=s[3];
      u64* dst = (u64*)(&Bsl[srow*36 + sseg*16]);
      dst[0]=a; dst[1]=b; dst[2]=c; dst[3]=d;
    }
    __syncthreads();
    bf16x8 af[2], bfr[8];
    #pragma unroll
    for (int mi=0;mi<2;mi++) af[mi] = ldfrag(&Asl[(wr + mi*16 + l16)*36 + q*8]);
    #pragma unroll
    for (int nj=0;nj<8;nj++) bfr[nj] = ldfrag(&Bsl[(wc + nj*16 + l16)*36 + q*8]);
    #pragma unroll
    for (int mi=0;mi<2;mi++)
      #pragma unroll
      for (int nj=0;nj<8;nj++)
        acc[mi][nj] = __builtin_amdgcn_mfma_f32_16x16x32_bf16(af[mi], bfr[nj], acc[mi][nj], 0,0,0);
    __syncthreads();
  }
  // o = acc + resid ; per-row stats via 16-lane shuffle + LDS combine across the 2 col-waves
  #pragma unroll
  for (int mi=0;mi<2;mi++){
    #pragma unroll
    for (int r=0;r<4;r++){
      const int lrow = wr + mi*16 + q*4 + r;
      float s = 0.f, ss = 0.f;
      #pragma unroll
      for (int nj=0;nj<8;nj++){
        const int col = wc + nj*16 + l16;
        const float o = acc[mi][nj][r] + h[(m0+lrow)*DMODEL + col];
        acc[mi][nj][r] = o;
        s += o; ss += o*o;
      }
      #pragma unroll
      for (int o2=1;o2<16;o2<<=1){ s += __shfl_xor(s,o2); ss += __shfl_xor(ss,o2); }
      if (l16 == 0) { red[lrow][w&1][0] = s; red[lrow][w&1][1] = ss; }
    }
  }
  __syncthreads();
  #pragma unroll
  for (int mi=0;mi<2;mi++){
    #pragma unroll
    for (int r=0;r<4;r++){
      const int lrow = wr + mi*16 + q*4 + r;
      const float S  = red[lrow][0][0] + red[lrow][1][0];
      const float SS = red[lrow][0][1] + red[lrow][1][1];
      const float mu = S * (1.f/256.f);
      const float var = SS * (1.f/256.f) - mu*mu;
      const float rs = rsqrtf(var + 1e-5f);
      #pragma unroll
      for (int nj=0;nj<8;nj++){
        const int col = wc + nj*16 + l16;
        const float v = (acc[mi][nj][r] - mu)*rs*lnw[col] + lnb[col];
        h [(m0+lrow)*DMODEL + col] = v;
        hb[(m0+lrow)*DMODEL + col] = f2bf(v);
      }
    }
  }
}

// ---------------- depthwise causal conv + SiLU: strip kernel ----------------
__global__ __launch_bounds__(256) void conv_kernel(const u16* __restrict__ xbc,
    const float* __restrict__ cw, const float* __restrict__ cb,
    u16* __restrict__ xsx, u16* __restrict__ Bb, u16* __restrict__ Cb)
{
  const long idx = (long)blockIdx.x * 256 + threadIdx.x;   // Mb*20 threads
  const int c4 = (int)(idx % 160) * 4;
  const long bt0 = (idx / 160) * 8;          // strip start (strips never cross batch)
  const int tseq = (int)(bt0 & (SEQ-1));
  const float4 b4 = *(const float4*)(cb + c4);
  const float4 w0v = *(const float4*)(cw + (c4+0)*4);
  const float4 w1v = *(const float4*)(cw + (c4+1)*4);
  const float4 w2v = *(const float4*)(cw + (c4+2)*4);
  const float4 w3v = *(const float4*)(cw + (c4+3)*4);
  const float W0[4] = {w0v.x,w0v.y,w0v.z,w0v.w};
  const float W1[4] = {w1v.x,w1v.y,w1v.z,w1v.w};
  const float W2[4] = {w2v.x,w2v.y,w2v.z,w2v.w};
  const float W3[4] = {w3v.x,w3v.y,w3v.z,w3v.w};
  float i0[11], i1[11], i2[11], i3[11];
  #pragma unroll
  for (int k = 0; k < 11; ++k) {
    u64 v = 0;
    if (tseq - 3 + k >= 0) v = *(const u64*)(xbc + (bt0 - 3 + k)*CONVDIM + c4);
    i0[k]=bf2f((u16)v); i1[k]=bf2f((u16)(v>>16)); i2[k]=bf2f((u16)(v>>32)); i3[k]=bf2f((u16)(v>>48));
  }
  u16* dst; long base; int stride;
  if (c4 < DIN)              { dst = xsx; base = bt0*DIN + c4;              stride = DIN; }
  else if (c4 < DIN+DSTATE)  { dst = Bb;  base = bt0*DSTATE + (c4-DIN);     stride = DSTATE; }
  else                       { dst = Cb;  base = bt0*DSTATE + (c4-DIN-DSTATE); stride = DSTATE; }
  #pragma unroll
  for (int j = 0; j < 8; ++j) {
    float a0=b4.x, a1=b4.y, a2=b4.z, a3=b4.w;
    #pragma unroll
    for (int k = 0; k < 4; ++k) {
      a0 += W0[k]*i0[j+k]; a1 += W1[k]*i1[j+k];
      a2 += W2[k]*i2[j+k]; a3 += W3[k]*i3[j+k];
    }
    a0=siluf(a0); a1=siluf(a1); a2=siluf(a2); a3=siluf(a3);
    const u64 r = (u64)f2bf(a0) | ((u64)f2bf(a1)<<16) | ((u64)f2bf(a2)<<32) | ((u64)f2bf(a3)<<48);
    *(u64*)(dst + base + (long)j*stride) = r;
  }
}

// ---------------- SSD phase A: per chunk-head local state via MFMA; Sloc bf16 ----------------
__global__ __launch_bounds__(256) void scanS_kernel(const u16* __restrict__ xsx,
    const u16* __restrict__ Bb, const float* __restrict__ lab, const float* __restrict__ dtb,
    u16* __restrict__ Sloc, float* __restrict__ Pb)
{
  __shared__ __align__(16) u16 Btr[64*STR128];   // [n][s]
  __shared__ __align__(16) u16 Uw[64*STR128];    // [p][s]
  __shared__ float cexpL[128];
  const int wg = blockIdx.x;
  const int c = wg & (NCHUNK-1), bh = wg >> 5, hh = bh & (NH-1), b = bh >> 3;
  const int tid = threadIdx.x;
  const long bt0 = (long)b*SEQ + c*CLEN;
  if (tid < 64) {   // wave 0: inclusive prefix of log dA over 128 steps
    float a0 = lab[(bt0+tid)*NH + hh];
    float a1 = lab[(bt0+64+tid)*NH + hh];
    const float d0 = dtb[(bt0+tid)*NH + hh];
    const float d1 = dtb[(bt0+64+tid)*NH + hh];
    #pragma unroll
    for (int o=1;o<64;o<<=1){
      const float t0=__shfl_up(a0,o), t1=__shfl_up(a1,o);
      if (tid>=o){a0+=t0;a1+=t1;}
    }
    a1 += __shfl(a0,63);
    const float ctot = __shfl(a1,63);
    cexpL[tid]    = d0*__expf(ctot - a0);
    cexpL[tid+64] = d1*__expf(ctot - a1);
    if (tid==0) Pb[wg] = __expf(ctot);
  }
  __syncthreads();
  {
    const int v = tid & 63, r0 = tid >> 6;
    #pragma unroll 4
    for (int k=0;k<32;k++){
      const int s = r0 + k*4;
      Btr[v*STR128 + s] = Bb[(bt0+s)*DSTATE + v];
      Uw[v*STR128 + s]  = f2bf(cexpL[s]*bf2f(xsx[(bt0+s)*DIN + hh*HD + v]));
    }
  }
  __syncthreads();
  const int w = tid>>6, lane = tid&63, q = lane>>4, l16 = lane&15;
  f32x4 acc[4] = {};
  #pragma unroll
  for (int ks=0;ks<4;ks++){
    const bf16x8 af = ldfrag(&Uw[(w*16+l16)*STR128 + ks*32 + q*8]);
    #pragma unroll
    for (int nj=0;nj<4;nj++){
      const bf16x8 bf = ldfrag(&Btr[(nj*16+l16)*STR128 + ks*32 + q*8]);
      acc[nj] = __builtin_amdgcn_mfma_f32_16x16x32_bf16(af, bf, acc[nj], 0,0,0);
    }
  }
  const long sb = (long)wg*4096;   // [wg][p][n] bf16
  #pragma unroll
  for (int nj=0;nj<4;nj++)
    #pragma unroll
    for (int r=0;r<4;r++)
      Sloc[sb + (w*16+q*4+r)*64 + nj*16 + l16] = f2bf(acc[nj][r]);
}

// Parallel combine over bf16 Sloc: run stays fp32 in registers
__global__ __launch_bounds__(64) void scanMid_kernel(u16* __restrict__ Sloc, const float* __restrict__ Pb)
{
  const int bh = blockIdx.x;
  const int rr = blockIdx.y;
  const int p  = threadIdx.x;
  float run = 0.f;
  for (int c = 0; c < NCHUNK; ++c) {
    const long base = ((long)(bh*NCHUNK + c))*4096 + rr*64 + p;
    const float Pc = Pb[bh*NCHUNK + c];
    const float tmp = bf2f(Sloc[base]);
    Sloc[base] = f2bf(run);
    run = run*Pc + tmp;
  }
}

// ---------------- SSD phase C: Y = ((C Bt) o L) U + diag(exp(cum)) (C h0) + D*x ; coalesced y out ----------------
__global__ __launch_bounds__(512) void scanY_kernel(const u16* __restrict__ xsx,
    u16* __restrict__ yg, const u16* __restrict__ Bb, const u16* __restrict__ Cb,
    const float* __restrict__ lab, const float* __restrict__ dtb,
    const u16* __restrict__ Sinit, const float* __restrict__ Dp)
{
  __shared__ __align__(16) u16 pool[2*128*STR64];  // Bs | Cs; overlaid by Ms[t][s]; then by y-bounce
  __shared__ __align__(16) u16 Ut[64*STR128];      // [p][s]
  __shared__ __align__(16) u16 h0t[64*STR64];      // [p][n]
  __shared__ float cumL[128];
  __shared__ float dtL[128];
  u16* Bs = pool;
  u16* Cs = pool + 128*STR64;
  u16* Ms = pool;

  const int wg = blockIdx.x;
  const int c = wg & (NCHUNK-1), bh = wg >> 5, hh = bh & (NH-1), b = bh >> 3;
  const int tid = threadIdx.x;
  const long bt0 = (long)b*SEQ + c*CLEN;

  if (tid < 64) {
    float a0 = lab[(bt0+tid)*NH + hh];
    float a1 = lab[(bt0+64+tid)*NH + hh];
    dtL[tid]    = dtb[(bt0+tid)*NH + hh];
    dtL[tid+64] = dtb[(bt0+64+tid)*NH + hh];
    #pragma unroll
    for (int o=1;o<64;o<<=1){
      const float t0=__shfl_up(a0,o), t1=__shfl_up(a1,o);
      if (tid>=o){a0+=t0;a1+=t1;}
    }
    a1 += __shfl(a0,63);
    cumL[tid]=a0; cumL[tid+64]=a1;
  }
  __syncthreads();
  {
    const int n = tid & 63, r0 = tid >> 6;   // 512 threads: r0 in 0..7
    #pragma unroll 4
    for (int k=0;k<16;k++){
      const int s = r0 + k*8;
      Bs[s*STR64 + n] = Bb[(bt0+s)*DSTATE + n];
      Cs[s*STR64 + n] = Cb[(bt0+s)*DSTATE + n];
      Ut[n*STR128 + s] = f2bf(dtL[s]*bf2f(xsx[(bt0+s)*DIN + hh*HD + n]));
    }
    const int n0 = r0*8;
    // h0 already bf16: 8 states = 16 B = TWO u64 copies (8-B aligned)
    const u64* sp = (const u64*)(Sinit + (long)wg*4096 + n*64 + n0);
    u64* dp = (u64*)(h0t + n*STR64 + n0);
    dp[0] = sp[0]; dp[1] = sp[1];
  }
  __syncthreads();

  const int w = tid>>6, lane = tid&63, q = lane>>4, l16 = lane&15;
  f32x4 accG[8] = {};
  f32x4 accI[4] = {};
  #pragma unroll
  for (int ks=0;ks<2;ks++){
    const bf16x8 af = ldfrag(&Cs[(w*16+l16)*STR64 + ks*32 + q*8]);
    #pragma unroll
    for (int nj=0;nj<8;nj++)
      accG[nj] = __builtin_amdgcn_mfma_f32_16x16x32_bf16(af, ldfrag(&Bs[(nj*16+l16)*STR64 + ks*32 + q*8]), accG[nj], 0,0,0);
    #pragma unroll
    for (int nj=0;nj<4;nj++)
      accI[nj] = __builtin_amdgcn_mfma_f32_16x16x32_bf16(af, ldfrag(&h0t[(nj*16+l16)*STR64 + ks*32 + q*8]), accI[nj], 0,0,0);
  }
  __syncthreads();
  #pragma unroll
  for (int nj=0;nj<8;nj++){
    const int s = nj*16 + l16;
    #pragma unroll
    for (int r=0;r<4;r++){
      const int t = w*16 + q*4 + r;
      const float v = (s<=t) ? accG[nj][r]*__expf(cumL[t]-cumL[s]) : 0.f;
      Ms[t*STR128 + s] = f2bf(v);
    }
  }
  __syncthreads();
  f32x4 accY[4] = {};
  #pragma unroll
  for (int ks=0;ks<4;ks++){
    const bf16x8 af = ldfrag(&Ms[(w*16+l16)*STR128 + ks*32 + q*8]);
    #pragma unroll
    for (int nj=0;nj<4;nj++)
      accY[nj] = __builtin_amdgcn_mfma_f32_16x16x32_bf16(af, ldfrag(&Ut[(nj*16+l16)*STR128 + ks*32 + q*8]), accY[nj], 0,0,0);
  }
  const float Dv = Dp[hh];
  __syncthreads();   // Ms reads done; reuse pool as y-bounce [128][68]
  #pragma unroll
  for (int nj=0;nj<4;nj++){
    const int p = nj*16 + l16;
    #pragma unroll
    for (int r=0;r<4;r++){
      const int t = w*16 + q*4 + r;
      const float xv = bf2f(xsx[(bt0+t)*DIN + hh*HD + p]);
      pool[t*STR64 + p] = f2bf(accY[nj][r] + __expf(cumL[t])*accI[nj][r] + Dv*xv);
    }
  }
  __syncthreads();
  {
    const int row = tid >> 2, seg = tid & 3;
    const u64* s = (const u64*)(pool + row*STR64 + seg*16);
    u64 a=s[0], b2=s[1], c2=s[2], d=s[3];
    u64* dptr = (u64*)(yg + (bt0+row)*DIN + hh*HD + seg*16);
    dptr[0]=a; dptr[1]=b2; dptr[2]=c2; dptr[3]=d;
  }
}

// ---------------- y*silu(z) + RMSNorm; bf16 in, bf16 out in place ----------------
__global__ __launch_bounds__(256) void gnorm_kernel(u16* __restrict__ y_io,
    const u16* __restrict__ zb, const float* __restrict__ nw)
{
  const long row = blockIdx.x;
  const int tid = threadIdx.x;
  float g[2];
  #pragma unroll
  for (int q=0;q<2;q++){
    const int cc = tid + q*256;
    const float yv = bf2f(y_io[row*DIN + cc]);
    const float zv = bf2f(zb[row*DIN + cc]);
    g[q] = yv * siluf(zv);
  }
  float ss = g[0]*g[0] + g[1]*g[1];
  #pragma unroll
  for (int o=32;o;o>>=1) ss += __shfl_down(ss, o);
  __shared__ float red[4];
  if ((tid & 63) == 0) red[tid>>6] = ss;
  __syncthreads();
  const float tot = red[0]+red[1]+red[2]+red[3];
  const float scale = rsqrtf(tot * (1.f/512.f) + 1e-5f);
  #pragma unroll
  for (int q=0;q<2;q++){
    const int cc = tid + q*256;
    y_io[row*DIN + cc] = f2bf(g[q] * scale * nw[cc]);
  }
}

// ---------------- decoder (fp32 output) ----------------
__global__ __launch_bounds__(64) void dec_kernel(const float* __restrict__ h,
    const float* __restrict__ W, const float* __restrict__ bias, float* __restrict__ out)
{
  const int wg = blockIdx.x;
  const int b = wg / 10, o = wg % 10;
  const int lane = threadIdx.x;
  const float* r = h + ((long)b*SEQ + SEQ-1)*DMODEL;
  float s = 0.f;
  #pragma unroll
  for (int q=0;q<4;q++){ const int k = lane + q*64; s += r[k]*W[k*10+o]; }
  #pragma unroll
  for (int o2=32;o2;o2>>=1) s += __shfl_down(s, o2);
  if (lane == 0) out[wg] = s + bias[o];
}

extern "C" void kernel_launch(void* const* d_in, const int* in_sizes, int n_in,
                              void* d_out, int out_size, void* d_ws, size_t ws_size,
                              hipStream_t stream) {
  const float* x        = (const float*)d_in[0];
  const float* enc_w    = (const float*)d_in[1];
  const float* enc_b    = (const float*)d_in[2];
  const float* in_proj  = (const float*)d_in[3];
  const float* conv_w   = (const float*)d_in[4];
  const float* conv_b   = (const float*)d_in[5];
  const float* dt_bias  = (const float*)d_in[6];
  const float* A_log    = (const float*)d_in[7];
  const float* Dp       = (const float*)d_in[8];
  const float* norm_w   = (const float*)d_in[9];
  const float* out_proj = (const float*)d_in[10];
  const float* ln_w     = (const float*)d_in[11];
  const float* ln_b     = (const float*)d_in[12];
  const float* dec_w    = (const float*)d_in[13];
  const float* dec_b    = (const float*)d_in[14];
  float* out = (float*)d_out;

  float* ws = (float*)d_ws;
  u16* WtIn  = (u16*)ws;                       // 2*NPAD*256 shorts = 655360
  u16* WtOut = WtIn + (long)2*NPAD*DMODEL;     // 2*256*512 shorts = 262144
  float* gbase = ws + 327680 + 131072;         // = ws + 458752 floats

  // Per-token fp32-equivalents: h 256 + hb 128 + z 256 + xbc 320 + xsx 256 + yg 256
  //                             + Bb 32 + Cb 32 + dtb 8 + lab 8 = 1552
  int NB = 8;
  while (NB > 1) {
    const long Mb = (long)NB * SEQ;
    const long bytes = (458752L + Mb * 1552L + 4096) * 4;
    if ((size_t)bytes <= ws_size) break;
    NB >>= 1;
  }
  const long Mb = (long)NB * SEQ;

  float* h    = gbase;                    // Mb*256 f
  u16*   hb   = (u16*)(h + Mb*DMODEL);    // Mb*256 u16
  u16*   zbuf = hb + Mb*DMODEL;           // Mb*512 u16
  u16*   xbc  = zbuf + Mb*DIN;            // Mb*640 u16 ; aliased by Sloc (Mb*256 u16)
  u16*   xsx  = xbc + Mb*CONVDIM;         // Mb*512 u16
  u16*   yg   = xsx + Mb*DIN;             // Mb*512 u16 (y, then g in place)
  u16*   Bb   = yg + Mb*DIN;              // Mb*64 u16
  u16*   Cb   = Bb + Mb*DSTATE;           // Mb*64 u16
  float* dtb  = (float*)(Cb + Mb*DSTATE); // Mb*8 f
  float* lab  = dtb + Mb*NH;              // Mb*8 f (log dA)
  float* Pb   = lab + Mb*NH;              // <= 2048
  u16*   Sloc = xbc;                      // alias: xbc dead after conv; Mb*256 u16

  cvt_inw <<<dim3(2*NPAD),   dim3(256), 0, stream>>>(in_proj,  WtIn);
  cvt_outw<<<dim3(2*DMODEL), dim3(256), 0, stream>>>(out_proj, WtOut);

  const int ngroups = B_SZ / NB;
  for (int g = 0; g < ngroups; ++g) {
    const float* xg = x + (long)g*NB*SEQ*64;

    enc_kernel<<<dim3((int)(Mb/32)), dim3(256), 0, stream>>>(xg, enc_w, enc_b, h, hb);

    for (int l = 0; l < 2; ++l) {
      inproj_mfma<<<dim3((int)(Mb/128), NPAD/128), dim3(256), 0, stream>>>(
          hb, WtIn + (long)l*NPAD*DMODEL, zbuf, xbc, dtb, lab,
          dt_bias + l*NH, A_log + l*NH);
      conv_kernel<<<dim3((int)(Mb*20/256)), dim3(256), 0, stream>>>(
          xbc, conv_w + (long)l*CONVDIM*4, conv_b + (long)l*CONVDIM, xsx, Bb, Cb);
      scanS_kernel<<<dim3(NB*8*NCHUNK), dim3(256), 0, stream>>>(xsx, Bb, lab, dtb, Sloc, Pb);
      scanMid_kernel<<<dim3(NB*8, 64), dim3(64), 0, stream>>>(Sloc, Pb);
      scanY_kernel<<<dim3(NB*8*NCHUNK), dim3(512), 0, stream>>>(xsx, yg, Bb, Cb, lab, dtb, Sloc, Dp + l*NH);
      gnorm_kernel<<<dim3((int)Mb), dim3(256), 0, stream>>>(yg, zbuf, norm_w + (long)l*DIN);
      outproj_fused<<<dim3((int)(Mb/128)), dim3(512), 0, stream>>>(
          yg, WtOut + (long)l*DMODEL*DIN, h, hb, ln_w + l*DMODEL, ln_b + l*DMODEL);
    }

    dec_kernel<<<dim3(NB*10), dim3(64), 0, stream>>>(h, dec_w, dec_b, out + (long)g*NB*10);
  }
}

// Round 16
// 511.686 us; speedup vs baseline: 1.4090x; 1.0310x over previous
//
#include <hip/hip_runtime.h>
#include <hip/hip_bf16.h>
#include <math.h>

// ---- model constants ----
#define B_SZ    8
#define SEQ     4096
#define DMODEL  256
#define DIN     512     // d_inner
#define DSTATE  64
#define NH      8
#define HD      64
#define CONVDIM 640
#define DPROJ   1160
#define NPAD    1280    // DPROJ padded to 10*128
#define NCHUNK  32      // scan chunks per (b,h)
#define CLEN    128     // SEQ / NCHUNK
#define STR64   68      // LDS row stride (shorts) for K=64 tiles
#define STR128  132     // LDS row stride (shorts) for K=128 tiles
#define EPSTR   140     // epilogue bounce stride (70*8 % 32 != 0: kills quad-set conflicts)

typedef unsigned long long u64;
typedef unsigned int u32;
typedef unsigned short u16;
typedef __attribute__((ext_vector_type(8))) short bf16x8;
typedef __attribute__((ext_vector_type(4))) float f32x4;

__device__ __forceinline__ float siluf(float v){ return v / (1.f + expf(-v)); }
__device__ __forceinline__ u16 f2bf(float f){ __hip_bfloat16 h = __float2bfloat16(f); return *(u16*)&h; }
__device__ __forceinline__ float bf2f(u16 u){ union{u32 i; float f;} t; t.i = ((u32)u)<<16; return t.f; }
__device__ __forceinline__ bf16x8 ldfrag(const u16* base){
  union { u64 u[2]; bf16x8 v; } t;
  const u64* p = (const u64*)base;
  t.u[0] = p[0]; t.u[1] = p[1];
  return t.v;
}

// ---------------- weight conversion (once per launch) ----------------
__global__ __launch_bounds__(256) void cvt_inw(const float* __restrict__ W, u16* __restrict__ Wt)
{
  const int blk = blockIdx.x;
  const int l = blk / NPAD, n = blk % NPAD;
  const int k = threadIdx.x;
  float v = 0.f;
  if (n < DPROJ) v = W[((long)l*DMODEL + k)*DPROJ + n];
  Wt[((long)l*NPAD + n)*DMODEL + k] = f2bf(v);
}

__global__ __launch_bounds__(256) void cvt_outw(const float* __restrict__ W, u16* __restrict__ Wt)
{
  const int blk = blockIdx.x;
  const int l = blk / DMODEL, n = blk % DMODEL;
  #pragma unroll
  for (int q = 0; q < 2; ++q) {
    const int k = threadIdx.x + q*256;
    const float v = W[((long)l*DIN + k)*DMODEL + n];
    Wt[((long)l*DMODEL + n)*DIN + k] = f2bf(v);
  }
}

// ---------------- encoder GEMM; writes hb bf16 ----------------
__global__ __launch_bounds__(256) void enc_kernel(const float* __restrict__ x,
    const float* __restrict__ W, const float* __restrict__ bias, u16* __restrict__ hb)
{
  __shared__ float xl[32*64];
  const int tid = threadIdx.x;
  const long t0 = (long)blockIdx.x * 32;
  for (int i = tid; i < 32*64; i += 256) xl[i] = x[t0*64 + i];
  __syncthreads();
  float acc[32];
  const float bv = bias[tid];
  #pragma unroll
  for (int tok = 0; tok < 32; ++tok) acc[tok] = bv;
  for (int k = 0; k < 64; ++k) {
    const float wv = W[k*DMODEL + tid];
    #pragma unroll
    for (int tok = 0; tok < 32; ++tok) acc[tok] += xl[tok*64 + k] * wv;
  }
  #pragma unroll
  for (int tok = 0; tok < 32; ++tok)
    hb[(t0 + tok)*DMODEL + tid] = f2bf(acc[tok]);
}

// ---------------- in_proj MFMA GEMM 128x128 tile, BK=32 ----------------
__global__ __launch_bounds__(256) void inproj_mfma(const u16* __restrict__ hb,
    const u16* __restrict__ Wt, u16* __restrict__ zbuf, u16* __restrict__ xbc,
    float* __restrict__ dtb, float* __restrict__ lab,
    const float* __restrict__ dt_bias, const float* __restrict__ A_log)
{
  __shared__ __align__(16) u16 pool[128*36*2];   // staging Asl|Bsl; epilogue bounce aliases it
  u16* Asl = pool;
  u16* Bsl = pool + 128*36;
  u16* Ep  = pool;                               // [64][EPSTR] u16 per mi-half (8960 <= 9216)
  const int tid = threadIdx.x;
  const long m0 = (long)blockIdx.x * 128;
  const int n0 = blockIdx.y * 128;
  const int w = tid >> 6, lane = tid & 63;
  const int q = lane >> 4, l16 = lane & 15;
  const int srow = tid >> 1, sseg = tid & 1;   // 2 lanes/row, 16 shorts (32 B) each
  f32x4 acc[2][8] = {{{0.f,0.f,0.f,0.f}}};
  for (int k0 = 0; k0 < DMODEL; k0 += 32) {
    {
      const u64* s = (const u64*)(hb + (m0 + srow)*DMODEL + k0 + sseg*16);
      u64 a=s[0], b=s[1], c=s[2], d=s[3];
      u64* dst = (u64*)(&Asl[srow*36 + sseg*16]);
      dst[0]=a; dst[1]=b; dst[2]=c; dst[3]=d;
    }
    {
      const u64* s = (const u64*)(Wt + (long)(n0 + srow)*DMODEL + k0 + sseg*16);
      u64 a=s[0], b=s[1], c=s[2], d=s[3];
      u64* dst = (u64*)(&Bsl[srow*36 + sseg*16]);
      dst[0]=a; dst[1]=b; dst[2]=c; dst[3]=d;
    }
    __syncthreads();
    bf16x8 af[2], bfr[8];
    #pragma unroll
    for (int mi=0;mi<2;mi++) af[mi] = ldfrag(&Asl[(w*32 + mi*16 + l16)*36 + q*8]);
    #pragma unroll
    for (int nj=0;nj<8;nj++) bfr[nj] = ldfrag(&Bsl[(nj*16 + l16)*36 + q*8]);
    #pragma unroll
    for (int mi=0;mi<2;mi++)
      #pragma unroll
      for (int nj=0;nj<8;nj++)
        acc[mi][nj] = __builtin_amdgcn_mfma_f32_16x16x32_bf16(af[mi], bfr[nj], acc[mi][nj], 0,0,0);
    __syncthreads();
  }
  if (n0 < DIN + CONVDIM) {
    // bounce each 64-row half through LDS, then full-line stores (4 thr/row x 32 shorts = 128)
    #pragma unroll
    for (int mi=0;mi<2;mi++){
      if (mi) __syncthreads();
      #pragma unroll
      for (int nj=0;nj<8;nj++){
        const int col = nj*16 + l16;
        #pragma unroll
        for (int r=0;r<4;r++){
          const int er = w*16 + q*4 + r;
          Ep[er*EPSTR + col] = f2bf(acc[mi][nj][r]);
        }
      }
      __syncthreads();
      {
        const int er2 = tid >> 2, seg = tid & 3;
        const long grow = m0 + (er2>>4)*32 + mi*16 + (er2&15);
        const u64* s = (const u64*)(Ep + er2*EPSTR + seg*32);
        u64 v0=s[0], v1=s[1], v2=s[2], v3=s[3], v4=s[4], v5=s[5], v6=s[6], v7=s[7];
        u64* dptr;
        if (n0 < DIN) dptr = (u64*)(zbuf + grow*DIN + n0 + seg*32);
        else          dptr = (u64*)(xbc + grow*CONVDIM + (n0 - DIN) + seg*32);
        dptr[0]=v0; dptr[1]=v1; dptr[2]=v2; dptr[3]=v3;
        dptr[4]=v4; dptr[5]=v5; dptr[6]=v6; dptr[7]=v7;
      }
    }
  } else {
    // dt tile: only cols 1152..1159 valid
    #pragma unroll
    for (int mi=0;mi<2;mi++){
      #pragma unroll
      for (int nj=0;nj<8;nj++){
        const int col = n0 + nj*16 + l16;
        if (col < DPROJ) {
          const int hh = col - (DIN + CONVDIM);
          #pragma unroll
          for (int r=0;r<4;r++){
            const long row = m0 + w*32 + mi*16 + q*4 + r;
            const float dv = acc[mi][nj][r] + dt_bias[hh];
            const float sp = dv > 20.f ? dv : log1pf(expf(dv));
            dtb[row*NH + hh] = sp;
            lab[row*NH + hh] = sp * (-expf(A_log[hh]));   // log dA
          }
        }
      }
    }
  }
}

// ---------------- out_proj 128x256 tile + residual + LayerNorm fused; hb bf16 in/out ----------------
// 512 threads, 8 waves: wave row-group (w>>1)*32, col-group (w&1)*128.
__global__ __launch_bounds__(512) void outproj_fused(const u16* __restrict__ gb,
    const u16* __restrict__ Wt, u16* __restrict__ hb,
    const float* __restrict__ lnw, const float* __restrict__ lnb)
{
  __shared__ __align__(16) u16 Asl[128*36];
  __shared__ __align__(16) u16 Bsl[256*36];
  __shared__ float red[128][2][2];     // [row][colgroup][sum, sumsq]
  const int tid = threadIdx.x;
  const long m0 = (long)blockIdx.x * 128;
  const int w = tid >> 6, lane = tid & 63;
  const int q = lane >> 4, l16 = lane & 15;
  const int wr = (w >> 1) * 32;        // wave row base (0/32/64/96)
  const int wc = (w & 1) * 128;        // wave col base (0/128)
  const int srow = tid >> 1, sseg = tid & 1;   // B staging: 256 rows x 2 segs
  f32x4 acc[2][8] = {{{0.f,0.f,0.f,0.f}}};
  for (int kk = 0; kk < 16; ++kk) {
    const int k0 = kk*32;
    if (tid < 256) {   // A staging: 128 rows x 2 segs
      const u64* s = (const u64*)(gb + (m0 + srow)*DIN + k0 + sseg*16);
      u64 a=s[0], b=s[1], c=s[2], d=s[3];
      u64* dst = (u64*)(&Asl[srow*36 + sseg*16]);
      dst[0]=a; dst[1]=b; dst[2]=c; dst[3]=d;
    }
    {
      const u64* s = (const u64*)(Wt + (long)srow*DIN + k0 + sseg*16);
      u64 a=s[0], b=s[1], c=s[2], d=s[3];
      u64* dst = (u64*)(&Bsl[srow*36 + sseg*16]);
      dst[0]=a; dst[1]=b; dst[2]=c; dst[3]=d;
    }
    __syncthreads();
    bf16x8 af[2], bfr[8];
    #pragma unroll
    for (int mi=0;mi<2;mi++) af[mi] = ldfrag(&Asl[(wr + mi*16 + l16)*36 + q*8]);
    #pragma unroll
    for (int nj=0;nj<8;nj++) bfr[nj] = ldfrag(&Bsl[(wc + nj*16 + l16)*36 + q*8]);
    #pragma unroll
    for (int mi=0;mi<2;mi++)
      #pragma unroll
      for (int nj=0;nj<8;nj++)
        acc[mi][nj] = __builtin_amdgcn_mfma_f32_16x16x32_bf16(af[mi], bfr[nj], acc[mi][nj], 0,0,0);
    __syncthreads();
  }
  // o = acc + resid(bf16) ; per-row stats via 16-lane shuffle + LDS combine across the 2 col-waves
  #pragma unroll
  for (int mi=0;mi<2;mi++){
    #pragma unroll
    for (int r=0;r<4;r++){
      const int lrow = wr + mi*16 + q*4 + r;
      float s = 0.f, ss = 0.f;
      #pragma unroll
      for (int nj=0;nj<8;nj++){
        const int col = wc + nj*16 + l16;
        const float o = acc[mi][nj][r] + bf2f(hb[(m0+lrow)*DMODEL + col]);
        acc[mi][nj][r] = o;
        s += o; ss += o*o;
      }
      #pragma unroll
      for (int o2=1;o2<16;o2<<=1){ s += __shfl_xor(s,o2); ss += __shfl_xor(ss,o2); }
      if (l16 == 0) { red[lrow][w&1][0] = s; red[lrow][w&1][1] = ss; }
    }
  }
  __syncthreads();
  #pragma unroll
  for (int mi=0;mi<2;mi++){
    #pragma unroll
    for (int r=0;r<4;r++){
      const int lrow = wr + mi*16 + q*4 + r;
      const float S  = red[lrow][0][0] + red[lrow][1][0];
      const float SS = red[lrow][0][1] + red[lrow][1][1];
      const float mu = S * (1.f/256.f);
      const float var = SS * (1.f/256.f) - mu*mu;
      const float rs = rsqrtf(var + 1e-5f);
      #pragma unroll
      for (int nj=0;nj<8;nj++){
        const int col = wc + nj*16 + l16;
        const float v = (acc[mi][nj][r] - mu)*rs*lnw[col] + lnb[col];
        hb[(m0+lrow)*DMODEL + col] = f2bf(v);
      }
    }
  }
}

// ---------------- depthwise causal conv + SiLU: strip kernel ----------------
__global__ __launch_bounds__(256) void conv_kernel(const u16* __restrict__ xbc,
    const float* __restrict__ cw, const float* __restrict__ cb,
    u16* __restrict__ xsx, u16* __restrict__ Bb, u16* __restrict__ Cb)
{
  const long idx = (long)blockIdx.x * 256 + threadIdx.x;   // Mb*20 threads
  const int c4 = (int)(idx % 160) * 4;
  const long bt0 = (idx / 160) * 8;          // strip start (strips never cross batch)
  const int tseq = (int)(bt0 & (SEQ-1));
  const float4 b4 = *(const float4*)(cb + c4);
  const float4 w0v = *(const float4*)(cw + (c4+0)*4);
  const float4 w1v = *(const float4*)(cw + (c4+1)*4);
  const float4 w2v = *(const float4*)(cw + (c4+2)*4);
  const float4 w3v = *(const float4*)(cw + (c4+3)*4);
  const float W0[4] = {w0v.x,w0v.y,w0v.z,w0v.w};
  const float W1[4] = {w1v.x,w1v.y,w1v.z,w1v.w};
  const float W2[4] = {w2v.x,w2v.y,w2v.z,w2v.w};
  const float W3[4] = {w3v.x,w3v.y,w3v.z,w3v.w};
  float i0[11], i1[11], i2[11], i3[11];
  #pragma unroll
  for (int k = 0; k < 11; ++k) {
    u64 v = 0;
    if (tseq - 3 + k >= 0) v = *(const u64*)(xbc + (bt0 - 3 + k)*CONVDIM + c4);
    i0[k]=bf2f((u16)v); i1[k]=bf2f((u16)(v>>16)); i2[k]=bf2f((u16)(v>>32)); i3[k]=bf2f((u16)(v>>48));
  }
  u16* dst; long base; int stride;
  if (c4 < DIN)              { dst = xsx; base = bt0*DIN + c4;              stride = DIN; }
  else if (c4 < DIN+DSTATE)  { dst = Bb;  base = bt0*DSTATE + (c4-DIN);     stride = DSTATE; }
  else                       { dst = Cb;  base = bt0*DSTATE + (c4-DIN-DSTATE); stride = DSTATE; }
  #pragma unroll
  for (int j = 0; j < 8; ++j) {
    float a0=b4.x, a1=b4.y, a2=b4.z, a3=b4.w;
    #pragma unroll
    for (int k = 0; k < 4; ++k) {
      a0 += W0[k]*i0[j+k]; a1 += W1[k]*i1[j+k];
      a2 += W2[k]*i2[j+k]; a3 += W3[k]*i3[j+k];
    }
    a0=siluf(a0); a1=siluf(a1); a2=siluf(a2); a3=siluf(a3);
    const u64 r = (u64)f2bf(a0) | ((u64)f2bf(a1)<<16) | ((u64)f2bf(a2)<<32) | ((u64)f2bf(a3)<<48);
    *(u64*)(dst + base + (long)j*stride) = r;
  }
}

// ---------------- SSD phase A: per chunk-head local state via MFMA; Sloc bf16 ----------------
__global__ __launch_bounds__(256) void scanS_kernel(const u16* __restrict__ xsx,
    const u16* __restrict__ Bb, const float* __restrict__ lab, const float* __restrict__ dtb,
    u16* __restrict__ Sloc, float* __restrict__ Pb)
{
  __shared__ __align__(16) u16 Btr[64*STR128];   // [n][s]
  __shared__ __align__(16) u16 Uw[64*STR128];    // [p][s]
  __shared__ float cexpL[128];
  const int wg = blockIdx.x;
  const int c = wg & (NCHUNK-1), bh = wg >> 5, hh = bh & (NH-1), b = bh >> 3;
  const int tid = threadIdx.x;
  const long bt0 = (long)b*SEQ + c*CLEN;
  if (tid < 64) {   // wave 0: inclusive prefix of log dA over 128 steps
    float a0 = lab[(bt0+tid)*NH + hh];
    float a1 = lab[(bt0+64+tid)*NH + hh];
    const float d0 = dtb[(bt0+tid)*NH + hh];
    const float d1 = dtb[(bt0+64+tid)*NH + hh];
    #pragma unroll
    for (int o=1;o<64;o<<=1){
      const float t0=__shfl_up(a0,o), t1=__shfl_up(a1,o);
      if (tid>=o){a0+=t0;a1+=t1;}
    }
    a1 += __shfl(a0,63);
    const float ctot = __shfl(a1,63);
    cexpL[tid]    = d0*__expf(ctot - a0);
    cexpL[tid+64] = d1*__expf(ctot - a1);
    if (tid==0) Pb[wg] = __expf(ctot);
  }
  __syncthreads();
  {
    const int v = tid & 63, r0 = tid >> 6;
    #pragma unroll 4
    for (int k=0;k<32;k++){
      const int s = r0 + k*4;
      Btr[v*STR128 + s] = Bb[(bt0+s)*DSTATE + v];
      Uw[v*STR128 + s]  = f2bf(cexpL[s]*bf2f(xsx[(bt0+s)*DIN + hh*HD + v]));
    }
  }
  __syncthreads();
  const int w = tid>>6, lane = tid&63, q = lane>>4, l16 = lane&15;
  f32x4 acc[4] = {};
  #pragma unroll
  for (int ks=0;ks<4;ks++){
    const bf16x8 af = ldfrag(&Uw[(w*16+l16)*STR128 + ks*32 + q*8]);
    #pragma unroll
    for (int nj=0;nj<4;nj++){
      const bf16x8 bf = ldfrag(&Btr[(nj*16+l16)*STR128 + ks*32 + q*8]);
      acc[nj] = __builtin_amdgcn_mfma_f32_16x16x32_bf16(af, bf, acc[nj], 0,0,0);
    }
  }
  const long sb = (long)wg*4096;   // [wg][p][n] bf16
  #pragma unroll
  for (int nj=0;nj<4;nj++)
    #pragma unroll
    for (int r=0;r<4;r++)
      Sloc[sb + (w*16+q*4+r)*64 + nj*16 + l16] = f2bf(acc[nj][r]);
}

// Parallel combine over bf16 Sloc: run stays fp32 in registers
__global__ __launch_bounds__(64) void scanMid_kernel(u16* __restrict__ Sloc, const float* __restrict__ Pb)
{
  const int bh = blockIdx.x;
  const int rr = blockIdx.y;
  const int p  = threadIdx.x;
  float run = 0.f;
  for (int c = 0; c < NCHUNK; ++c) {
    const long base = ((long)(bh*NCHUNK + c))*4096 + rr*64 + p;
    const float Pc = Pb[bh*NCHUNK + c];
    const float tmp = bf2f(Sloc[base]);
    Sloc[base] = f2bf(run);
    run = run*Pc + tmp;
  }
}

// ---------------- SSD phase C: Y = ((C Bt) o L) U + diag(exp(cum)) (C h0) + D*x ; coalesced y out ----------------
__global__ __launch_bounds__(512) void scanY_kernel(const u16* __restrict__ xsx,
    u16* __restrict__ yg, const u16* __restrict__ Bb, const u16* __restrict__ Cb,
    const float* __restrict__ lab, const float* __restrict__ dtb,
    const u16* __restrict__ Sinit, const float* __restrict__ Dp)
{
  __shared__ __align__(16) u16 pool[2*128*STR64];  // Bs | Cs; overlaid by Ms[t][s]; then by y-bounce
  __shared__ __align__(16) u16 Ut[64*STR128];      // [p][s]
  __shared__ __align__(16) u16 h0t[64*STR64];      // [p][n]
  __shared__ float cumL[128];
  __shared__ float dtL[128];
  u16* Bs = pool;
  u16* Cs = pool + 128*STR64;
  u16* Ms = pool;

  const int wg = blockIdx.x;
  const int c = wg & (NCHUNK-1), bh = wg >> 5, hh = bh & (NH-1), b = bh >> 3;
  const int tid = threadIdx.x;
  const long bt0 = (long)b*SEQ + c*CLEN;

  if (tid < 64) {
    float a0 = lab[(bt0+tid)*NH + hh];
    float a1 = lab[(bt0+64+tid)*NH + hh];
    dtL[tid]    = dtb[(bt0+tid)*NH + hh];
    dtL[tid+64] = dtb[(bt0+64+tid)*NH + hh];
    #pragma unroll
    for (int o=1;o<64;o<<=1){
      const float t0=__shfl_up(a0,o), t1=__shfl_up(a1,o);
      if (tid>=o){a0+=t0;a1+=t1;}
    }
    a1 += __shfl(a0,63);
    cumL[tid]=a0; cumL[tid+64]=a1;
  }
  __syncthreads();
  {
    const int n = tid & 63, r0 = tid >> 6;   // 512 threads: r0 in 0..7
    #pragma unroll 4
    for (int k=0;k<16;k++){
      const int s = r0 + k*8;
      Bs[s*STR64 + n] = Bb[(bt0+s)*DSTATE + n];
      Cs[s*STR64 + n] = Cb[(bt0+s)*DSTATE + n];
      Ut[n*STR128 + s] = f2bf(dtL[s]*bf2f(xsx[(bt0+s)*DIN + hh*HD + n]));
    }
    const int n0 = r0*8;
    // h0 bf16: 8 states = 16 B = two u64 copies
    const u64* sp = (const u64*)(Sinit + (long)wg*4096 + n*64 + n0);
    u64* dp = (u64*)(h0t + n*STR64 + n0);
    dp[0] = sp[0]; dp[1] = sp[1];
  }
  __syncthreads();

  const int w = tid>>6, lane = tid&63, q = lane>>4, l16 = lane&15;
  f32x4 accG[8] = {};
  f32x4 accI[4] = {};
  #pragma unroll
  for (int ks=0;ks<2;ks++){
    const bf16x8 af = ldfrag(&Cs[(w*16+l16)*STR64 + ks*32 + q*8]);
    #pragma unroll
    for (int nj=0;nj<8;nj++)
      accG[nj] = __builtin_amdgcn_mfma_f32_16x16x32_bf16(af, ldfrag(&Bs[(nj*16+l16)*STR64 + ks*32 + q*8]), accG[nj], 0,0,0);
    #pragma unroll
    for (int nj=0;nj<4;nj++)
      accI[nj] = __builtin_amdgcn_mfma_f32_16x16x32_bf16(af, ldfrag(&h0t[(nj*16+l16)*STR64 + ks*32 + q*8]), accI[nj], 0,0,0);
  }
  __syncthreads();
  #pragma unroll
  for (int nj=0;nj<8;nj++){
    const int s = nj*16 + l16;
    #pragma unroll
    for (int r=0;r<4;r++){
      const int t = w*16 + q*4 + r;
      const float v = (s<=t) ? accG[nj][r]*__expf(cumL[t]-cumL[s]) : 0.f;
      Ms[t*STR128 + s] = f2bf(v);
    }
  }
  __syncthreads();
  f32x4 accY[4] = {};
  #pragma unroll
  for (int ks=0;ks<4;ks++){
    const bf16x8 af = ldfrag(&Ms[(w*16+l16)*STR128 + ks*32 + q*8]);
    #pragma unroll
    for (int nj=0;nj<4;nj++)
      accY[nj] = __builtin_amdgcn_mfma_f32_16x16x32_bf16(af, ldfrag(&Ut[(nj*16+l16)*STR128 + ks*32 + q*8]), accY[nj], 0,0,0);
  }
  const float Dv = Dp[hh];
  __syncthreads();   // Ms reads done; reuse pool as y-bounce [128][STR64]
  #pragma unroll
  for (int nj=0;nj<4;nj++){
    const int p = nj*16 + l16;
    #pragma unroll
    for (int r=0;r<4;r++){
      const int t = w*16 + q*4 + r;
      const float xv = bf2f(xsx[(bt0+t)*DIN + hh*HD + p]);
      pool[t*STR64 + p] = f2bf(accY[nj][r] + __expf(cumL[t])*accI[nj][r] + Dv*xv);
    }
  }
  __syncthreads();
  {
    const int row = tid >> 2, seg = tid & 3;
    const u64* s = (const u64*)(pool + row*STR64 + seg*16);
    u64 a=s[0], b2=s[1], c2=s[2], d=s[3];
    u64* dptr = (u64*)(yg + (bt0+row)*DIN + hh*HD + seg*16);
    dptr[0]=a; dptr[1]=b2; dptr[2]=c2; dptr[3]=d;
  }
}

// ---------------- y*silu(z) + RMSNorm; bf16 in, bf16 out in place ----------------
__global__ __launch_bounds__(256) void gnorm_kernel(u16* __restrict__ y_io,
    const u16* __restrict__ zb, const float* __restrict__ nw)
{
  const long row = blockIdx.x;
  const int tid = threadIdx.x;
  float g[2];
  #pragma unroll
  for (int q=0;q<2;q++){
    const int cc = tid + q*256;
    const float yv = bf2f(y_io[row*DIN + cc]);
    const float zv = bf2f(zb[row*DIN + cc]);
    g[q] = yv * siluf(zv);
  }
  float ss = g[0]*g[0] + g[1]*g[1];
  #pragma unroll
  for (int o=32;o;o>>=1) ss += __shfl_down(ss, o);
  __shared__ float red[4];
  if ((tid & 63) == 0) red[tid>>6] = ss;
  __syncthreads();
  const float tot = red[0]+red[1]+red[2]+red[3];
  const float scale = rsqrtf(tot * (1.f/512.f) + 1e-5f);
  #pragma unroll
  for (int q=0;q<2;q++){
    const int cc = tid + q*256;
    y_io[row*DIN + cc] = f2bf(g[q] * scale * nw[cc]);
  }
}

// ---------------- decoder: hb bf16 in, fp32 out ----------------
__global__ __launch_bounds__(64) void dec_kernel(const u16* __restrict__ hb,
    const float* __restrict__ W, const float* __restrict__ bias, float* __restrict__ out)
{
  const int wg = blockIdx.x;
  const int b = wg / 10, o = wg % 10;
  const int lane = threadIdx.x;
  const u16* r = hb + ((long)b*SEQ + SEQ-1)*DMODEL;
  float s = 0.f;
  #pragma unroll
  for (int q=0;q<4;q++){ const int k = lane + q*64; s += bf2f(r[k])*W[k*10+o]; }
  #pragma unroll
  for (int o2=32;o2;o2>>=1) s += __shfl_down(s, o2);
  if (lane == 0) out[wg] = s + bias[o];
}

extern "C" void kernel_launch(void* const* d_in, const int* in_sizes, int n_in,
                              void* d_out, int out_size, void* d_ws, size_t ws_size,
                              hipStream_t stream) {
  const float* x        = (const float*)d_in[0];
  const float* enc_w    = (const float*)d_in[1];
  const float* enc_b    = (const float*)d_in[2];
  const float* in_proj  = (const float*)d_in[3];
  const float* conv_w   = (const float*)d_in[4];
  const float* conv_b   = (const float*)d_in[5];
  const float* dt_bias  = (const float*)d_in[6];
  const float* A_log    = (const float*)d_in[7];
  const float* Dp       = (const float*)d_in[8];
  const float* norm_w   = (const float*)d_in[9];
  const float* out_proj = (const float*)d_in[10];
  const float* ln_w     = (const float*)d_in[11];
  const float* ln_b     = (const float*)d_in[12];
  const float* dec_w    = (const float*)d_in[13];
  const float* dec_b    = (const float*)d_in[14];
  float* out = (float*)d_out;

  float* ws = (float*)d_ws;
  u16* WtIn  = (u16*)ws;                       // 2*NPAD*256 shorts = 655360
  u16* WtOut = WtIn + (long)2*NPAD*DMODEL;     // 2*256*512 shorts = 262144
  float* gbase = ws + 327680 + 131072;         // = ws + 458752 floats

  // Per-token fp32-equivalents: hb 128 + z 256 + xbc 320 + xsx 256 + yg 256
  //                             + Bb 32 + Cb 32 + dtb 8 + lab 8 = 1296
  int NB = 8;
  while (NB > 1) {
    const long Mb = (long)NB * SEQ;
    const long bytes = (458752L + Mb * 1296L + 4096) * 4;
    if ((size_t)bytes <= ws_size) break;
    NB >>= 1;
  }
  const long Mb = (long)NB * SEQ;

  u16*   hb   = (u16*)gbase;              // Mb*256 u16 (residual stream, bf16 only)
  u16*   zbuf = hb + Mb*DMODEL;           // Mb*512 u16
  u16*   xbc  = zbuf + Mb*DIN;            // Mb*640 u16 ; aliased by Sloc (Mb*256 u16)
  u16*   xsx  = xbc + Mb*CONVDIM;         // Mb*512 u16
  u16*   yg   = xsx + Mb*DIN;             // Mb*512 u16 (y, then g in place)
  u16*   Bb   = yg + Mb*DIN;              // Mb*64 u16
  u16*   Cb   = Bb + Mb*DSTATE;           // Mb*64 u16
  float* dtb  = (float*)(Cb + Mb*DSTATE); // Mb*8 f
  float* lab  = dtb + Mb*NH;              // Mb*8 f (log dA)
  float* Pb   = lab + Mb*NH;              // <= 2048
  u16*   Sloc = xbc;                      // alias: xbc dead after conv; Mb*256 u16

  cvt_inw <<<dim3(2*NPAD),   dim3(256), 0, stream>>>(in_proj,  WtIn);
  cvt_outw<<<dim3(2*DMODEL), dim3(256), 0, stream>>>(out_proj, WtOut);

  const int ngroups = B_SZ / NB;
  for (int g = 0; g < ngroups; ++g) {
    const float* xg = x + (long)g*NB*SEQ*64;

    enc_kernel<<<dim3((int)(Mb/32)), dim3(256), 0, stream>>>(xg, enc_w, enc_b, hb);

    for (int l = 0; l < 2; ++l) {
      inproj_mfma<<<dim3((int)(Mb/128), NPAD/128), dim3(256), 0, stream>>>(
          hb, WtIn + (long)l*NPAD*DMODEL, zbuf, xbc, dtb, lab,
          dt_bias + l*NH, A_log + l*NH);
      conv_kernel<<<dim3((int)(Mb*20/256)), dim3(256), 0, stream>>>(
          xbc, conv_w + (long)l*CONVDIM*4, conv_b + (long)l*CONVDIM, xsx, Bb, Cb);
      scanS_kernel<<<dim3(NB*8*NCHUNK), dim3(256), 0, stream>>>(xsx, Bb, lab, dtb, Sloc, Pb);
      scanMid_kernel<<<dim3(NB*8, 64), dim3(64), 0, stream>>>(Sloc, Pb);
      scanY_kernel<<<dim3(NB*8*NCHUNK), dim3(512), 0, stream>>>(xsx, yg, Bb, Cb, lab, dtb, Sloc, Dp + l*NH);
      gnorm_kernel<<<dim3((int)Mb), dim3(256), 0, stream>>>(yg, zbuf, norm_w + (long)l*DIN);
      outproj_fused<<<dim3((int)(Mb/128)), dim3(512), 0, stream>>>(
          yg, WtOut + (long)l*DMODEL*DIN, hb, ln_w + l*DMODEL, ln_b + l*DMODEL);
    }

    dec_kernel<<<dim3(NB*10), dim3(64), 0, stream>>>(hb, dec_w, dec_b, out + (long)g*NB*10);
  }
}

// Round 17
// 491.682 us; speedup vs baseline: 1.4663x; 1.0407x over previous
//
#include <hip/hip_runtime.h>
#include <hip/hip_bf16.h>
#include <math.h>

// ---- model constants ----
#define B_SZ    8
#define SEQ     4096
#define DMODEL  256
#define DIN     512     // d_inner
#define DSTATE  64
#define NH      8
#define HD      64
#define CONVDIM 640
#define DPROJ   1160
#define NPAD    1280    // DPROJ padded to 10*128
#define NCHUNK  32      // scan chunks per (b,h)
#define CLEN    128     // SEQ / NCHUNK
#define STR64   68      // LDS row stride (shorts) for K=64 tiles
#define STR128  132     // LDS row stride (shorts) for K=128 tiles
#define EPSTR   140     // epilogue bounce stride

typedef unsigned long long u64;
typedef unsigned int u32;
typedef unsigned short u16;
typedef __attribute__((ext_vector_type(8))) short bf16x8;
typedef __attribute__((ext_vector_type(4))) float f32x4;

__device__ __forceinline__ float siluf(float v){ return v / (1.f + expf(-v)); }
__device__ __forceinline__ u16 f2bf(float f){ __hip_bfloat16 h = __float2bfloat16(f); return *(u16*)&h; }
__device__ __forceinline__ float bf2f(u16 u){ union{u32 i; float f;} t; t.i = ((u32)u)<<16; return t.f; }
__device__ __forceinline__ bf16x8 ldfrag(const u16* base){
  union { u64 u[2]; bf16x8 v; } t;
  const u64* p = (const u64*)base;
  t.u[0] = p[0]; t.u[1] = p[1];
  return t.v;
}

// ---------------- weight conversion (once per launch) ----------------
__global__ __launch_bounds__(256) void cvt_inw(const float* __restrict__ W, u16* __restrict__ Wt)
{
  const int blk = blockIdx.x;
  const int l = blk / NPAD, n = blk % NPAD;
  const int k = threadIdx.x;
  float v = 0.f;
  if (n < DPROJ) v = W[((long)l*DMODEL + k)*DPROJ + n];
  Wt[((long)l*NPAD + n)*DMODEL + k] = f2bf(v);
}

__global__ __launch_bounds__(256) void cvt_outw(const float* __restrict__ W, u16* __restrict__ Wt)
{
  const int blk = blockIdx.x;
  const int l = blk / DMODEL, n = blk % DMODEL;
  #pragma unroll
  for (int q = 0; q < 2; ++q) {
    const int k = threadIdx.x + q*256;
    const float v = W[((long)l*DIN + k)*DMODEL + n];
    Wt[((long)l*DMODEL + n)*DIN + k] = f2bf(v);
  }
}

// ---------------- encoder GEMM; writes hb bf16 ----------------
__global__ __launch_bounds__(256) void enc_kernel(const float* __restrict__ x,
    const float* __restrict__ W, const float* __restrict__ bias, u16* __restrict__ hb)
{
  __shared__ float xl[32*64];
  const int tid = threadIdx.x;
  const long t0 = (long)blockIdx.x * 32;
  for (int i = tid; i < 32*64; i += 256) xl[i] = x[t0*64 + i];
  __syncthreads();
  float acc[32];
  const float bv = bias[tid];
  #pragma unroll
  for (int tok = 0; tok < 32; ++tok) acc[tok] = bv;
  for (int k = 0; k < 64; ++k) {
    const float wv = W[k*DMODEL + tid];
    #pragma unroll
    for (int tok = 0; tok < 32; ++tok) acc[tok] += xl[tok*64 + k] * wv;
  }
  #pragma unroll
  for (int tok = 0; tok < 32; ++tok)
    hb[(t0 + tok)*DMODEL + tid] = f2bf(acc[tok]);
}

// ---------------- in_proj MFMA GEMM 128x128 tile, BK=32 ----------------
__global__ __launch_bounds__(256) void inproj_mfma(const u16* __restrict__ hb,
    const u16* __restrict__ Wt, u16* __restrict__ zbuf, u16* __restrict__ xbc,
    float* __restrict__ dtb, float* __restrict__ lab,
    const float* __restrict__ dt_bias, const float* __restrict__ A_log)
{
  __shared__ __align__(16) u16 pool[128*36*2];   // staging Asl|Bsl; epilogue bounce aliases it
  u16* Asl = pool;
  u16* Bsl = pool + 128*36;
  u16* Ep  = pool;                               // [64][EPSTR] u16 per mi-half (8960 <= 9216)
  const int tid = threadIdx.x;
  const long m0 = (long)blockIdx.x * 128;
  const int n0 = blockIdx.y * 128;
  const int w = tid >> 6, lane = tid & 63;
  const int q = lane >> 4, l16 = lane & 15;
  const int srow = tid >> 1, sseg = tid & 1;   // 2 lanes/row, 16 shorts (32 B) each
  f32x4 acc[2][8] = {{{0.f,0.f,0.f,0.f}}};
  for (int k0 = 0; k0 < DMODEL; k0 += 32) {
    {
      const u64* s = (const u64*)(hb + (m0 + srow)*DMODEL + k0 + sseg*16);
      u64 a=s[0], b=s[1], c=s[2], d=s[3];
      u64* dst = (u64*)(&Asl[srow*36 + sseg*16]);
      dst[0]=a; dst[1]=b; dst[2]=c; dst[3]=d;
    }
    {
      const u64* s = (const u64*)(Wt + (long)(n0 + srow)*DMODEL + k0 + sseg*16);
      u64 a=s[0], b=s[1], c=s[2], d=s[3];
      u64* dst = (u64*)(&Bsl[srow*36 + sseg*16]);
      dst[0]=a; dst[1]=b; dst[2]=c; dst[3]=d;
    }
    __syncthreads();
    bf16x8 af[2], bfr[8];
    #pragma unroll
    for (int mi=0;mi<2;mi++) af[mi] = ldfrag(&Asl[(w*32 + mi*16 + l16)*36 + q*8]);
    #pragma unroll
    for (int nj=0;nj<8;nj++) bfr[nj] = ldfrag(&Bsl[(nj*16 + l16)*36 + q*8]);
    #pragma unroll
    for (int mi=0;mi<2;mi++)
      #pragma unroll
      for (int nj=0;nj<8;nj++)
        acc[mi][nj] = __builtin_amdgcn_mfma_f32_16x16x32_bf16(af[mi], bfr[nj], acc[mi][nj], 0,0,0);
    __syncthreads();
  }
  if (n0 < DIN + CONVDIM) {
    // bounce each 64-row half through LDS, then full-line stores (4 thr/row x 32 shorts = 128)
    #pragma unroll
    for (int mi=0;mi<2;mi++){
      if (mi) __syncthreads();
      #pragma unroll
      for (int nj=0;nj<8;nj++){
        const int col = nj*16 + l16;
        #pragma unroll
        for (int r=0;r<4;r++){
          const int er = w*16 + q*4 + r;
          Ep[er*EPSTR + col] = f2bf(acc[mi][nj][r]);
        }
      }
      __syncthreads();
      {
        const int er2 = tid >> 2, seg = tid & 3;
        const long grow = m0 + (er2>>4)*32 + mi*16 + (er2&15);
        const u64* s = (const u64*)(Ep + er2*EPSTR + seg*32);
        u64 v0=s[0], v1=s[1], v2=s[2], v3=s[3], v4=s[4], v5=s[5], v6=s[6], v7=s[7];
        u64* dptr;
        if (n0 < DIN) dptr = (u64*)(zbuf + grow*DIN + n0 + seg*32);
        else          dptr = (u64*)(xbc + grow*CONVDIM + (n0 - DIN) + seg*32);
        dptr[0]=v0; dptr[1]=v1; dptr[2]=v2; dptr[3]=v3;
        dptr[4]=v4; dptr[5]=v5; dptr[6]=v6; dptr[7]=v7;
      }
    }
  } else {
    // dt tile: only cols 1152..1159 valid
    #pragma unroll
    for (int mi=0;mi<2;mi++){
      #pragma unroll
      for (int nj=0;nj<8;nj++){
        const int col = n0 + nj*16 + l16;
        if (col < DPROJ) {
          const int hh = col - (DIN + CONVDIM);
          #pragma unroll
          for (int r=0;r<4;r++){
            const long row = m0 + w*32 + mi*16 + q*4 + r;
            const float dv = acc[mi][nj][r] + dt_bias[hh];
            const float sp = dv > 20.f ? dv : log1pf(expf(dv));
            dtb[row*NH + hh] = sp;
            lab[row*NH + hh] = sp * (-expf(A_log[hh]));   // log dA
          }
        }
      }
    }
  }
}

// ---------------- out_proj fused: gnorm (y*silu(z), RMS) + GEMM + residual + LayerNorm ----------------
// RMS scale commutes through GEMM: out = scale_row * ((g*nw) @ W). 512 threads.
__global__ __launch_bounds__(512) void outproj_fused(const u16* __restrict__ yb,
    const u16* __restrict__ zb, const u16* __restrict__ Wt, u16* __restrict__ hb,
    const float* __restrict__ nw, const float* __restrict__ lnw, const float* __restrict__ lnb)
{
  __shared__ __align__(16) u16 Asl[128*36];
  __shared__ __align__(16) u16 Bsl[256*36];
  __shared__ float red[128][2][2];     // [row][colgroup][sum, sumsq] for LN
  __shared__ float red2[128][2];       // [row][seg] partial sum g^2 for RMS
  __shared__ float nwl[512];
  const int tid = threadIdx.x;
  const long m0 = (long)blockIdx.x * 128;
  const int w = tid >> 6, lane = tid & 63;
  const int q = lane >> 4, l16 = lane & 15;
  const int wr = (w >> 1) * 32;        // wave row base (0/32/64/96)
  const int wc = (w & 1) * 128;        // wave col base (0/128)
  const int srow = tid >> 1, sseg = tid & 1;   // staging: 2 threads/row, 16 shorts each
  if (tid < 512) nwl[tid] = nw[tid];
  __syncthreads();
  float sq = 0.f;
  f32x4 acc[2][8] = {{{0.f,0.f,0.f,0.f}}};
  for (int kk = 0; kk < 16; ++kk) {
    const int k0 = kk*32;
    if (tid < 256) {   // A staging: compute g = y*silu(z); stage g*nw bf16; accumulate g^2
      const u64* yp = (const u64*)(yb + (m0 + srow)*DIN + k0 + sseg*16);
      const u64* zp = (const u64*)(zb + (m0 + srow)*DIN + k0 + sseg*16);
      const u64 ys[4] = {yp[0], yp[1], yp[2], yp[3]};
      const u64 zs[4] = {zp[0], zp[1], zp[2], zp[3]};
      u16 gv[16];
      #pragma unroll
      for (int u=0;u<4;u++){
        #pragma unroll
        for (int j=0;j<4;j++){
          const float yv = bf2f((u16)(ys[u] >> (16*j)));
          const float zv = bf2f((u16)(zs[u] >> (16*j)));
          const float g = yv * siluf(zv);
          sq += g*g;
          gv[u*4+j] = f2bf(g * nwl[k0 + sseg*16 + u*4 + j]);
        }
      }
      const u64* gp = (const u64*)gv;
      u64* dst = (u64*)(&Asl[srow*36 + sseg*16]);
      dst[0]=gp[0]; dst[1]=gp[1]; dst[2]=gp[2]; dst[3]=gp[3];
    }
    {
      const u64* s = (const u64*)(Wt + (long)srow*DIN + k0 + sseg*16);
      u64 a=s[0], b=s[1], c=s[2], d=s[3];
      u64* dst = (u64*)(&Bsl[srow*36 + sseg*16]);
      dst[0]=a; dst[1]=b; dst[2]=c; dst[3]=d;
    }
    __syncthreads();
    bf16x8 af[2], bfr[8];
    #pragma unroll
    for (int mi=0;mi<2;mi++) af[mi] = ldfrag(&Asl[(wr + mi*16 + l16)*36 + q*8]);
    #pragma unroll
    for (int nj=0;nj<8;nj++) bfr[nj] = ldfrag(&Bsl[(wc + nj*16 + l16)*36 + q*8]);
    #pragma unroll
    for (int mi=0;mi<2;mi++)
      #pragma unroll
      for (int nj=0;nj<8;nj++)
        acc[mi][nj] = __builtin_amdgcn_mfma_f32_16x16x32_bf16(af[mi], bfr[nj], acc[mi][nj], 0,0,0);
    __syncthreads();
  }
  if (tid < 256) { red2[srow][sseg] = sq; }
  __syncthreads();
  // o = acc*rms_scale + resid(bf16) ; per-row LN stats via 16-lane shuffle + LDS combine
  #pragma unroll
  for (int mi=0;mi<2;mi++){
    #pragma unroll
    for (int r=0;r<4;r++){
      const int lrow = wr + mi*16 + q*4 + r;
      const float S2 = red2[lrow][0] + red2[lrow][1];
      const float rscale = rsqrtf(S2*(1.f/512.f) + 1e-5f);
      float s = 0.f, ss = 0.f;
      #pragma unroll
      for (int nj=0;nj<8;nj++){
        const int col = wc + nj*16 + l16;
        const float o = acc[mi][nj][r]*rscale + bf2f(hb[(m0+lrow)*DMODEL + col]);
        acc[mi][nj][r] = o;
        s += o; ss += o*o;
      }
      #pragma unroll
      for (int o2=1;o2<16;o2<<=1){ s += __shfl_xor(s,o2); ss += __shfl_xor(ss,o2); }
      if (l16 == 0) { red[lrow][w&1][0] = s; red[lrow][w&1][1] = ss; }
    }
  }
  __syncthreads();
  #pragma unroll
  for (int mi=0;mi<2;mi++){
    #pragma unroll
    for (int r=0;r<4;r++){
      const int lrow = wr + mi*16 + q*4 + r;
      const float S  = red[lrow][0][0] + red[lrow][1][0];
      const float SS = red[lrow][0][1] + red[lrow][1][1];
      const float mu = S * (1.f/256.f);
      const float var = SS * (1.f/256.f) - mu*mu;
      const float rs = rsqrtf(var + 1e-5f);
      #pragma unroll
      for (int nj=0;nj<8;nj++){
        const int col = wc + nj*16 + l16;
        const float v = (acc[mi][nj][r] - mu)*rs*lnw[col] + lnb[col];
        hb[(m0+lrow)*DMODEL + col] = f2bf(v);
      }
    }
  }
}

// ---------------- depthwise causal conv + SiLU: strip kernel ----------------
__global__ __launch_bounds__(256) void conv_kernel(const u16* __restrict__ xbc,
    const float* __restrict__ cw, const float* __restrict__ cb,
    u16* __restrict__ xsx, u16* __restrict__ Bb, u16* __restrict__ Cb)
{
  const long idx = (long)blockIdx.x * 256 + threadIdx.x;   // Mb*20 threads
  const int c4 = (int)(idx % 160) * 4;
  const long bt0 = (idx / 160) * 8;          // strip start (strips never cross batch)
  const int tseq = (int)(bt0 & (SEQ-1));
  const float4 b4 = *(const float4*)(cb + c4);
  const float4 w0v = *(const float4*)(cw + (c4+0)*4);
  const float4 w1v = *(const float4*)(cw + (c4+1)*4);
  const float4 w2v = *(const float4*)(cw + (c4+2)*4);
  const float4 w3v = *(const float4*)(cw + (c4+3)*4);
  const float W0[4] = {w0v.x,w0v.y,w0v.z,w0v.w};
  const float W1[4] = {w1v.x,w1v.y,w1v.z,w1v.w};
  const float W2[4] = {w2v.x,w2v.y,w2v.z,w2v.w};
  const float W3[4] = {w3v.x,w3v.y,w3v.z,w3v.w};
  float i0[11], i1[11], i2[11], i3[11];
  #pragma unroll
  for (int k = 0; k < 11; ++k) {
    u64 v = 0;
    if (tseq - 3 + k >= 0) v = *(const u64*)(xbc + (bt0 - 3 + k)*CONVDIM + c4);
    i0[k]=bf2f((u16)v); i1[k]=bf2f((u16)(v>>16)); i2[k]=bf2f((u16)(v>>32)); i3[k]=bf2f((u16)(v>>48));
  }
  u16* dst; long base; int stride;
  if (c4 < DIN)              { dst = xsx; base = bt0*DIN + c4;              stride = DIN; }
  else if (c4 < DIN+DSTATE)  { dst = Bb;  base = bt0*DSTATE + (c4-DIN);     stride = DSTATE; }
  else                       { dst = Cb;  base = bt0*DSTATE + (c4-DIN-DSTATE); stride = DSTATE; }
  #pragma unroll
  for (int j = 0; j < 8; ++j) {
    float a0=b4.x, a1=b4.y, a2=b4.z, a3=b4.w;
    #pragma unroll
    for (int k = 0; k < 4; ++k) {
      a0 += W0[k]*i0[j+k]; a1 += W1[k]*i1[j+k];
      a2 += W2[k]*i2[j+k]; a3 += W3[k]*i3[j+k];
    }
    a0=siluf(a0); a1=siluf(a1); a2=siluf(a2); a3=siluf(a3);
    const u64 r = (u64)f2bf(a0) | ((u64)f2bf(a1)<<16) | ((u64)f2bf(a2)<<32) | ((u64)f2bf(a3)<<48);
    *(u64*)(dst + base + (long)j*stride) = r;
  }
}

// ---------------- SSD phase A: per chunk-head local state via MFMA; Sloc bf16 ----------------
__global__ __launch_bounds__(256) void scanS_kernel(const u16* __restrict__ xsx,
    const u16* __restrict__ Bb, const float* __restrict__ lab, const float* __restrict__ dtb,
    u16* __restrict__ Sloc, float* __restrict__ Pb)
{
  __shared__ __align__(16) u16 Btr[64*STR128];   // [n][s]
  __shared__ __align__(16) u16 Uw[64*STR128];    // [p][s]
  __shared__ float cexpL[128];
  const int wg = blockIdx.x;
  const int c = wg & (NCHUNK-1), bh = wg >> 5, hh = bh & (NH-1), b = bh >> 3;
  const int tid = threadIdx.x;
  const long bt0 = (long)b*SEQ + c*CLEN;
  if (tid < 64) {   // wave 0: inclusive prefix of log dA over 128 steps
    float a0 = lab[(bt0+tid)*NH + hh];
    float a1 = lab[(bt0+64+tid)*NH + hh];
    const float d0 = dtb[(bt0+tid)*NH + hh];
    const float d1 = dtb[(bt0+64+tid)*NH + hh];
    #pragma unroll
    for (int o=1;o<64;o<<=1){
      const float t0=__shfl_up(a0,o), t1=__shfl_up(a1,o);
      if (tid>=o){a0+=t0;a1+=t1;}
    }
    a1 += __shfl(a0,63);
    const float ctot = __shfl(a1,63);
    cexpL[tid]    = d0*__expf(ctot - a0);
    cexpL[tid+64] = d1*__expf(ctot - a1);
    if (tid==0) Pb[wg] = __expf(ctot);
  }
  __syncthreads();
  {
    const int v = tid & 63, r0 = tid >> 6;
    #pragma unroll 4
    for (int k=0;k<32;k++){
      const int s = r0 + k*4;
      Btr[v*STR128 + s] = Bb[(bt0+s)*DSTATE + v];
      Uw[v*STR128 + s]  = f2bf(cexpL[s]*bf2f(xsx[(bt0+s)*DIN + hh*HD + v]));
    }
  }
  __syncthreads();
  const int w = tid>>6, lane = tid&63, q = lane>>4, l16 = lane&15;
  f32x4 acc[4] = {};
  #pragma unroll
  for (int ks=0;ks<4;ks++){
    const bf16x8 af = ldfrag(&Uw[(w*16+l16)*STR128 + ks*32 + q*8]);
    #pragma unroll
    for (int nj=0;nj<4;nj++){
      const bf16x8 bf = ldfrag(&Btr[(nj*16+l16)*STR128 + ks*32 + q*8]);
      acc[nj] = __builtin_amdgcn_mfma_f32_16x16x32_bf16(af, bf, acc[nj], 0,0,0);
    }
  }
  const long sb = (long)wg*4096;   // [wg][p][n] bf16
  #pragma unroll
  for (int nj=0;nj<4;nj++)
    #pragma unroll
    for (int r=0;r<4;r++)
      Sloc[sb + (w*16+q*4+r)*64 + nj*16 + l16] = f2bf(acc[nj][r]);
}

// Parallel combine over bf16 Sloc: run stays fp32 in registers
__global__ __launch_bounds__(64) void scanMid_kernel(u16* __restrict__ Sloc, const float* __restrict__ Pb)
{
  const int bh = blockIdx.x;
  const int rr = blockIdx.y;
  const int p  = threadIdx.x;
  float run = 0.f;
  for (int c = 0; c < NCHUNK; ++c) {
    const long base = ((long)(bh*NCHUNK + c))*4096 + rr*64 + p;
    const float Pc = Pb[bh*NCHUNK + c];
    const float tmp = bf2f(Sloc[base]);
    Sloc[base] = f2bf(run);
    run = run*Pc + tmp;
  }
}

// ---------------- SSD phase C: Y = ((C Bt) o L) U + diag(exp(cum)) (C h0) + D*x ; coalesced y out ----------------
__global__ __launch_bounds__(512) void scanY_kernel(const u16* __restrict__ xsx,
    u16* __restrict__ yg, const u16* __restrict__ Bb, const u16* __restrict__ Cb,
    const float* __restrict__ lab, const float* __restrict__ dtb,
    const u16* __restrict__ Sinit, const float* __restrict__ Dp)
{
  __shared__ __align__(16) u16 pool[2*128*STR64];  // Bs | Cs; overlaid by Ms[t][s]; then by y-bounce
  __shared__ __align__(16) u16 Ut[64*STR128];      // [p][s]
  __shared__ __align__(16) u16 h0t[64*STR64];      // [p][n]
  __shared__ float cumL[128];
  __shared__ float dtL[128];
  u16* Bs = pool;
  u16* Cs = pool + 128*STR64;
  u16* Ms = pool;

  const int wg = blockIdx.x;
  const int c = wg & (NCHUNK-1), bh = wg >> 5, hh = bh & (NH-1), b = bh >> 3;
  const int tid = threadIdx.x;
  const long bt0 = (long)b*SEQ + c*CLEN;

  if (tid < 64) {
    float a0 = lab[(bt0+tid)*NH + hh];
    float a1 = lab[(bt0+64+tid)*NH + hh];
    dtL[tid]    = dtb[(bt0+tid)*NH + hh];
    dtL[tid+64] = dtb[(bt0+64+tid)*NH + hh];
    #pragma unroll
    for (int o=1;o<64;o<<=1){
      const float t0=__shfl_up(a0,o), t1=__shfl_up(a1,o);
      if (tid>=o){a0+=t0;a1+=t1;}
    }
    a1 += __shfl(a0,63);
    cumL[tid]=a0; cumL[tid+64]=a1;
  }
  __syncthreads();
  {
    const int n = tid & 63, r0 = tid >> 6;   // 512 threads: r0 in 0..7
    #pragma unroll 4
    for (int k=0;k<16;k++){
      const int s = r0 + k*8;
      Bs[s*STR64 + n] = Bb[(bt0+s)*DSTATE + n];
      Cs[s*STR64 + n] = Cb[(bt0+s)*DSTATE + n];
      Ut[n*STR128 + s] = f2bf(dtL[s]*bf2f(xsx[(bt0+s)*DIN + hh*HD + n]));
    }
    const int n0 = r0*8;
    // h0 bf16: 8 states = 16 B = two u64 copies
    const u64* sp = (const u64*)(Sinit + (long)wg*4096 + n*64 + n0);
    u64* dp = (u64*)(h0t + n*STR64 + n0);
    dp[0] = sp[0]; dp[1] = sp[1];
  }
  __syncthreads();

  const int w = tid>>6, lane = tid&63, q = lane>>4, l16 = lane&15;
  f32x4 accG[8] = {};
  f32x4 accI[4] = {};
  #pragma unroll
  for (int ks=0;ks<2;ks++){
    const bf16x8 af = ldfrag(&Cs[(w*16+l16)*STR64 + ks*32 + q*8]);
    #pragma unroll
    for (int nj=0;nj<8;nj++)
      accG[nj] = __builtin_amdgcn_mfma_f32_16x16x32_bf16(af, ldfrag(&Bs[(nj*16+l16)*STR64 + ks*32 + q*8]), accG[nj], 0,0,0);
    #pragma unroll
    for (int nj=0;nj<4;nj++)
      accI[nj] = __builtin_amdgcn_mfma_f32_16x16x32_bf16(af, ldfrag(&h0t[(nj*16+l16)*STR64 + ks*32 + q*8]), accI[nj], 0,0,0);
  }
  __syncthreads();
  #pragma unroll
  for (int nj=0;nj<8;nj++){
    const int s = nj*16 + l16;
    #pragma unroll
    for (int r=0;r<4;r++){
      const int t = w*16 + q*4 + r;
      const float v = (s<=t) ? accG[nj][r]*__expf(cumL[t]-cumL[s]) : 0.f;
      Ms[t*STR128 + s] = f2bf(v);
    }
  }
  __syncthreads();
  f32x4 accY[4] = {};
  #pragma unroll
  for (int ks=0;ks<4;ks++){
    const bf16x8 af = ldfrag(&Ms[(w*16+l16)*STR128 + ks*32 + q*8]);
    #pragma unroll
    for (int nj=0;nj<4;nj++)
      accY[nj] = __builtin_amdgcn_mfma_f32_16x16x32_bf16(af, ldfrag(&Ut[(nj*16+l16)*STR128 + ks*32 + q*8]), accY[nj], 0,0,0);
  }
  const float Dv = Dp[hh];
  __syncthreads();   // Ms reads done; reuse pool as y-bounce [128][STR64]
  #pragma unroll
  for (int nj=0;nj<4;nj++){
    const int p = nj*16 + l16;
    #pragma unroll
    for (int r=0;r<4;r++){
      const int t = w*16 + q*4 + r;
      const float xv = bf2f(xsx[(bt0+t)*DIN + hh*HD + p]);
      pool[t*STR64 + p] = f2bf(accY[nj][r] + __expf(cumL[t])*accI[nj][r] + Dv*xv);
    }
  }
  __syncthreads();
  {
    const int row = tid >> 2, seg = tid & 3;
    const u64* s = (const u64*)(pool + row*STR64 + seg*16);
    u64 a=s[0], b2=s[1], c2=s[2], d=s[3];
    u64* dptr = (u64*)(yg + (bt0+row)*DIN + hh*HD + seg*16);
    dptr[0]=a; dptr[1]=b2; dptr[2]=c2; dptr[3]=d;
  }
}

// ---------------- decoder: hb bf16 in, fp32 out ----------------
__global__ __launch_bounds__(64) void dec_kernel(const u16* __restrict__ hb,
    const float* __restrict__ W, const float* __restrict__ bias, float* __restrict__ out)
{
  const int wg = blockIdx.x;
  const int b = wg / 10, o = wg % 10;
  const int lane = threadIdx.x;
  const u16* r = hb + ((long)b*SEQ + SEQ-1)*DMODEL;
  float s = 0.f;
  #pragma unroll
  for (int q=0;q<4;q++){ const int k = lane + q*64; s += bf2f(r[k])*W[k*10+o]; }
  #pragma unroll
  for (int o2=32;o2;o2>>=1) s += __shfl_down(s, o2);
  if (lane == 0) out[wg] = s + bias[o];
}

extern "C" void kernel_launch(void* const* d_in, const int* in_sizes, int n_in,
                              void* d_out, int out_size, void* d_ws, size_t ws_size,
                              hipStream_t stream) {
  const float* x        = (const float*)d_in[0];
  const float* enc_w    = (const float*)d_in[1];
  const float* enc_b    = (const float*)d_in[2];
  const float* in_proj  = (const float*)d_in[3];
  const float* conv_w   = (const float*)d_in[4];
  const float* conv_b   = (const float*)d_in[5];
  const float* dt_bias  = (const float*)d_in[6];
  const float* A_log    = (const float*)d_in[7];
  const float* Dp       = (const float*)d_in[8];
  const float* norm_w   = (const float*)d_in[9];
  const float* out_proj = (const float*)d_in[10];
  const float* ln_w     = (const float*)d_in[11];
  const float* ln_b     = (const float*)d_in[12];
  const float* dec_w    = (const float*)d_in[13];
  const float* dec_b    = (const float*)d_in[14];
  float* out = (float*)d_out;

  float* ws = (float*)d_ws;
  u16* WtIn  = (u16*)ws;                       // 2*NPAD*256 shorts = 655360
  u16* WtOut = WtIn + (long)2*NPAD*DMODEL;     // 2*256*512 shorts = 262144
  float* gbase = ws + 327680 + 131072;         // = ws + 458752 floats

  // Per-token fp32-equivalents: hb 128 + z 256 + xbc 320 + xsx 256 + yg 256
  //                             + Bb 32 + Cb 32 + dtb 8 + lab 8 = 1296
  int NB = 8;
  while (NB > 1) {
    const long Mb = (long)NB * SEQ;
    const long bytes = (458752L + Mb * 1296L + 4096) * 4;
    if ((size_t)bytes <= ws_size) break;
    NB >>= 1;
  }
  const long Mb = (long)NB * SEQ;

  u16*   hb   = (u16*)gbase;              // Mb*256 u16 (residual stream, bf16 only)
  u16*   zbuf = hb + Mb*DMODEL;           // Mb*512 u16
  u16*   xbc  = zbuf + Mb*DIN;            // Mb*640 u16 ; aliased by Sloc (Mb*256 u16)
  u16*   xsx  = xbc + Mb*CONVDIM;         // Mb*512 u16
  u16*   yg   = xsx + Mb*DIN;             // Mb*512 u16 (y)
  u16*   Bb   = yg + Mb*DIN;              // Mb*64 u16
  u16*   Cb   = Bb + Mb*DSTATE;           // Mb*64 u16
  float* dtb  = (float*)(Cb + Mb*DSTATE); // Mb*8 f
  float* lab  = dtb + Mb*NH;              // Mb*8 f (log dA)
  float* Pb   = lab + Mb*NH;              // <= 2048
  u16*   Sloc = xbc;                      // alias: xbc dead after conv; Mb*256 u16

  cvt_inw <<<dim3(2*NPAD),   dim3(256), 0, stream>>>(in_proj,  WtIn);
  cvt_outw<<<dim3(2*DMODEL), dim3(256), 0, stream>>>(out_proj, WtOut);

  const int ngroups = B_SZ / NB;
  for (int g = 0; g < ngroups; ++g) {
    const float* xg = x + (long)g*NB*SEQ*64;

    enc_kernel<<<dim3((int)(Mb/32)), dim3(256), 0, stream>>>(xg, enc_w, enc_b, hb);

    for (int l = 0; l < 2; ++l) {
      inproj_mfma<<<dim3((int)(Mb/128), NPAD/128), dim3(256), 0, stream>>>(
          hb, WtIn + (long)l*NPAD*DMODEL, zbuf, xbc, dtb, lab,
          dt_bias + l*NH, A_log + l*NH);
      conv_kernel<<<dim3((int)(Mb*20/256)), dim3(256), 0, stream>>>(
          xbc, conv_w + (long)l*CONVDIM*4, conv_b + (long)l*CONVDIM, xsx, Bb, Cb);
      scanS_kernel<<<dim3(NB*8*NCHUNK), dim3(256), 0, stream>>>(xsx, Bb, lab, dtb, Sloc, Pb);
      scanMid_kernel<<<dim3(NB*8, 64), dim3(64), 0, stream>>>(Sloc, Pb);
      scanY_kernel<<<dim3(NB*8*NCHUNK), dim3(512), 0, stream>>>(xsx, yg, Bb, Cb, lab, dtb, Sloc, Dp + l*NH);
      outproj_fused<<<dim3((int)(Mb/128)), dim3(512), 0, stream>>>(
          yg, zbuf, WtOut + (long)l*DMODEL*DIN, hb,
          norm_w + (long)l*DIN, ln_w + l*DMODEL, ln_b + l*DMODEL);
    }

    dec_kernel<<<dim3(NB*10), dim3(64), 0, stream>>>(hb, dec_w, dec_b, out + (long)g*NB*10);
  }
}

// Round 18
// 477.109 us; speedup vs baseline: 1.5111x; 1.0305x over previous
//
#include <hip/hip_runtime.h>
#include <hip/hip_bf16.h>
#include <math.h>

// ---- model constants ----
#define B_SZ    8
#define SEQ     4096
#define DMODEL  256
#define DIN     512     // d_inner
#define DSTATE  64
#define NH      8
#define HD      64
#define CONVDIM 640
#define DPROJ   1160
#define NPAD    1280    // DPROJ padded to 10*128
#define NCHUNK  32      // scan chunks per (b,h)
#define CLEN    128     // SEQ / NCHUNK
#define STR64   68      // LDS row stride (shorts) for K=64 tiles
#define STR128  132     // LDS row stride (shorts) for K=128 tiles
#define EPSTR   140     // epilogue bounce stride

typedef unsigned long long u64;
typedef unsigned int u32;
typedef unsigned short u16;
typedef __attribute__((ext_vector_type(8))) short bf16x8;
typedef __attribute__((ext_vector_type(4))) float f32x4;

__device__ __forceinline__ float siluf(float v){ return v / (1.f + __expf(-v)); }   // native v_exp
__device__ __forceinline__ u16 f2bf(float f){ __hip_bfloat16 h = __float2bfloat16(f); return *(u16*)&h; }
__device__ __forceinline__ float bf2f(u16 u){ union{u32 i; float f;} t; t.i = ((u32)u)<<16; return t.f; }
__device__ __forceinline__ bf16x8 ldfrag(const u16* base){
  union { u64 u[2]; bf16x8 v; } t;
  const u64* p = (const u64*)base;
  t.u[0] = p[0]; t.u[1] = p[1];
  return t.v;
}

// ---------------- weight conversion (once per launch) ----------------
__global__ __launch_bounds__(256) void cvt_inw(const float* __restrict__ W, u16* __restrict__ Wt)
{
  const int blk = blockIdx.x;
  const int l = blk / NPAD, n = blk % NPAD;
  const int k = threadIdx.x;
  float v = 0.f;
  if (n < DPROJ) v = W[((long)l*DMODEL + k)*DPROJ + n];
  Wt[((long)l*NPAD + n)*DMODEL + k] = f2bf(v);
}

__global__ __launch_bounds__(256) void cvt_outw(const float* __restrict__ W, u16* __restrict__ Wt)
{
  const int blk = blockIdx.x;
  const int l = blk / DMODEL, n = blk % DMODEL;
  #pragma unroll
  for (int q = 0; q < 2; ++q) {
    const int k = threadIdx.x + q*256;
    const float v = W[((long)l*DIN + k)*DMODEL + n];
    Wt[((long)l*DMODEL + n)*DIN + k] = f2bf(v);
  }
}

// ---------------- encoder GEMM; writes hb bf16 ----------------
__global__ __launch_bounds__(256) void enc_kernel(const float* __restrict__ x,
    const float* __restrict__ W, const float* __restrict__ bias, u16* __restrict__ hb)
{
  __shared__ float xl[32*64];
  const int tid = threadIdx.x;
  const long t0 = (long)blockIdx.x * 32;
  for (int i = tid; i < 32*64; i += 256) xl[i] = x[t0*64 + i];
  __syncthreads();
  float acc[32];
  const float bv = bias[tid];
  #pragma unroll
  for (int tok = 0; tok < 32; ++tok) acc[tok] = bv;
  for (int k = 0; k < 64; ++k) {
    const float wv = W[k*DMODEL + tid];
    #pragma unroll
    for (int tok = 0; tok < 32; ++tok) acc[tok] += xl[tok*64 + k] * wv;
  }
  #pragma unroll
  for (int tok = 0; tok < 32; ++tok)
    hb[(t0 + tok)*DMODEL + tid] = f2bf(acc[tok]);
}

// ---------------- in_proj MFMA GEMM 128x128 tile, BK=32 ----------------
// Grid (10, Mb/128): col-tiles vary fastest -> the 10 tiles of one m-strip co-run, A-strip L2-resident.
__global__ __launch_bounds__(256) void inproj_mfma(const u16* __restrict__ hb,
    const u16* __restrict__ Wt, u16* __restrict__ zbuf, u16* __restrict__ xbc,
    float* __restrict__ dtb, float* __restrict__ lab,
    const float* __restrict__ dt_bias, const float* __restrict__ A_log)
{
  __shared__ __align__(16) u16 pool[128*36*2];   // staging Asl|Bsl; epilogue bounce aliases it
  u16* Asl = pool;
  u16* Bsl = pool + 128*36;
  u16* Ep  = pool;                               // [64][EPSTR] u16 per mi-half (8960 <= 9216)
  const int tid = threadIdx.x;
  const long m0 = (long)blockIdx.y * 128;
  const int n0 = blockIdx.x * 128;
  const int w = tid >> 6, lane = tid & 63;
  const int q = lane >> 4, l16 = lane & 15;
  const int srow = tid >> 1, sseg = tid & 1;   // 2 lanes/row, 16 shorts (32 B) each
  f32x4 acc[2][8] = {{{0.f,0.f,0.f,0.f}}};
  for (int k0 = 0; k0 < DMODEL; k0 += 32) {
    {
      const u64* s = (const u64*)(hb + (m0 + srow)*DMODEL + k0 + sseg*16);
      u64 a=s[0], b=s[1], c=s[2], d=s[3];
      u64* dst = (u64*)(&Asl[srow*36 + sseg*16]);
      dst[0]=a; dst[1]=b; dst[2]=c; dst[3]=d;
    }
    {
      const u64* s = (const u64*)(Wt + (long)(n0 + srow)*DMODEL + k0 + sseg*16);
      u64 a=s[0], b=s[1], c=s[2], d=s[3];
      u64* dst = (u64*)(&Bsl[srow*36 + sseg*16]);
      dst[0]=a; dst[1]=b; dst[2]=c; dst[3]=d;
    }
    __syncthreads();
    bf16x8 af[2], bfr[8];
    #pragma unroll
    for (int mi=0;mi<2;mi++) af[mi] = ldfrag(&Asl[(w*32 + mi*16 + l16)*36 + q*8]);
    #pragma unroll
    for (int nj=0;nj<8;nj++) bfr[nj] = ldfrag(&Bsl[(nj*16 + l16)*36 + q*8]);
    #pragma unroll
    for (int mi=0;mi<2;mi++)
      #pragma unroll
      for (int nj=0;nj<8;nj++)
        acc[mi][nj] = __builtin_amdgcn_mfma_f32_16x16x32_bf16(af[mi], bfr[nj], acc[mi][nj], 0,0,0);
    __syncthreads();
  }
  if (n0 < DIN + CONVDIM) {
    // bounce each 64-row half through LDS, then full-line stores (4 thr/row x 32 shorts = 128)
    #pragma unroll
    for (int mi=0;mi<2;mi++){
      if (mi) __syncthreads();
      #pragma unroll
      for (int nj=0;nj<8;nj++){
        const int col = nj*16 + l16;
        #pragma unroll
        for (int r=0;r<4;r++){
          const int er = w*16 + q*4 + r;
          Ep[er*EPSTR + col] = f2bf(acc[mi][nj][r]);
        }
      }
      __syncthreads();
      {
        const int er2 = tid >> 2, seg = tid & 3;
        const long grow = m0 + (er2>>4)*32 + mi*16 + (er2&15);
        const u64* s = (const u64*)(Ep + er2*EPSTR + seg*32);
        u64 v0=s[0], v1=s[1], v2=s[2], v3=s[3], v4=s[4], v5=s[5], v6=s[6], v7=s[7];
        u64* dptr;
        if (n0 < DIN) dptr = (u64*)(zbuf + grow*DIN + n0 + seg*32);
        else          dptr = (u64*)(xbc + grow*CONVDIM + (n0 - DIN) + seg*32);
        dptr[0]=v0; dptr[1]=v1; dptr[2]=v2; dptr[3]=v3;
        dptr[4]=v4; dptr[5]=v5; dptr[6]=v6; dptr[7]=v7;
      }
    }
  } else {
    // dt tile: only cols 1152..1159 valid
    #pragma unroll
    for (int mi=0;mi<2;mi++){
      #pragma unroll
      for (int nj=0;nj<8;nj++){
        const int col = n0 + nj*16 + l16;
        if (col < DPROJ) {
          const int hh = col - (DIN + CONVDIM);
          #pragma unroll
          for (int r=0;r<4;r++){
            const long row = m0 + w*32 + mi*16 + q*4 + r;
            const float dv = acc[mi][nj][r] + dt_bias[hh];
            const float sp = dv > 20.f ? dv : log1pf(expf(dv));
            dtb[row*NH + hh] = sp;
            lab[row*NH + hh] = sp * (-expf(A_log[hh]));   // log dA
          }
        }
      }
    }
  }
}

// ---------------- out_proj fused: gnorm (y*silu(z), RMS) + GEMM + residual + LayerNorm ----------------
// RMS scale commutes through GEMM: out = scale_row * ((g*nw) @ W). 512 threads.
__global__ __launch_bounds__(512) void outproj_fused(const u16* __restrict__ yb,
    const u16* __restrict__ zb, const u16* __restrict__ Wt, u16* __restrict__ hb,
    const float* __restrict__ nw, const float* __restrict__ lnw, const float* __restrict__ lnb)
{
  __shared__ __align__(16) u16 Asl[128*36];
  __shared__ __align__(16) u16 Bsl[256*36];
  __shared__ float red[128][2][2];     // [row][colgroup][sum, sumsq] for LN
  __shared__ float red2[128][2];       // [row][seg] partial sum g^2 for RMS
  __shared__ float nwl[512];
  const int tid = threadIdx.x;
  const long m0 = (long)blockIdx.x * 128;
  const int w = tid >> 6, lane = tid & 63;
  const int q = lane >> 4, l16 = lane & 15;
  const int wr = (w >> 1) * 32;        // wave row base (0/32/64/96)
  const int wc = (w & 1) * 128;        // wave col base (0/128)
  const int srow = tid >> 1, sseg = tid & 1;   // staging: 2 threads/row, 16 shorts each
  if (tid < 512) nwl[tid] = nw[tid];
  __syncthreads();
  float sq = 0.f;
  f32x4 acc[2][8] = {{{0.f,0.f,0.f,0.f}}};
  for (int kk = 0; kk < 16; ++kk) {
    const int k0 = kk*32;
    if (tid < 256) {   // A staging: compute g = y*silu(z); stage g*nw bf16; accumulate g^2
      const u64* yp = (const u64*)(yb + (m0 + srow)*DIN + k0 + sseg*16);
      const u64* zp = (const u64*)(zb + (m0 + srow)*DIN + k0 + sseg*16);
      const u64 ys[4] = {yp[0], yp[1], yp[2], yp[3]};
      const u64 zs[4] = {zp[0], zp[1], zp[2], zp[3]};
      u16 gv[16];
      #pragma unroll
      for (int u=0;u<4;u++){
        #pragma unroll
        for (int j=0;j<4;j++){
          const float yv = bf2f((u16)(ys[u] >> (16*j)));
          const float zv = bf2f((u16)(zs[u] >> (16*j)));
          const float g = yv * siluf(zv);
          sq += g*g;
          gv[u*4+j] = f2bf(g * nwl[k0 + sseg*16 + u*4 + j]);
        }
      }
      const u64* gp = (const u64*)gv;
      u64* dst = (u64*)(&Asl[srow*36 + sseg*16]);
      dst[0]=gp[0]; dst[1]=gp[1]; dst[2]=gp[2]; dst[3]=gp[3];
    }
    {
      const u64* s = (const u64*)(Wt + (long)srow*DIN + k0 + sseg*16);
      u64 a=s[0], b=s[1], c=s[2], d=s[3];
      u64* dst = (u64*)(&Bsl[srow*36 + sseg*16]);
      dst[0]=a; dst[1]=b; dst[2]=c; dst[3]=d;
    }
    __syncthreads();
    bf16x8 af[2], bfr[8];
    #pragma unroll
    for (int mi=0;mi<2;mi++) af[mi] = ldfrag(&Asl[(wr + mi*16 + l16)*36 + q*8]);
    #pragma unroll
    for (int nj=0;nj<8;nj++) bfr[nj] = ldfrag(&Bsl[(wc + nj*16 + l16)*36 + q*8]);
    #pragma unroll
    for (int mi=0;mi<2;mi++)
      #pragma unroll
      for (int nj=0;nj<8;nj++)
        acc[mi][nj] = __builtin_amdgcn_mfma_f32_16x16x32_bf16(af[mi], bfr[nj], acc[mi][nj], 0,0,0);
    __syncthreads();
  }
  if (tid < 256) { red2[srow][sseg] = sq; }
  __syncthreads();
  // o = acc*rms_scale + resid(bf16) ; per-row LN stats via 16-lane shuffle + LDS combine
  #pragma unroll
  for (int mi=0;mi<2;mi++){
    #pragma unroll
    for (int r=0;r<4;r++){
      const int lrow = wr + mi*16 + q*4 + r;
      const float S2 = red2[lrow][0] + red2[lrow][1];
      const float rscale = rsqrtf(S2*(1.f/512.f) + 1e-5f);
      float s = 0.f, ss = 0.f;
      #pragma unroll
      for (int nj=0;nj<8;nj++){
        const int col = wc + nj*16 + l16;
        const float o = acc[mi][nj][r]*rscale + bf2f(hb[(m0+lrow)*DMODEL + col]);
        acc[mi][nj][r] = o;
        s += o; ss += o*o;
      }
      #pragma unroll
      for (int o2=1;o2<16;o2<<=1){ s += __shfl_xor(s,o2); ss += __shfl_xor(ss,o2); }
      if (l16 == 0) { red[lrow][w&1][0] = s; red[lrow][w&1][1] = ss; }
    }
  }
  __syncthreads();
  #pragma unroll
  for (int mi=0;mi<2;mi++){
    #pragma unroll
    for (int r=0;r<4;r++){
      const int lrow = wr + mi*16 + q*4 + r;
      const float S  = red[lrow][0][0] + red[lrow][1][0];
      const float SS = red[lrow][0][1] + red[lrow][1][1];
      const float mu = S * (1.f/256.f);
      const float var = SS * (1.f/256.f) - mu*mu;
      const float rs = rsqrtf(var + 1e-5f);
      #pragma unroll
      for (int nj=0;nj<8;nj++){
        const int col = wc + nj*16 + l16;
        const float v = (acc[mi][nj][r] - mu)*rs*lnw[col] + lnb[col];
        hb[(m0+lrow)*DMODEL + col] = f2bf(v);
      }
    }
  }
}

// ---------------- depthwise causal conv + SiLU: strip kernel ----------------
__global__ __launch_bounds__(256) void conv_kernel(const u16* __restrict__ xbc,
    const float* __restrict__ cw, const float* __restrict__ cb,
    u16* __restrict__ xsx, u16* __restrict__ Bb, u16* __restrict__ Cb)
{
  const long idx = (long)blockIdx.x * 256 + threadIdx.x;   // Mb*20 threads
  const int c4 = (int)(idx % 160) * 4;
  const long bt0 = (idx / 160) * 8;          // strip start (strips never cross batch)
  const int tseq = (int)(bt0 & (SEQ-1));
  const float4 b4 = *(const float4*)(cb + c4);
  const float4 w0v = *(const float4*)(cw + (c4+0)*4);
  const float4 w1v = *(const float4*)(cw + (c4+1)*4);
  const float4 w2v = *(const float4*)(cw + (c4+2)*4);
  const float4 w3v = *(const float4*)(cw + (c4+3)*4);
  const float W0[4] = {w0v.x,w0v.y,w0v.z,w0v.w};
  const float W1[4] = {w1v.x,w1v.y,w1v.z,w1v.w};
  const float W2[4] = {w2v.x,w2v.y,w2v.z,w2v.w};
  const float W3[4] = {w3v.x,w3v.y,w3v.z,w3v.w};
  float i0[11], i1[11], i2[11], i3[11];
  #pragma unroll
  for (int k = 0; k < 11; ++k) {
    u64 v = 0;
    if (tseq - 3 + k >= 0) v = *(const u64*)(xbc + (bt0 - 3 + k)*CONVDIM + c4);
    i0[k]=bf2f((u16)v); i1[k]=bf2f((u16)(v>>16)); i2[k]=bf2f((u16)(v>>32)); i3[k]=bf2f((u16)(v>>48));
  }
  u16* dst; long base; int stride;
  if (c4 < DIN)              { dst = xsx; base = bt0*DIN + c4;              stride = DIN; }
  else if (c4 < DIN+DSTATE)  { dst = Bb;  base = bt0*DSTATE + (c4-DIN);     stride = DSTATE; }
  else                       { dst = Cb;  base = bt0*DSTATE + (c4-DIN-DSTATE); stride = DSTATE; }
  #pragma unroll
  for (int j = 0; j < 8; ++j) {
    float a0=b4.x, a1=b4.y, a2=b4.z, a3=b4.w;
    #pragma unroll
    for (int k = 0; k < 4; ++k) {
      a0 += W0[k]*i0[j+k]; a1 += W1[k]*i1[j+k];
      a2 += W2[k]*i2[j+k]; a3 += W3[k]*i3[j+k];
    }
    a0=siluf(a0); a1=siluf(a1); a2=siluf(a2); a3=siluf(a3);
    const u64 r = (u64)f2bf(a0) | ((u64)f2bf(a1)<<16) | ((u64)f2bf(a2)<<32) | ((u64)f2bf(a3)<<48);
    *(u64*)(dst + base + (long)j*stride) = r;
  }
}

// ---------------- SSD phase A: per chunk-head local state via MFMA; Sloc bf16 ----------------
__global__ __launch_bounds__(256) void scanS_kernel(const u16* __restrict__ xsx,
    const u16* __restrict__ Bb, const float* __restrict__ lab, const float* __restrict__ dtb,
    u16* __restrict__ Sloc, float* __restrict__ Pb)
{
  __shared__ __align__(16) u16 Btr[64*STR128];   // [n][s]
  __shared__ __align__(16) u16 Uw[64*STR128];    // [p][s]
  __shared__ float cexpL[128];
  const int wg = blockIdx.x;
  const int c = wg & (NCHUNK-1), bh = wg >> 5, hh = bh & (NH-1), b = bh >> 3;
  const int tid = threadIdx.x;
  const long bt0 = (long)b*SEQ + c*CLEN;
  if (tid < 64) {   // wave 0: inclusive prefix of log dA over 128 steps
    float a0 = lab[(bt0+tid)*NH + hh];
    float a1 = lab[(bt0+64+tid)*NH + hh];
    const float d0 = dtb[(bt0+tid)*NH + hh];
    const float d1 = dtb[(bt0+64+tid)*NH + hh];
    #pragma unroll
    for (int o=1;o<64;o<<=1){
      const float t0=__shfl_up(a0,o), t1=__shfl_up(a1,o);
      if (tid>=o){a0+=t0;a1+=t1;}
    }
    a1 += __shfl(a0,63);
    const float ctot = __shfl(a1,63);
    cexpL[tid]    = d0*__expf(ctot - a0);
    cexpL[tid+64] = d1*__expf(ctot - a1);
    if (tid==0) Pb[wg] = __expf(ctot);
  }
  __syncthreads();
  {
    const int v = tid & 63, r0 = tid >> 6;
    #pragma unroll 4
    for (int k=0;k<32;k++){
      const int s = r0 + k*4;
      Btr[v*STR128 + s] = Bb[(bt0+s)*DSTATE + v];
      Uw[v*STR128 + s]  = f2bf(cexpL[s]*bf2f(xsx[(bt0+s)*DIN + hh*HD + v]));
    }
  }
  __syncthreads();
  const int w = tid>>6, lane = tid&63, q = lane>>4, l16 = lane&15;
  f32x4 acc[4] = {};
  #pragma unroll
  for (int ks=0;ks<4;ks++){
    const bf16x8 af = ldfrag(&Uw[(w*16+l16)*STR128 + ks*32 + q*8]);
    #pragma unroll
    for (int nj=0;nj<4;nj++){
      const bf16x8 bf = ldfrag(&Btr[(nj*16+l16)*STR128 + ks*32 + q*8]);
      acc[nj] = __builtin_amdgcn_mfma_f32_16x16x32_bf16(af, bf, acc[nj], 0,0,0);
    }
  }
  const long sb = (long)wg*4096;   // [wg][p][n] bf16
  #pragma unroll
  for (int nj=0;nj<4;nj++)
    #pragma unroll
    for (int r=0;r<4;r++)
      Sloc[sb + (w*16+q*4+r)*64 + nj*16 + l16] = f2bf(acc[nj][r]);
}

// Parallel combine over bf16 Sloc: run stays fp32 in registers
__global__ __launch_bounds__(64) void scanMid_kernel(u16* __restrict__ Sloc, const float* __restrict__ Pb)
{
  const int bh = blockIdx.x;
  const int rr = blockIdx.y;
  const int p  = threadIdx.x;
  float run = 0.f;
  for (int c = 0; c < NCHUNK; ++c) {
    const long base = ((long)(bh*NCHUNK + c))*4096 + rr*64 + p;
    const float Pc = Pb[bh*NCHUNK + c];
    const float tmp = bf2f(Sloc[base]);
    Sloc[base] = f2bf(run);
    run = run*Pc + tmp;
  }
}

// ---------------- SSD phase C: Y = ((C Bt) o L) U + diag(exp(cum)) (C h0) + D*x ; coalesced y out ----------------
__global__ __launch_bounds__(512) void scanY_kernel(const u16* __restrict__ xsx,
    u16* __restrict__ yg, const u16* __restrict__ Bb, const u16* __restrict__ Cb,
    const float* __restrict__ lab, const float* __restrict__ dtb,
    const u16* __restrict__ Sinit, const float* __restrict__ Dp)
{
  __shared__ __align__(16) u16 pool[2*128*STR64];  // Bs | Cs; overlaid by Ms[t][s]; then by y-bounce
  __shared__ __align__(16) u16 Ut[64*STR128];      // [p][s]
  __shared__ __align__(16) u16 h0t[64*STR64];      // [p][n]
  __shared__ float cumL[128];
  __shared__ float dtL[128];
  u16* Bs = pool;
  u16* Cs = pool + 128*STR64;
  u16* Ms = pool;

  const int wg = blockIdx.x;
  const int c = wg & (NCHUNK-1), bh = wg >> 5, hh = bh & (NH-1), b = bh >> 3;
  const int tid = threadIdx.x;
  const long bt0 = (long)b*SEQ + c*CLEN;

  if (tid < 64) {
    float a0 = lab[(bt0+tid)*NH + hh];
    float a1 = lab[(bt0+64+tid)*NH + hh];
    dtL[tid]    = dtb[(bt0+tid)*NH + hh];
    dtL[tid+64] = dtb[(bt0+64+tid)*NH + hh];
    #pragma unroll
    for (int o=1;o<64;o<<=1){
      const float t0=__shfl_up(a0,o), t1=__shfl_up(a1,o);
      if (tid>=o){a0+=t0;a1+=t1;}
    }
    a1 += __shfl(a0,63);
    cumL[tid]=a0; cumL[tid+64]=a1;
  }
  __syncthreads();
  {
    const int n = tid & 63, r0 = tid >> 6;   // 512 threads: r0 in 0..7
    #pragma unroll 4
    for (int k=0;k<16;k++){
      const int s = r0 + k*8;
      Bs[s*STR64 + n] = Bb[(bt0+s)*DSTATE + n];
      Cs[s*STR64 + n] = Cb[(bt0+s)*DSTATE + n];
      Ut[n*STR128 + s] = f2bf(dtL[s]*bf2f(xsx[(bt0+s)*DIN + hh*HD + n]));
    }
    const int n0 = r0*8;
    // h0 bf16: 8 states = 16 B = two u64 copies
    const u64* sp = (const u64*)(Sinit + (long)wg*4096 + n*64 + n0);
    u64* dp = (u64*)(h0t + n*STR64 + n0);
    dp[0] = sp[0]; dp[1] = sp[1];
  }
  __syncthreads();

  const int w = tid>>6, lane = tid&63, q = lane>>4, l16 = lane&15;
  f32x4 accG[8] = {};
  f32x4 accI[4] = {};
  #pragma unroll
  for (int ks=0;ks<2;ks++){
    const bf16x8 af = ldfrag(&Cs[(w*16+l16)*STR64 + ks*32 + q*8]);
    #pragma unroll
    for (int nj=0;nj<8;nj++)
      accG[nj] = __builtin_amdgcn_mfma_f32_16x16x32_bf16(af, ldfrag(&Bs[(nj*16+l16)*STR64 + ks*32 + q*8]), accG[nj], 0,0,0);
    #pragma unroll
    for (int nj=0;nj<4;nj++)
      accI[nj] = __builtin_amdgcn_mfma_f32_16x16x32_bf16(af, ldfrag(&h0t[(nj*16+l16)*STR64 + ks*32 + q*8]), accI[nj], 0,0,0);
  }
  __syncthreads();
  #pragma unroll
  for (int nj=0;nj<8;nj++){
    const int s = nj*16 + l16;
    #pragma unroll
    for (int r=0;r<4;r++){
      const int t = w*16 + q*4 + r;
      const float v = (s<=t) ? accG[nj][r]*__expf(cumL[t]-cumL[s]) : 0.f;
      Ms[t*STR128 + s] = f2bf(v);
    }
  }
  __syncthreads();
  f32x4 accY[4] = {};
  #pragma unroll
  for (int ks=0;ks<4;ks++){
    const bf16x8 af = ldfrag(&Ms[(w*16+l16)*STR128 + ks*32 + q*8]);
    #pragma unroll
    for (int nj=0;nj<4;nj++)
      accY[nj] = __builtin_amdgcn_mfma_f32_16x16x32_bf16(af, ldfrag(&Ut[(nj*16+l16)*STR128 + ks*32 + q*8]), accY[nj], 0,0,0);
  }
  const float Dv = Dp[hh];
  __syncthreads();   // Ms reads done; reuse pool as y-bounce [128][STR64]
  #pragma unroll
  for (int nj=0;nj<4;nj++){
    const int p = nj*16 + l16;
    #pragma unroll
    for (int r=0;r<4;r++){
      const int t = w*16 + q*4 + r;
      const float xv = bf2f(xsx[(bt0+t)*DIN + hh*HD + p]);
      pool[t*STR64 + p] = f2bf(accY[nj][r] + __expf(cumL[t])*accI[nj][r] + Dv*xv);
    }
  }
  __syncthreads();
  {
    const int row = tid >> 2, seg = tid & 3;
    const u64* s = (const u64*)(pool + row*STR64 + seg*16);
    u64 a=s[0], b2=s[1], c2=s[2], d=s[3];
    u64* dptr = (u64*)(yg + (bt0+row)*DIN + hh*HD + seg*16);
    dptr[0]=a; dptr[1]=b2; dptr[2]=c2; dptr[3]=d;
  }
}

// ---------------- decoder: hb bf16 in, fp32 out ----------------
__global__ __launch_bounds__(64) void dec_kernel(const u16* __restrict__ hb,
    const float* __restrict__ W, const float* __restrict__ bias, float* __restrict__ out)
{
  const int wg = blockIdx.x;
  const int b = wg / 10, o = wg % 10;
  const int lane = threadIdx.x;
  const u16* r = hb + ((long)b*SEQ + SEQ-1)*DMODEL;
  float s = 0.f;
  #pragma unroll
  for (int q=0;q<4;q++){ const int k = lane + q*64; s += bf2f(r[k])*W[k*10+o]; }
  #pragma unroll
  for (int o2=32;o2;o2>>=1) s += __shfl_down(s, o2);
  if (lane == 0) out[wg] = s + bias[o];
}

extern "C" void kernel_launch(void* const* d_in, const int* in_sizes, int n_in,
                              void* d_out, int out_size, void* d_ws, size_t ws_size,
                              hipStream_t stream) {
  const float* x        = (const float*)d_in[0];
  const float* enc_w    = (const float*)d_in[1];
  const float* enc_b    = (const float*)d_in[2];
  const float* in_proj  = (const float*)d_in[3];
  const float* conv_w   = (const float*)d_in[4];
  const float* conv_b   = (const float*)d_in[5];
  const float* dt_bias  = (const float*)d_in[6];
  const float* A_log    = (const float*)d_in[7];
  const float* Dp       = (const float*)d_in[8];
  const float* norm_w   = (const float*)d_in[9];
  const float* out_proj = (const float*)d_in[10];
  const float* ln_w     = (const float*)d_in[11];
  const float* ln_b     = (const float*)d_in[12];
  const float* dec_w    = (const float*)d_in[13];
  const float* dec_b    = (const float*)d_in[14];
  float* out = (float*)d_out;

  float* ws = (float*)d_ws;
  u16* WtIn  = (u16*)ws;                       // 2*NPAD*256 shorts = 655360
  u16* WtOut = WtIn + (long)2*NPAD*DMODEL;     // 2*256*512 shorts = 262144
  float* gbase = ws + 327680 + 131072;         // = ws + 458752 floats

  // Per-token fp32-equivalents: hb 128 + z 256 + xbc 320 + xsx 256 + yg 256
  //                             + Bb 32 + Cb 32 + dtb 8 + lab 8 = 1296
  int NB = 8;
  while (NB > 1) {
    const long Mb = (long)NB * SEQ;
    const long bytes = (458752L + Mb * 1296L + 4096) * 4;
    if ((size_t)bytes <= ws_size) break;
    NB >>= 1;
  }
  const long Mb = (long)NB * SEQ;

  u16*   hb   = (u16*)gbase;              // Mb*256 u16 (residual stream, bf16 only)
  u16*   zbuf = hb + Mb*DMODEL;           // Mb*512 u16
  u16*   xbc  = zbuf + Mb*DIN;            // Mb*640 u16 ; aliased by Sloc (Mb*256 u16)
  u16*   xsx  = xbc + Mb*CONVDIM;         // Mb*512 u16
  u16*   yg   = xsx + Mb*DIN;             // Mb*512 u16 (y)
  u16*   Bb   = yg + Mb*DIN;              // Mb*64 u16
  u16*   Cb   = Bb + Mb*DSTATE;           // Mb*64 u16
  float* dtb  = (float*)(Cb + Mb*DSTATE); // Mb*8 f
  float* lab  = dtb + Mb*NH;              // Mb*8 f (log dA)
  float* Pb   = lab + Mb*NH;              // <= 2048
  u16*   Sloc = xbc;                      // alias: xbc dead after conv; Mb*256 u16

  cvt_inw <<<dim3(2*NPAD),   dim3(256), 0, stream>>>(in_proj,  WtIn);
  cvt_outw<<<dim3(2*DMODEL), dim3(256), 0, stream>>>(out_proj, WtOut);

  const int ngroups = B_SZ / NB;
  for (int g = 0; g < ngroups; ++g) {
    const float* xg = x + (long)g*NB*SEQ*64;

    enc_kernel<<<dim3((int)(Mb/32)), dim3(256), 0, stream>>>(xg, enc_w, enc_b, hb);

    for (int l = 0; l < 2; ++l) {
      inproj_mfma<<<dim3(NPAD/128, (int)(Mb/128)), dim3(256), 0, stream>>>(
          hb, WtIn + (long)l*NPAD*DMODEL, zbuf, xbc, dtb, lab,
          dt_bias + l*NH, A_log + l*NH);
      conv_kernel<<<dim3((int)(Mb*20/256)), dim3(256), 0, stream>>>(
          xbc, conv_w + (long)l*CONVDIM*4, conv_b + (long)l*CONVDIM, xsx, Bb, Cb);
      scanS_kernel<<<dim3(NB*8*NCHUNK), dim3(256), 0, stream>>>(xsx, Bb, lab, dtb, Sloc, Pb);
      scanMid_kernel<<<dim3(NB*8, 64), dim3(64), 0, stream>>>(Sloc, Pb);
      scanY_kernel<<<dim3(NB*8*NCHUNK), dim3(512), 0, stream>>>(xsx, yg, Bb, Cb, lab, dtb, Sloc, Dp + l*NH);
      outproj_fused<<<dim3((int)(Mb/128)), dim3(512), 0, stream>>>(
          yg, zbuf, WtOut + (long)l*DMODEL*DIN, hb,
          norm_w + (long)l*DIN, ln_w + l*DMODEL, ln_b + l*DMODEL);
    }

    dec_kernel<<<dim3(NB*10), dim3(64), 0, stream>>>(hb, dec_w, dec_b, out + (long)g*NB*10);
  }
}

// Round 19
// 470.681 us; speedup vs baseline: 1.5318x; 1.0137x over previous
//
#include <hip/hip_runtime.h>
#include <hip/hip_bf16.h>
#include <math.h>

// ---- model constants ----
#define B_SZ    8
#define SEQ     4096
#define DMODEL  256
#define DIN     512     // d_inner
#define DSTATE  64
#define NH      8
#define HD      64
#define CONVDIM 640
#define DPROJ   1160
#define NPAD    1280    // DPROJ padded to 10*128
#define NCHUNK  32      // scan chunks per (b,h)
#define CLEN    128     // SEQ / NCHUNK
#define STR64   68      // LDS row stride (shorts) for K=64 tiles
#define STR128  132     // LDS row stride (shorts) for K=128 tiles
#define EPSTR   140     // epilogue bounce stride

typedef unsigned long long u64;
typedef unsigned int u32;
typedef unsigned short u16;
typedef __attribute__((ext_vector_type(8))) short bf16x8;
typedef __attribute__((ext_vector_type(4))) float f32x4;

__device__ __forceinline__ float siluf(float v){ return v / (1.f + __expf(-v)); }   // native v_exp
__device__ __forceinline__ u16 f2bf(float f){ __hip_bfloat16 h = __float2bfloat16(f); return *(u16*)&h; }
__device__ __forceinline__ float bf2f(u16 u){ union{u32 i; float f;} t; t.i = ((u32)u)<<16; return t.f; }
__device__ __forceinline__ bf16x8 ldfrag(const u16* base){
  union { u64 u[2]; bf16x8 v; } t;
  const u64* p = (const u64*)base;
  t.u[0] = p[0]; t.u[1] = p[1];
  return t.v;
}

// ---------------- weight conversion (once per launch) ----------------
__global__ __launch_bounds__(256) void cvt_inw(const float* __restrict__ W, u16* __restrict__ Wt)
{
  const int blk = blockIdx.x;
  const int l = blk / NPAD, n = blk % NPAD;
  const int k = threadIdx.x;
  float v = 0.f;
  if (n < DPROJ) v = W[((long)l*DMODEL + k)*DPROJ + n];
  Wt[((long)l*NPAD + n)*DMODEL + k] = f2bf(v);
}

__global__ __launch_bounds__(256) void cvt_outw(const float* __restrict__ W, u16* __restrict__ Wt)
{
  const int blk = blockIdx.x;
  const int l = blk / DMODEL, n = blk % DMODEL;
  #pragma unroll
  for (int q = 0; q < 2; ++q) {
    const int k = threadIdx.x + q*256;
    const float v = W[((long)l*DIN + k)*DMODEL + n];
    Wt[((long)l*DMODEL + n)*DIN + k] = f2bf(v);
  }
}

// ---------------- encoder GEMM; writes hb bf16 ----------------
__global__ __launch_bounds__(256) void enc_kernel(const float* __restrict__ x,
    const float* __restrict__ W, const float* __restrict__ bias, u16* __restrict__ hb)
{
  __shared__ float xl[32*64];
  const int tid = threadIdx.x;
  const long t0 = (long)blockIdx.x * 32;
  for (int i = tid; i < 32*64; i += 256) xl[i] = x[t0*64 + i];
  __syncthreads();
  float acc[32];
  const float bv = bias[tid];
  #pragma unroll
  for (int tok = 0; tok < 32; ++tok) acc[tok] = bv;
  for (int k = 0; k < 64; ++k) {
    const float wv = W[k*DMODEL + tid];
    #pragma unroll
    for (int tok = 0; tok < 32; ++tok) acc[tok] += xl[tok*64 + k] * wv;
  }
  #pragma unroll
  for (int tok = 0; tok < 32; ++tok)
    hb[(t0 + tok)*DMODEL + tid] = f2bf(acc[tok]);
}

// ---------------- in_proj MFMA GEMM 128x128 tile, BK=32 ----------------
// Grid (Mb/128, 10), m fastest: linear id = col*256+m -> XCD = m%8, so all 10 col-tiles
// of one m-strip share an XCD and its L2-cached A-strip (R16-measured FETCH ~33 MB).
__global__ __launch_bounds__(256) void inproj_mfma(const u16* __restrict__ hb,
    const u16* __restrict__ Wt, u16* __restrict__ zbuf, u16* __restrict__ xbc,
    float* __restrict__ dtb, float* __restrict__ lab,
    const float* __restrict__ dt_bias, const float* __restrict__ A_log)
{
  __shared__ __align__(16) u16 pool[128*36*2];   // staging Asl|Bsl; epilogue bounce aliases it
  u16* Asl = pool;
  u16* Bsl = pool + 128*36;
  u16* Ep  = pool;                               // [64][EPSTR] u16 per mi-half (8960 <= 9216)
  const int tid = threadIdx.x;
  const long m0 = (long)blockIdx.x * 128;
  const int n0 = blockIdx.y * 128;
  const int w = tid >> 6, lane = tid & 63;
  const int q = lane >> 4, l16 = lane & 15;
  const int srow = tid >> 1, sseg = tid & 1;   // 2 lanes/row, 16 shorts (32 B) each
  f32x4 acc[2][8] = {{{0.f,0.f,0.f,0.f}}};
  for (int k0 = 0; k0 < DMODEL; k0 += 32) {
    {
      const u64* s = (const u64*)(hb + (m0 + srow)*DMODEL + k0 + sseg*16);
      u64 a=s[0], b=s[1], c=s[2], d=s[3];
      u64* dst = (u64*)(&Asl[srow*36 + sseg*16]);
      dst[0]=a; dst[1]=b; dst[2]=c; dst[3]=d;
    }
    {
      const u64* s = (const u64*)(Wt + (long)(n0 + srow)*DMODEL + k0 + sseg*16);
      u64 a=s[0], b=s[1], c=s[2], d=s[3];
      u64* dst = (u64*)(&Bsl[srow*36 + sseg*16]);
      dst[0]=a; dst[1]=b; dst[2]=c; dst[3]=d;
    }
    __syncthreads();
    bf16x8 af[2], bfr[8];
    #pragma unroll
    for (int mi=0;mi<2;mi++) af[mi] = ldfrag(&Asl[(w*32 + mi*16 + l16)*36 + q*8]);
    #pragma unroll
    for (int nj=0;nj<8;nj++) bfr[nj] = ldfrag(&Bsl[(nj*16 + l16)*36 + q*8]);
    #pragma unroll
    for (int mi=0;mi<2;mi++)
      #pragma unroll
      for (int nj=0;nj<8;nj++)
        acc[mi][nj] = __builtin_amdgcn_mfma_f32_16x16x32_bf16(af[mi], bfr[nj], acc[mi][nj], 0,0,0);
    __syncthreads();
  }
  if (n0 < DIN + CONVDIM) {
    // bounce each 64-row half through LDS, then full-line stores (4 thr/row x 32 shorts = 128)
    #pragma unroll
    for (int mi=0;mi<2;mi++){
      if (mi) __syncthreads();
      #pragma unroll
      for (int nj=0;nj<8;nj++){
        const int col = nj*16 + l16;
        #pragma unroll
        for (int r=0;r<4;r++){
          const int er = w*16 + q*4 + r;
          Ep[er*EPSTR + col] = f2bf(acc[mi][nj][r]);
        }
      }
      __syncthreads();
      {
        const int er2 = tid >> 2, seg = tid & 3;
        const long grow = m0 + (er2>>4)*32 + mi*16 + (er2&15);
        const u64* s = (const u64*)(Ep + er2*EPSTR + seg*32);
        u64 v0=s[0], v1=s[1], v2=s[2], v3=s[3], v4=s[4], v5=s[5], v6=s[6], v7=s[7];
        u64* dptr;
        if (n0 < DIN) dptr = (u64*)(zbuf + grow*DIN + n0 + seg*32);
        else          dptr = (u64*)(xbc + grow*CONVDIM + (n0 - DIN) + seg*32);
        dptr[0]=v0; dptr[1]=v1; dptr[2]=v2; dptr[3]=v3;
        dptr[4]=v4; dptr[5]=v5; dptr[6]=v6; dptr[7]=v7;
      }
    }
  } else {
    // dt tile: only cols 1152..1159 valid
    #pragma unroll
    for (int mi=0;mi<2;mi++){
      #pragma unroll
      for (int nj=0;nj<8;nj++){
        const int col = n0 + nj*16 + l16;
        if (col < DPROJ) {
          const int hh = col - (DIN + CONVDIM);
          #pragma unroll
          for (int r=0;r<4;r++){
            const long row = m0 + w*32 + mi*16 + q*4 + r;
            const float dv = acc[mi][nj][r] + dt_bias[hh];
            const float sp = dv > 20.f ? dv : log1pf(expf(dv));
            dtb[row*NH + hh] = sp;
            lab[row*NH + hh] = sp * (-expf(A_log[hh]));   // log dA
          }
        }
      }
    }
  }
}

// ---------------- out_proj fused: gnorm (y*silu(z), RMS) + GEMM + residual + LayerNorm ----------------
// RMS scale commutes through GEMM: out = scale_row * ((g*nw) @ W). 512 threads.
__global__ __launch_bounds__(512) void outproj_fused(const u16* __restrict__ yb,
    const u16* __restrict__ zb, const u16* __restrict__ Wt, u16* __restrict__ hb,
    const float* __restrict__ nw, const float* __restrict__ lnw, const float* __restrict__ lnb)
{
  __shared__ __align__(16) u16 Asl[128*36];
  __shared__ __align__(16) u16 Bsl[256*36];
  __shared__ float red[128][2][2];     // [row][colgroup][sum, sumsq] for LN
  __shared__ float red2[128][2];       // [row][seg] partial sum g^2 for RMS
  __shared__ float nwl[512];
  const int tid = threadIdx.x;
  const long m0 = (long)blockIdx.x * 128;
  const int w = tid >> 6, lane = tid & 63;
  const int q = lane >> 4, l16 = lane & 15;
  const int wr = (w >> 1) * 32;        // wave row base (0/32/64/96)
  const int wc = (w & 1) * 128;        // wave col base (0/128)
  const int srow = tid >> 1, sseg = tid & 1;   // staging: 2 threads/row, 16 shorts each
  if (tid < 512) nwl[tid] = nw[tid];
  __syncthreads();
  float sq = 0.f;
  f32x4 acc[2][8] = {{{0.f,0.f,0.f,0.f}}};
  for (int kk = 0; kk < 16; ++kk) {
    const int k0 = kk*32;
    if (tid < 256) {   // A staging: compute g = y*silu(z); stage g*nw bf16; accumulate g^2
      const u64* yp = (const u64*)(yb + (m0 + srow)*DIN + k0 + sseg*16);
      const u64* zp = (const u64*)(zb + (m0 + srow)*DIN + k0 + sseg*16);
      const u64 ys[4] = {yp[0], yp[1], yp[2], yp[3]};
      const u64 zs[4] = {zp[0], zp[1], zp[2], zp[3]};
      u16 gv[16];
      #pragma unroll
      for (int u=0;u<4;u++){
        #pragma unroll
        for (int j=0;j<4;j++){
          const float yv = bf2f((u16)(ys[u] >> (16*j)));
          const float zv = bf2f((u16)(zs[u] >> (16*j)));
          const float g = yv * siluf(zv);
          sq += g*g;
          gv[u*4+j] = f2bf(g * nwl[k0 + sseg*16 + u*4 + j]);
        }
      }
      const u64* gp = (const u64*)gv;
      u64* dst = (u64*)(&Asl[srow*36 + sseg*16]);
      dst[0]=gp[0]; dst[1]=gp[1]; dst[2]=gp[2]; dst[3]=gp[3];
    }
    {
      const u64* s = (const u64*)(Wt + (long)srow*DIN + k0 + sseg*16);
      u64 a=s[0], b=s[1], c=s[2], d=s[3];
      u64* dst = (u64*)(&Bsl[srow*36 + sseg*16]);
      dst[0]=a; dst[1]=b; dst[2]=c; dst[3]=d;
    }
    __syncthreads();
    bf16x8 af[2], bfr[8];
    #pragma unroll
    for (int mi=0;mi<2;mi++) af[mi] = ldfrag(&Asl[(wr + mi*16 + l16)*36 + q*8]);
    #pragma unroll
    for (int nj=0;nj<8;nj++) bfr[nj] = ldfrag(&Bsl[(wc + nj*16 + l16)*36 + q*8]);
    #pragma unroll
    for (int mi=0;mi<2;mi++)
      #pragma unroll
      for (int nj=0;nj<8;nj++)
        acc[mi][nj] = __builtin_amdgcn_mfma_f32_16x16x32_bf16(af[mi], bfr[nj], acc[mi][nj], 0,0,0);
    __syncthreads();
  }
  if (tid < 256) { red2[srow][sseg] = sq; }
  __syncthreads();
  // o = acc*rms_scale + resid(bf16) ; per-row LN stats via 16-lane shuffle + LDS combine
  #pragma unroll
  for (int mi=0;mi<2;mi++){
    #pragma unroll
    for (int r=0;r<4;r++){
      const int lrow = wr + mi*16 + q*4 + r;
      const float S2 = red2[lrow][0] + red2[lrow][1];
      const float rscale = rsqrtf(S2*(1.f/512.f) + 1e-5f);
      float s = 0.f, ss = 0.f;
      #pragma unroll
      for (int nj=0;nj<8;nj++){
        const int col = wc + nj*16 + l16;
        const float o = acc[mi][nj][r]*rscale + bf2f(hb[(m0+lrow)*DMODEL + col]);
        acc[mi][nj][r] = o;
        s += o; ss += o*o;
      }
      #pragma unroll
      for (int o2=1;o2<16;o2<<=1){ s += __shfl_xor(s,o2); ss += __shfl_xor(ss,o2); }
      if (l16 == 0) { red[lrow][w&1][0] = s; red[lrow][w&1][1] = ss; }
    }
  }
  __syncthreads();
  #pragma unroll
  for (int mi=0;mi<2;mi++){
    #pragma unroll
    for (int r=0;r<4;r++){
      const int lrow = wr + mi*16 + q*4 + r;
      const float S  = red[lrow][0][0] + red[lrow][1][0];
      const float SS = red[lrow][0][1] + red[lrow][1][1];
      const float mu = S * (1.f/256.f);
      const float var = SS * (1.f/256.f) - mu*mu;
      const float rs = rsqrtf(var + 1e-5f);
      #pragma unroll
      for (int nj=0;nj<8;nj++){
        const int col = wc + nj*16 + l16;
        const float v = (acc[mi][nj][r] - mu)*rs*lnw[col] + lnb[col];
        hb[(m0+lrow)*DMODEL + col] = f2bf(v);
      }
    }
  }
}

// ---------------- depthwise causal conv + SiLU: strip kernel ----------------
__global__ __launch_bounds__(256) void conv_kernel(const u16* __restrict__ xbc,
    const float* __restrict__ cw, const float* __restrict__ cb,
    u16* __restrict__ xsx, u16* __restrict__ Bb, u16* __restrict__ Cb)
{
  const long idx = (long)blockIdx.x * 256 + threadIdx.x;   // Mb*20 threads
  const int c4 = (int)(idx % 160) * 4;
  const long bt0 = (idx / 160) * 8;          // strip start (strips never cross batch)
  const int tseq = (int)(bt0 & (SEQ-1));
  const float4 b4 = *(const float4*)(cb + c4);
  const float4 w0v = *(const float4*)(cw + (c4+0)*4);
  const float4 w1v = *(const float4*)(cw + (c4+1)*4);
  const float4 w2v = *(const float4*)(cw + (c4+2)*4);
  const float4 w3v = *(const float4*)(cw + (c4+3)*4);
  const float W0[4] = {w0v.x,w0v.y,w0v.z,w0v.w};
  const float W1[4] = {w1v.x,w1v.y,w1v.z,w1v.w};
  const float W2[4] = {w2v.x,w2v.y,w2v.z,w2v.w};
  const float W3[4] = {w3v.x,w3v.y,w3v.z,w3v.w};
  float i0[11], i1[11], i2[11], i3[11];
  #pragma unroll
  for (int k = 0; k < 11; ++k) {
    u64 v = 0;
    if (tseq - 3 + k >= 0) v = *(const u64*)(xbc + (bt0 - 3 + k)*CONVDIM + c4);
    i0[k]=bf2f((u16)v); i1[k]=bf2f((u16)(v>>16)); i2[k]=bf2f((u16)(v>>32)); i3[k]=bf2f((u16)(v>>48));
  }
  u16* dst; long base; int stride;
  if (c4 < DIN)              { dst = xsx; base = bt0*DIN + c4;              stride = DIN; }
  else if (c4 < DIN+DSTATE)  { dst = Bb;  base = bt0*DSTATE + (c4-DIN);     stride = DSTATE; }
  else                       { dst = Cb;  base = bt0*DSTATE + (c4-DIN-DSTATE); stride = DSTATE; }
  #pragma unroll
  for (int j = 0; j < 8; ++j) {
    float a0=b4.x, a1=b4.y, a2=b4.z, a3=b4.w;
    #pragma unroll
    for (int k = 0; k < 4; ++k) {
      a0 += W0[k]*i0[j+k]; a1 += W1[k]*i1[j+k];
      a2 += W2[k]*i2[j+k]; a3 += W3[k]*i3[j+k];
    }
    a0=siluf(a0); a1=siluf(a1); a2=siluf(a2); a3=siluf(a3);
    const u64 r = (u64)f2bf(a0) | ((u64)f2bf(a1)<<16) | ((u64)f2bf(a2)<<32) | ((u64)f2bf(a3)<<48);
    *(u64*)(dst + base + (long)j*stride) = r;
  }
}

// ---------------- SSD phase A: per chunk-head local state via MFMA; Sloc bf16 ----------------
__global__ __launch_bounds__(256) void scanS_kernel(const u16* __restrict__ xsx,
    const u16* __restrict__ Bb, const float* __restrict__ lab, const float* __restrict__ dtb,
    u16* __restrict__ Sloc, float* __restrict__ Pb)
{
  __shared__ __align__(16) u16 Btr[64*STR128];   // [n][s]
  __shared__ __align__(16) u16 Uw[64*STR128];    // [p][s]
  __shared__ float cexpL[128];
  const int wg = blockIdx.x;
  const int c = wg & (NCHUNK-1), bh = wg >> 5, hh = bh & (NH-1), b = bh >> 3;
  const int tid = threadIdx.x;
  const long bt0 = (long)b*SEQ + c*CLEN;
  if (tid < 64) {   // wave 0: inclusive prefix of log dA over 128 steps
    float a0 = lab[(bt0+tid)*NH + hh];
    float a1 = lab[(bt0+64+tid)*NH + hh];
    const float d0 = dtb[(bt0+tid)*NH + hh];
    const float d1 = dtb[(bt0+64+tid)*NH + hh];
    #pragma unroll
    for (int o=1;o<64;o<<=1){
      const float t0=__shfl_up(a0,o), t1=__shfl_up(a1,o);
      if (tid>=o){a0+=t0;a1+=t1;}
    }
    a1 += __shfl(a0,63);
    const float ctot = __shfl(a1,63);
    cexpL[tid]    = d0*__expf(ctot - a0);
    cexpL[tid+64] = d1*__expf(ctot - a1);
    if (tid==0) Pb[wg] = __expf(ctot);
  }
  __syncthreads();
  {
    const int v = tid & 63, r0 = tid >> 6;
    #pragma unroll 4
    for (int k=0;k<32;k++){
      const int s = r0 + k*4;
      Btr[v*STR128 + s] = Bb[(bt0+s)*DSTATE + v];
      Uw[v*STR128 + s]  = f2bf(cexpL[s]*bf2f(xsx[(bt0+s)*DIN + hh*HD + v]));
    }
  }
  __syncthreads();
  const int w = tid>>6, lane = tid&63, q = lane>>4, l16 = lane&15;
  f32x4 acc[4] = {};
  #pragma unroll
  for (int ks=0;ks<4;ks++){
    const bf16x8 af = ldfrag(&Uw[(w*16+l16)*STR128 + ks*32 + q*8]);
    #pragma unroll
    for (int nj=0;nj<4;nj++){
      const bf16x8 bf = ldfrag(&Btr[(nj*16+l16)*STR128 + ks*32 + q*8]);
      acc[nj] = __builtin_amdgcn_mfma_f32_16x16x32_bf16(af, bf, acc[nj], 0,0,0);
    }
  }
  const long sb = (long)wg*4096;   // [wg][p][n] bf16
  #pragma unroll
  for (int nj=0;nj<4;nj++)
    #pragma unroll
    for (int r=0;r<4;r++)
      Sloc[sb + (w*16+q*4+r)*64 + nj*16 + l16] = f2bf(acc[nj][r]);
}

// Parallel combine over bf16 Sloc: run stays fp32 in registers
__global__ __launch_bounds__(64) void scanMid_kernel(u16* __restrict__ Sloc, const float* __restrict__ Pb)
{
  const int bh = blockIdx.x;
  const int rr = blockIdx.y;
  const int p  = threadIdx.x;
  float run = 0.f;
  for (int c = 0; c < NCHUNK; ++c) {
    const long base = ((long)(bh*NCHUNK + c))*4096 + rr*64 + p;
    const float Pc = Pb[bh*NCHUNK + c];
    const float tmp = bf2f(Sloc[base]);
    Sloc[base] = f2bf(run);
    run = run*Pc + tmp;
  }
}

// ---------------- SSD phase C: Y = ((C Bt) o L) U + diag(exp(cum)) (C h0) + D*x ; coalesced y out ----------------
// Epilogue recovers x = Ut/dt from LDS (Ut = bf16(dt*x), dt = softplus > 0) -> no 2nd global xsx read.
__global__ __launch_bounds__(512) void scanY_kernel(const u16* __restrict__ xsx,
    u16* __restrict__ yg, const u16* __restrict__ Bb, const u16* __restrict__ Cb,
    const float* __restrict__ lab, const float* __restrict__ dtb,
    const u16* __restrict__ Sinit, const float* __restrict__ Dp)
{
  __shared__ __align__(16) u16 pool[2*128*STR64];  // Bs | Cs; overlaid by Ms[t][s]; then by y-bounce
  __shared__ __align__(16) u16 Ut[64*STR128];      // [p][s]
  __shared__ __align__(16) u16 h0t[64*STR64];      // [p][n]
  __shared__ float cumL[128];
  __shared__ float dtL[128];
  u16* Bs = pool;
  u16* Cs = pool + 128*STR64;
  u16* Ms = pool;

  const int wg = blockIdx.x;
  const int c = wg & (NCHUNK-1), bh = wg >> 5, hh = bh & (NH-1), b = bh >> 3;
  const int tid = threadIdx.x;
  const long bt0 = (long)b*SEQ + c*CLEN;

  if (tid < 64) {
    float a0 = lab[(bt0+tid)*NH + hh];
    float a1 = lab[(bt0+64+tid)*NH + hh];
    dtL[tid]    = dtb[(bt0+tid)*NH + hh];
    dtL[tid+64] = dtb[(bt0+64+tid)*NH + hh];
    #pragma unroll
    for (int o=1;o<64;o<<=1){
      const float t0=__shfl_up(a0,o), t1=__shfl_up(a1,o);
      if (tid>=o){a0+=t0;a1+=t1;}
    }
    a1 += __shfl(a0,63);
    cumL[tid]=a0; cumL[tid+64]=a1;
  }
  __syncthreads();
  {
    const int n = tid & 63, r0 = tid >> 6;   // 512 threads: r0 in 0..7
    #pragma unroll 4
    for (int k=0;k<16;k++){
      const int s = r0 + k*8;
      Bs[s*STR64 + n] = Bb[(bt0+s)*DSTATE + n];
      Cs[s*STR64 + n] = Cb[(bt0+s)*DSTATE + n];
      Ut[n*STR128 + s] = f2bf(dtL[s]*bf2f(xsx[(bt0+s)*DIN + hh*HD + n]));
    }
    const int n0 = r0*8;
    // h0 bf16: 8 states = 16 B = two u64 copies
    const u64* sp = (const u64*)(Sinit + (long)wg*4096 + n*64 + n0);
    u64* dp = (u64*)(h0t + n*STR64 + n0);
    dp[0] = sp[0]; dp[1] = sp[1];
  }
  __syncthreads();

  const int w = tid>>6, lane = tid&63, q = lane>>4, l16 = lane&15;
  f32x4 accG[8] = {};
  f32x4 accI[4] = {};
  #pragma unroll
  for (int ks=0;ks<2;ks++){
    const bf16x8 af = ldfrag(&Cs[(w*16+l16)*STR64 + ks*32 + q*8]);
    #pragma unroll
    for (int nj=0;nj<8;nj++)
      accG[nj] = __builtin_amdgcn_mfma_f32_16x16x32_bf16(af, ldfrag(&Bs[(nj*16+l16)*STR64 + ks*32 + q*8]), accG[nj], 0,0,0);
    #pragma unroll
    for (int nj=0;nj<4;nj++)
      accI[nj] = __builtin_amdgcn_mfma_f32_16x16x32_bf16(af, ldfrag(&h0t[(nj*16+l16)*STR64 + ks*32 + q*8]), accI[nj], 0,0,0);
  }
  __syncthreads();
  #pragma unroll
  for (int nj=0;nj<8;nj++){
    const int s = nj*16 + l16;
    #pragma unroll
    for (int r=0;r<4;r++){
      const int t = w*16 + q*4 + r;
      const float v = (s<=t) ? accG[nj][r]*__expf(cumL[t]-cumL[s]) : 0.f;
      Ms[t*STR128 + s] = f2bf(v);
    }
  }
  __syncthreads();
  f32x4 accY[4] = {};
  #pragma unroll
  for (int ks=0;ks<4;ks++){
    const bf16x8 af = ldfrag(&Ms[(w*16+l16)*STR128 + ks*32 + q*8]);
    #pragma unroll
    for (int nj=0;nj<4;nj++)
      accY[nj] = __builtin_amdgcn_mfma_f32_16x16x32_bf16(af, ldfrag(&Ut[(nj*16+l16)*STR128 + ks*32 + q*8]), accY[nj], 0,0,0);
  }
  const float Dv = Dp[hh];
  float rdt[4], ec[4];
  #pragma unroll
  for (int r=0;r<4;r++){
    const int t = w*16 + q*4 + r;
    rdt[r] = 1.f / dtL[t];           // dt = softplus(..) > 0
    ec[r]  = __expf(cumL[t]);
  }
  __syncthreads();   // Ms reads done; reuse pool as y-bounce [128][STR64]
  #pragma unroll
  for (int nj=0;nj<4;nj++){
    const int p = nj*16 + l16;
    #pragma unroll
    for (int r=0;r<4;r++){
      const int t = w*16 + q*4 + r;
      const float xv = bf2f(Ut[p*STR128 + t]) * rdt[r];   // x = (dt*x)/dt
      pool[t*STR64 + p] = f2bf(accY[nj][r] + ec[r]*accI[nj][r] + Dv*xv);
    }
  }
  __syncthreads();
  {
    const int row = tid >> 2, seg = tid & 3;
    const u64* s = (const u64*)(pool + row*STR64 + seg*16);
    u64 a=s[0], b2=s[1], c2=s[2], d=s[3];
    u64* dptr = (u64*)(yg + (bt0+row)*DIN + hh*HD + seg*16);
    dptr[0]=a; dptr[1]=b2; dptr[2]=c2; dptr[3]=d;
  }
}

// ---------------- decoder: hb bf16 in, fp32 out ----------------
__global__ __launch_bounds__(64) void dec_kernel(const u16* __restrict__ hb,
    const float* __restrict__ W, const float* __restrict__ bias, float* __restrict__ out)
{
  const int wg = blockIdx.x;
  const int b = wg / 10, o = wg % 10;
  const int lane = threadIdx.x;
  const u16* r = hb + ((long)b*SEQ + SEQ-1)*DMODEL;
  float s = 0.f;
  #pragma unroll
  for (int q=0;q<4;q++){ const int k = lane + q*64; s += bf2f(r[k])*W[k*10+o]; }
  #pragma unroll
  for (int o2=32;o2;o2>>=1) s += __shfl_down(s, o2);
  if (lane == 0) out[wg] = s + bias[o];
}

extern "C" void kernel_launch(void* const* d_in, const int* in_sizes, int n_in,
                              void* d_out, int out_size, void* d_ws, size_t ws_size,
                              hipStream_t stream) {
  const float* x        = (const float*)d_in[0];
  const float* enc_w    = (const float*)d_in[1];
  const float* enc_b    = (const float*)d_in[2];
  const float* in_proj  = (const float*)d_in[3];
  const float* conv_w   = (const float*)d_in[4];
  const float* conv_b   = (const float*)d_in[5];
  const float* dt_bias  = (const float*)d_in[6];
  const float* A_log    = (const float*)d_in[7];
  const float* Dp       = (const float*)d_in[8];
  const float* norm_w   = (const float*)d_in[9];
  const float* out_proj = (const float*)d_in[10];
  const float* ln_w     = (const float*)d_in[11];
  const float* ln_b     = (const float*)d_in[12];
  const float* dec_w    = (const float*)d_in[13];
  const float* dec_b    = (const float*)d_in[14];
  float* out = (float*)d_out;

  float* ws = (float*)d_ws;
  u16* WtIn  = (u16*)ws;                       // 2*NPAD*256 shorts = 655360
  u16* WtOut = WtIn + (long)2*NPAD*DMODEL;     // 2*256*512 shorts = 262144
  float* gbase = ws + 327680 + 131072;         // = ws + 458752 floats

  // Per-token fp32-equivalents: hb 128 + z 256 + xbc 320 + xsx 256 + yg 256
  //                             + Bb 32 + Cb 32 + dtb 8 + lab 8 = 1296
  int NB = 8;
  while (NB > 1) {
    const long Mb = (long)NB * SEQ;
    const long bytes = (458752L + Mb * 1296L + 4096) * 4;
    if ((size_t)bytes <= ws_size) break;
    NB >>= 1;
  }
  const long Mb = (long)NB * SEQ;

  u16*   hb   = (u16*)gbase;              // Mb*256 u16 (residual stream, bf16 only)
  u16*   zbuf = hb + Mb*DMODEL;           // Mb*512 u16
  u16*   xbc  = zbuf + Mb*DIN;            // Mb*640 u16 ; aliased by Sloc (Mb*256 u16)
  u16*   xsx  = xbc + Mb*CONVDIM;         // Mb*512 u16
  u16*   yg   = xsx + Mb*DIN;             // Mb*512 u16 (y)
  u16*   Bb   = yg + Mb*DIN;              // Mb*64 u16
  u16*   Cb   = Bb + Mb*DSTATE;           // Mb*64 u16
  float* dtb  = (float*)(Cb + Mb*DSTATE); // Mb*8 f
  float* lab  = dtb + Mb*NH;              // Mb*8 f (log dA)
  float* Pb   = lab + Mb*NH;              // <= 2048
  u16*   Sloc = xbc;                      // alias: xbc dead after conv; Mb*256 u16

  cvt_inw <<<dim3(2*NPAD),   dim3(256), 0, stream>>>(in_proj,  WtIn);
  cvt_outw<<<dim3(2*DMODEL), dim3(256), 0, stream>>>(out_proj, WtOut);

  const int ngroups = B_SZ / NB;
  for (int g = 0; g < ngroups; ++g) {
    const float* xg = x + (long)g*NB*SEQ*64;

    enc_kernel<<<dim3((int)(Mb/32)), dim3(256), 0, stream>>>(xg, enc_w, enc_b, hb);

    for (int l = 0; l < 2; ++l) {
      inproj_mfma<<<dim3((int)(Mb/128), NPAD/128), dim3(256), 0, stream>>>(
          hb, WtIn + (long)l*NPAD*DMODEL, zbuf, xbc, dtb, lab,
          dt_bias + l*NH, A_log + l*NH);
      conv_kernel<<<dim3((int)(Mb*20/256)), dim3(256), 0, stream>>>(
          xbc, conv_w + (long)l*CONVDIM*4, conv_b + (long)l*CONVDIM, xsx, Bb, Cb);
      scanS_kernel<<<dim3(NB*8*NCHUNK), dim3(256), 0, stream>>>(xsx, Bb, lab, dtb, Sloc, Pb);
      scanMid_kernel<<<dim3(NB*8, 64), dim3(64), 0, stream>>>(Sloc, Pb);
      scanY_kernel<<<dim3(NB*8*NCHUNK), dim3(512), 0, stream>>>(xsx, yg, Bb, Cb, lab, dtb, Sloc, Dp + l*NH);
      outproj_fused<<<dim3((int)(Mb/128)), dim3(512), 0, stream>>>(
          yg, zbuf, WtOut + (long)l*DMODEL*DIN, hb,
          norm_w + (long)l*DIN, ln_w + l*DMODEL, ln_b + l*DMODEL);
    }

    dec_kernel<<<dim3(NB*10), dim3(64), 0, stream>>>(hb, dec_w, dec_b, out + (long)g*NB*10);
  }
}

// Round 21
// 468.982 us; speedup vs baseline: 1.5373x; 1.0036x over previous
//
#include <hip/hip_runtime.h>
#include <hip/hip_bf16.h>
#include <math.h>

// ---- model constants ----
#define B_SZ    8
#define SEQ     4096
#define DMODEL  256
#define DIN     512     // d_inner
#define DSTATE  64
#define NH      8
#define HD      64
#define CONVDIM 640
#define DPROJ   1160
#define NPAD    1280    // DPROJ padded to 10*128
#define NCHUNK  32      // scan chunks per (b,h)
#define CLEN    128     // SEQ / NCHUNK
#define STR64   68      // LDS row stride (shorts) for K=64 tiles
#define STR128  132     // LDS row stride (shorts) for K=128 tiles
#define EPSTR   140     // epilogue bounce stride (64*EPSTR = 8960 shorts <= 9216 pool: in bounds)

typedef unsigned long long u64;
typedef unsigned int u32;
typedef unsigned short u16;
typedef __attribute__((ext_vector_type(8))) short bf16x8;
typedef __attribute__((ext_vector_type(4))) float f32x4;

__device__ __forceinline__ float siluf(float v){ return v / (1.f + __expf(-v)); }   // native v_exp
__device__ __forceinline__ u16 f2bf(float f){ __hip_bfloat16 h = __float2bfloat16(f); return *(u16*)&h; }
__device__ __forceinline__ float bf2f(u16 u){ union{u32 i; float f;} t; t.i = ((u32)u)<<16; return t.f; }
__device__ __forceinline__ bf16x8 ldfrag(const u16* base){
  union { u64 u[2]; bf16x8 v; } t;
  const u64* p = (const u64*)base;
  t.u[0] = p[0]; t.u[1] = p[1];
  return t.v;
}

// ---------------- weight conversion (once per launch) ----------------
__global__ __launch_bounds__(256) void cvt_inw(const float* __restrict__ W, u16* __restrict__ Wt)
{
  const int blk = blockIdx.x;
  const int l = blk / NPAD, n = blk % NPAD;
  const int k = threadIdx.x;
  float v = 0.f;
  if (n < DPROJ) v = W[((long)l*DMODEL + k)*DPROJ + n];
  Wt[((long)l*NPAD + n)*DMODEL + k] = f2bf(v);
}

__global__ __launch_bounds__(256) void cvt_outw(const float* __restrict__ W, u16* __restrict__ Wt)
{
  const int blk = blockIdx.x;
  const int l = blk / DMODEL, n = blk % DMODEL;
  #pragma unroll
  for (int q = 0; q < 2; ++q) {
    const int k = threadIdx.x + q*256;
    const float v = W[((long)l*DIN + k)*DMODEL + n];
    Wt[((long)l*DMODEL + n)*DIN + k] = f2bf(v);
  }
}

// ---------------- encoder GEMM; writes hb bf16 ----------------
__global__ __launch_bounds__(256) void enc_kernel(const float* __restrict__ x,
    const float* __restrict__ W, const float* __restrict__ bias, u16* __restrict__ hb)
{
  __shared__ float xl[32*64];
  const int tid = threadIdx.x;
  const long t0 = (long)blockIdx.x * 32;
  for (int i = tid; i < 32*64; i += 256) xl[i] = x[t0*64 + i];
  __syncthreads();
  float acc[32];
  const float bv = bias[tid];
  #pragma unroll
  for (int tok = 0; tok < 32; ++tok) acc[tok] = bv;
  for (int k = 0; k < 64; ++k) {
    const float wv = W[k*DMODEL + tid];
    #pragma unroll
    for (int tok = 0; tok < 32; ++tok) acc[tok] += xl[tok*64 + k] * wv;
  }
  #pragma unroll
  for (int tok = 0; tok < 32; ++tok)
    hb[(t0 + tok)*DMODEL + tid] = f2bf(acc[tok]);
}

// ---------------- in_proj MFMA GEMM 128x128 tile, BK=32 ----------------
// Grid (Mb/128, 10), m fastest: XCD = m%8 -> col-tiles of one m-strip share L2-cached A.
__global__ __launch_bounds__(256) void inproj_mfma(const u16* __restrict__ hb,
    const u16* __restrict__ Wt, u16* __restrict__ zbuf, u16* __restrict__ xbc,
    float* __restrict__ dtb, float* __restrict__ lab,
    const float* __restrict__ dt_bias, const float* __restrict__ A_log)
{
  __shared__ __align__(16) u16 pool[128*36*2];   // staging Asl|Bsl; epilogue bounce aliases it
  u16* Asl = pool;
  u16* Bsl = pool + 128*36;
  u16* Ep  = pool;                               // [64][EPSTR] u16 per mi-half (8960 <= 9216)
  const int tid = threadIdx.x;
  const long m0 = (long)blockIdx.x * 128;
  const int n0 = blockIdx.y * 128;
  const int w = tid >> 6, lane = tid & 63;
  const int q = lane >> 4, l16 = lane & 15;
  const int srow = tid >> 1, sseg = tid & 1;   // 2 lanes/row, 16 shorts (32 B) each
  f32x4 acc[2][8] = {{{0.f,0.f,0.f,0.f}}};
  for (int k0 = 0; k0 < DMODEL; k0 += 32) {
    {
      const u64* s = (const u64*)(hb + (m0 + srow)*DMODEL + k0 + sseg*16);
      u64 a=s[0], b=s[1], c=s[2], d=s[3];
      u64* dst = (u64*)(&Asl[srow*36 + sseg*16]);
      dst[0]=a; dst[1]=b; dst[2]=c; dst[3]=d;
    }
    {
      const u64* s = (const u64*)(Wt + (long)(n0 + srow)*DMODEL + k0 + sseg*16);
      u64 a=s[0], b=s[1], c=s[2], d=s[3];
      u64* dst = (u64*)(&Bsl[srow*36 + sseg*16]);
      dst[0]=a; dst[1]=b; dst[2]=c; dst[3]=d;
    }
    __syncthreads();
    bf16x8 af[2], bfr[8];
    #pragma unroll
    for (int mi=0;mi<2;mi++) af[mi] = ldfrag(&Asl[(w*32 + mi*16 + l16)*36 + q*8]);
    #pragma unroll
    for (int nj=0;nj<8;nj++) bfr[nj] = ldfrag(&Bsl[(nj*16 + l16)*36 + q*8]);
    #pragma unroll
    for (int mi=0;mi<2;mi++)
      #pragma unroll
      for (int nj=0;nj<8;nj++)
        acc[mi][nj] = __builtin_amdgcn_mfma_f32_16x16x32_bf16(af[mi], bfr[nj], acc[mi][nj], 0,0,0);
    __syncthreads();
  }
  if (n0 < DIN + CONVDIM) {
    // bounce each 64-row half through LDS, then full-line stores (4 thr/row x 32 shorts = 128)
    #pragma unroll
    for (int mi=0;mi<2;mi++){
      if (mi) __syncthreads();
      #pragma unroll
      for (int nj=0;nj<8;nj++){
        const int col = nj*16 + l16;
        #pragma unroll
        for (int r=0;r<4;r++){
          const int er = w*16 + q*4 + r;
          Ep[er*EPSTR + col] = f2bf(acc[mi][nj][r]);
        }
      }
      __syncthreads();
      {
        const int er2 = tid >> 2, seg = tid & 3;
        const long grow = m0 + (er2>>4)*32 + mi*16 + (er2&15);
        const u64* s = (const u64*)(Ep + er2*EPSTR + seg*32);
        u64 v0=s[0], v1=s[1], v2=s[2], v3=s[3], v4=s[4], v5=s[5], v6=s[6], v7=s[7];
        u64* dptr;
        if (n0 < DIN) dptr = (u64*)(zbuf + grow*DIN + n0 + seg*32);
        else          dptr = (u64*)(xbc + grow*CONVDIM + (n0 - DIN) + seg*32);
        dptr[0]=v0; dptr[1]=v1; dptr[2]=v2; dptr[3]=v3;
        dptr[4]=v4; dptr[5]=v5; dptr[6]=v6; dptr[7]=v7;
      }
    }
  } else {
    // dt tile: only cols 1152..1159 valid
    #pragma unroll
    for (int mi=0;mi<2;mi++){
      #pragma unroll
      for (int nj=0;nj<8;nj++){
        const int col = n0 + nj*16 + l16;
        if (col < DPROJ) {
          const int hh = col - (DIN + CONVDIM);
          #pragma unroll
          for (int r=0;r<4;r++){
            const long row = m0 + w*32 + mi*16 + q*4 + r;
            const float dv = acc[mi][nj][r] + dt_bias[hh];
            const float sp = dv > 20.f ? dv : log1pf(expf(dv));
            dtb[row*NH + hh] = sp;
            lab[row*NH + hh] = sp * (-expf(A_log[hh]));   // log dA
          }
        }
      }
    }
  }
}

// ---------------- out_proj fused: gnorm (y*silu(z), RMS) + GEMM + residual + LayerNorm ----------------
// RMS scale commutes through GEMM: out = scale_row * ((g*nw) @ W). 512 threads; A staged by all 512.
__global__ __launch_bounds__(512) void outproj_fused(const u16* __restrict__ yb,
    const u16* __restrict__ zb, const u16* __restrict__ Wt, u16* __restrict__ hb,
    const float* __restrict__ nw, const float* __restrict__ lnw, const float* __restrict__ lnb)
{
  __shared__ __align__(16) u16 Asl[128*36];
  __shared__ __align__(16) u16 Bsl[256*36];
  __shared__ float red[128][2][2];     // [row][colgroup][sum, sumsq] for LN
  __shared__ float red2[128][4];       // [row][seg] partial sum g^2 for RMS
  __shared__ float nwl[512];
  const int tid = threadIdx.x;
  const long m0 = (long)blockIdx.x * 128;
  const int w = tid >> 6, lane = tid & 63;
  const int q = lane >> 4, l16 = lane & 15;
  const int wr = (w >> 1) * 32;        // wave row base (0/32/64/96)
  const int wc = (w & 1) * 128;        // wave col base (0/128)
  const int arow = tid >> 2, aseg = tid & 3;   // A staging: 128 rows x 4 segs x 8 shorts
  const int brow = tid >> 1, bseg = tid & 1;   // B staging: 256 rows x 2 segs x 16 shorts
  if (tid < 512) nwl[tid] = nw[tid];
  __syncthreads();
  float sq = 0.f;
  f32x4 acc[2][8] = {{{0.f,0.f,0.f,0.f}}};
  for (int kk = 0; kk < 16; ++kk) {
    const int k0 = kk*32;
    {   // A staging (all 512): g = y*silu(z); stage g*nw bf16; accumulate g^2
      const u64* yp = (const u64*)(yb + (m0 + arow)*DIN + k0 + aseg*8);
      const u64* zp = (const u64*)(zb + (m0 + arow)*DIN + k0 + aseg*8);
      const u64 ys[2] = {yp[0], yp[1]};
      const u64 zs[2] = {zp[0], zp[1]};
      u16 gv[8];
      #pragma unroll
      for (int u=0;u<2;u++){
        #pragma unroll
        for (int j=0;j<4;j++){
          const float yv = bf2f((u16)(ys[u] >> (16*j)));
          const float zv = bf2f((u16)(zs[u] >> (16*j)));
          const float g = yv * siluf(zv);
          sq += g*g;
          gv[u*4+j] = f2bf(g * nwl[k0 + aseg*8 + u*4 + j]);
        }
      }
      const u64* gp = (const u64*)gv;
      u64* dst = (u64*)(&Asl[arow*36 + aseg*8]);
      dst[0]=gp[0]; dst[1]=gp[1];
    }
    {
      const u64* s = (const u64*)(Wt + (long)brow*DIN + k0 + bseg*16);
      u64 a=s[0], b=s[1], c=s[2], d=s[3];
      u64* dst = (u64*)(&Bsl[brow*36 + bseg*16]);
      dst[0]=a; dst[1]=b; dst[2]=c; dst[3]=d;
    }
    __syncthreads();
    bf16x8 af[2], bfr[8];
    #pragma unroll
    for (int mi=0;mi<2;mi++) af[mi] = ldfrag(&Asl[(wr + mi*16 + l16)*36 + q*8]);
    #pragma unroll
    for (int nj=0;nj<8;nj++) bfr[nj] = ldfrag(&Bsl[(wc + nj*16 + l16)*36 + q*8]);
    #pragma unroll
    for (int mi=0;mi<2;mi++)
      #pragma unroll
      for (int nj=0;nj<8;nj++)
        acc[mi][nj] = __builtin_amdgcn_mfma_f32_16x16x32_bf16(af[mi], bfr[nj], acc[mi][nj], 0,0,0);
    __syncthreads();
  }
  red2[arow][aseg] = sq;
  __syncthreads();
  // o = acc*rms_scale + resid(bf16) ; per-row LN stats via 16-lane shuffle + LDS combine
  #pragma unroll
  for (int mi=0;mi<2;mi++){
    #pragma unroll
    for (int r=0;r<4;r++){
      const int lrow = wr + mi*16 + q*4 + r;
      const float S2 = red2[lrow][0] + red2[lrow][1] + red2[lrow][2] + red2[lrow][3];
      const float rscale = rsqrtf(S2*(1.f/512.f) + 1e-5f);
      float s = 0.f, ss = 0.f;
      #pragma unroll
      for (int nj=0;nj<8;nj++){
        const int col = wc + nj*16 + l16;
        const float o = acc[mi][nj][r]*rscale + bf2f(hb[(m0+lrow)*DMODEL + col]);
        acc[mi][nj][r] = o;
        s += o; ss += o*o;
      }
      #pragma unroll
      for (int o2=1;o2<16;o2<<=1){ s += __shfl_xor(s,o2); ss += __shfl_xor(ss,o2); }
      if (l16 == 0) { red[lrow][w&1][0] = s; red[lrow][w&1][1] = ss; }
    }
  }
  __syncthreads();
  #pragma unroll
  for (int mi=0;mi<2;mi++){
    #pragma unroll
    for (int r=0;r<4;r++){
      const int lrow = wr + mi*16 + q*4 + r;
      const float S  = red[lrow][0][0] + red[lrow][1][0];
      const float SS = red[lrow][0][1] + red[lrow][1][1];
      const float mu = S * (1.f/256.f);
      const float var = SS * (1.f/256.f) - mu*mu;
      const float rs = rsqrtf(var + 1e-5f);
      #pragma unroll
      for (int nj=0;nj<8;nj++){
        const int col = wc + nj*16 + l16;
        const float v = (acc[mi][nj][r] - mu)*rs*lnw[col] + lnb[col];
        hb[(m0+lrow)*DMODEL + col] = f2bf(v);
      }
    }
  }
}

// ---------------- depthwise causal conv + SiLU: strip kernel ----------------
__global__ __launch_bounds__(256) void conv_kernel(const u16* __restrict__ xbc,
    const float* __restrict__ cw, const float* __restrict__ cb,
    u16* __restrict__ xsx, u16* __restrict__ Bb, u16* __restrict__ Cb)
{
  const long idx = (long)blockIdx.x * 256 + threadIdx.x;   // Mb*20 threads
  const int c4 = (int)(idx % 160) * 4;
  const long bt0 = (idx / 160) * 8;          // strip start (strips never cross batch)
  const int tseq = (int)(bt0 & (SEQ-1));
  const float4 b4 = *(const float4*)(cb + c4);
  const float4 w0v = *(const float4*)(cw + (c4+0)*4);
  const float4 w1v = *(const float4*)(cw + (c4+1)*4);
  const float4 w2v = *(const float4*)(cw + (c4+2)*4);
  const float4 w3v = *(const float4*)(cw + (c4+3)*4);
  const float W0[4] = {w0v.x,w0v.y,w0v.z,w0v.w};
  const float W1[4] = {w1v.x,w1v.y,w1v.z,w1v.w};
  const float W2[4] = {w2v.x,w2v.y,w2v.z,w2v.w};
  const float W3[4] = {w3v.x,w3v.y,w3v.z,w3v.w};
  float i0[11], i1[11], i2[11], i3[11];
  #pragma unroll
  for (int k = 0; k < 11; ++k) {
    u64 v = 0;
    if (tseq - 3 + k >= 0) v = *(const u64*)(xbc + (bt0 - 3 + k)*CONVDIM + c4);
    i0[k]=bf2f((u16)v); i1[k]=bf2f((u16)(v>>16)); i2[k]=bf2f((u16)(v>>32)); i3[k]=bf2f((u16)(v>>48));
  }
  u16* dst; long base; int stride;
  if (c4 < DIN)              { dst = xsx; base = bt0*DIN + c4;              stride = DIN; }
  else if (c4 < DIN+DSTATE)  { dst = Bb;  base = bt0*DSTATE + (c4-DIN);     stride = DSTATE; }
  else                       { dst = Cb;  base = bt0*DSTATE + (c4-DIN-DSTATE); stride = DSTATE; }
  #pragma unroll
  for (int j = 0; j < 8; ++j) {
    float a0=b4.x, a1=b4.y, a2=b4.z, a3=b4.w;
    #pragma unroll
    for (int k = 0; k < 4; ++k) {
      a0 += W0[k]*i0[j+k]; a1 += W1[k]*i1[j+k];
      a2 += W2[k]*i2[j+k]; a3 += W3[k]*i3[j+k];
    }
    a0=siluf(a0); a1=siluf(a1); a2=siluf(a2); a3=siluf(a3);
    const u64 r = (u64)f2bf(a0) | ((u64)f2bf(a1)<<16) | ((u64)f2bf(a2)<<32) | ((u64)f2bf(a3)<<48);
    *(u64*)(dst + base + (long)j*stride) = r;
  }
}

// ---------------- SSD phase A: per chunk-head local state via MFMA; Sloc bf16 ----------------
__global__ __launch_bounds__(256) void scanS_kernel(const u16* __restrict__ xsx,
    const u16* __restrict__ Bb, const float* __restrict__ lab, const float* __restrict__ dtb,
    u16* __restrict__ Sloc, float* __restrict__ Pb)
{
  __shared__ __align__(16) u16 Btr[64*STR128];   // [n][s]
  __shared__ __align__(16) u16 Uw[64*STR128];    // [p][s]
  __shared__ float cexpL[128];
  const int wg = blockIdx.x;
  const int c = wg & (NCHUNK-1), bh = wg >> 5, hh = bh & (NH-1), b = bh >> 3;
  const int tid = threadIdx.x;
  const long bt0 = (long)b*SEQ + c*CLEN;
  if (tid < 64) {   // wave 0: inclusive prefix of log dA over 128 steps
    float a0 = lab[(bt0+tid)*NH + hh];
    float a1 = lab[(bt0+64+tid)*NH + hh];
    const float d0 = dtb[(bt0+tid)*NH + hh];
    const float d1 = dtb[(bt0+64+tid)*NH + hh];
    #pragma unroll
    for (int o=1;o<64;o<<=1){
      const float t0=__shfl_up(a0,o), t1=__shfl_up(a1,o);
      if (tid>=o){a0+=t0;a1+=t1;}
    }
    a1 += __shfl(a0,63);
    const float ctot = __shfl(a1,63);
    cexpL[tid]    = d0*__expf(ctot - a0);
    cexpL[tid+64] = d1*__expf(ctot - a1);
    if (tid==0) Pb[wg] = __expf(ctot);
  }
  __syncthreads();
  {
    const int v = tid & 63, r0 = tid >> 6;
    #pragma unroll 4
    for (int k=0;k<32;k++){
      const int s = r0 + k*4;
      Btr[v*STR128 + s] = Bb[(bt0+s)*DSTATE + v];
      Uw[v*STR128 + s]  = f2bf(cexpL[s]*bf2f(xsx[(bt0+s)*DIN + hh*HD + v]));
    }
  }
  __syncthreads();
  const int w = tid>>6, lane = tid&63, q = lane>>4, l16 = lane&15;
  f32x4 acc[4] = {};
  #pragma unroll
  for (int ks=0;ks<4;ks++){
    const bf16x8 af = ldfrag(&Uw[(w*16+l16)*STR128 + ks*32 + q*8]);
    #pragma unroll
    for (int nj=0;nj<4;nj++){
      const bf16x8 bf = ldfrag(&Btr[(nj*16+l16)*STR128 + ks*32 + q*8]);
      acc[nj] = __builtin_amdgcn_mfma_f32_16x16x32_bf16(af, bf, acc[nj], 0,0,0);
    }
  }
  const long sb = (long)wg*4096;   // [wg][p][n] bf16
  #pragma unroll
  for (int nj=0;nj<4;nj++)
    #pragma unroll
    for (int r=0;r<4;r++)
      Sloc[sb + (w*16+q*4+r)*64 + nj*16 + l16] = f2bf(acc[nj][r]);
}

// Parallel combine over bf16 Sloc: run stays fp32 in registers
__global__ __launch_bounds__(64) void scanMid_kernel(u16* __restrict__ Sloc, const float* __restrict__ Pb)
{
  const int bh = blockIdx.x;
  const int rr = blockIdx.y;
  const int p  = threadIdx.x;
  float run = 0.f;
  for (int c = 0; c < NCHUNK; ++c) {
    const long base = ((long)(bh*NCHUNK + c))*4096 + rr*64 + p;
    const float Pc = Pb[bh*NCHUNK + c];
    const float tmp = bf2f(Sloc[base]);
    Sloc[base] = f2bf(run);
    run = run*Pc + tmp;
  }
}

// ---------------- SSD phase C: Y = ((C Bt) o L) U + diag(exp(cum)) (C h0) + D*x ; coalesced y out ----------------
// Epilogue recovers x = Ut/dt from LDS (Ut = bf16(dt*x), dt = softplus > 0) -> no 2nd global xsx read.
__global__ __launch_bounds__(512) void scanY_kernel(const u16* __restrict__ xsx,
    u16* __restrict__ yg, const u16* __restrict__ Bb, const u16* __restrict__ Cb,
    const float* __restrict__ lab, const float* __restrict__ dtb,
    const u16* __restrict__ Sinit, const float* __restrict__ Dp)
{
  __shared__ __align__(16) u16 pool[2*128*STR64];  // Bs | Cs; overlaid by Ms[t][s]; then by y-bounce
  __shared__ __align__(16) u16 Ut[64*STR128];      // [p][s]
  __shared__ __align__(16) u16 h0t[64*STR64];      // [p][n]
  __shared__ float cumL[128];
  __shared__ float dtL[128];
  u16* Bs = pool;
  u16* Cs = pool + 128*STR64;
  u16* Ms = pool;

  const int wg = blockIdx.x;
  const int c = wg & (NCHUNK-1), bh = wg >> 5, hh = bh & (NH-1), b = bh >> 3;
  const int tid = threadIdx.x;
  const long bt0 = (long)b*SEQ + c*CLEN;

  if (tid < 64) {
    float a0 = lab[(bt0+tid)*NH + hh];
    float a1 = lab[(bt0+64+tid)*NH + hh];
    dtL[tid]    = dtb[(bt0+tid)*NH + hh];
    dtL[tid+64] = dtb[(bt0+64+tid)*NH + hh];
    #pragma unroll
    for (int o=1;o<64;o<<=1){
      const float t0=__shfl_up(a0,o), t1=__shfl_up(a1,o);
      if (tid>=o){a0+=t0;a1+=t1;}
    }
    a1 += __shfl(a0,63);
    cumL[tid]=a0; cumL[tid+64]=a1;
  }
  __syncthreads();
  {
    const int n = tid & 63, r0 = tid >> 6;   // 512 threads: r0 in 0..7
    #pragma unroll 4
    for (int k=0;k<16;k++){
      const int s = r0 + k*8;
      Bs[s*STR64 + n] = Bb[(bt0+s)*DSTATE + n];
      Cs[s*STR64 + n] = Cb[(bt0+s)*DSTATE + n];
      Ut[n*STR128 + s] = f2bf(dtL[s]*bf2f(xsx[(bt0+s)*DIN + hh*HD + n]));
    }
    const int n0 = r0*8;
    // h0 bf16: 8 states = 16 B = two u64 copies
    const u64* sp = (const u64*)(Sinit + (long)wg*4096 + n*64 + n0);
    u64* dp = (u64*)(h0t + n*STR64 + n0);
    dp[0] = sp[0]; dp[1] = sp[1];
  }
  __syncthreads();

  const int w = tid>>6, lane = tid&63, q = lane>>4, l16 = lane&15;
  f32x4 accG[8] = {};
  f32x4 accI[4] = {};
  #pragma unroll
  for (int ks=0;ks<2;ks++){
    const bf16x8 af = ldfrag(&Cs[(w*16+l16)*STR64 + ks*32 + q*8]);
    #pragma unroll
    for (int nj=0;nj<8;nj++)
      accG[nj] = __builtin_amdgcn_mfma_f32_16x16x32_bf16(af, ldfrag(&Bs[(nj*16+l16)*STR64 + ks*32 + q*8]), accG[nj], 0,0,0);
    #pragma unroll
    for (int nj=0;nj<4;nj++)
      accI[nj] = __builtin_amdgcn_mfma_f32_16x16x32_bf16(af, ldfrag(&h0t[(nj*16+l16)*STR64 + ks*32 + q*8]), accI[nj], 0,0,0);
  }
  __syncthreads();
  #pragma unroll
  for (int nj=0;nj<8;nj++){
    const int s = nj*16 + l16;
    #pragma unroll
    for (int r=0;r<4;r++){
      const int t = w*16 + q*4 + r;
      const float v = (s<=t) ? accG[nj][r]*__expf(cumL[t]-cumL[s]) : 0.f;
      Ms[t*STR128 + s] = f2bf(v);
    }
  }
  __syncthreads();
  f32x4 accY[4] = {};
  #pragma unroll
  for (int ks=0;ks<4;ks++){
    const bf16x8 af = ldfrag(&Ms[(w*16+l16)*STR128 + ks*32 + q*8]);
    #pragma unroll
    for (int nj=0;nj<4;nj++)
      accY[nj] = __builtin_amdgcn_mfma_f32_16x16x32_bf16(af, ldfrag(&Ut[(nj*16+l16)*STR128 + ks*32 + q*8]), accY[nj], 0,0,0);
  }
  const float Dv = Dp[hh];
  float rdt[4], ec[4];
  #pragma unroll
  for (int r=0;r<4;r++){
    const int t = w*16 + q*4 + r;
    rdt[r] = 1.f / dtL[t];           // dt = softplus(..) > 0
    ec[r]  = __expf(cumL[t]);
  }
  __syncthreads();   // Ms reads done; reuse pool as y-bounce [128][STR64]
  #pragma unroll
  for (int nj=0;nj<4;nj++){
    const int p = nj*16 + l16;
    #pragma unroll
    for (int r=0;r<4;r++){
      const int t = w*16 + q*4 + r;
      const float xv = bf2f(Ut[p*STR128 + t]) * rdt[r];   // x = (dt*x)/dt
      pool[t*STR64 + p] = f2bf(accY[nj][r] + ec[r]*accI[nj][r] + Dv*xv);
    }
  }
  __syncthreads();
  {
    const int row = tid >> 2, seg = tid & 3;
    const u64* s = (const u64*)(pool + row*STR64 + seg*16);
    u64 a=s[0], b2=s[1], c2=s[2], d=s[3];
    u64* dptr = (u64*)(yg + (bt0+row)*DIN + hh*HD + seg*16);
    dptr[0]=a; dptr[1]=b2; dptr[2]=c2; dptr[3]=d;
  }
}

// ---------------- decoder: hb bf16 in, fp32 out ----------------
__global__ __launch_bounds__(64) void dec_kernel(const u16* __restrict__ hb,
    const float* __restrict__ W, const float* __restrict__ bias, float* __restrict__ out)
{
  const int wg = blockIdx.x;
  const int b = wg / 10, o = wg % 10;
  const int lane = threadIdx.x;
  const u16* r = hb + ((long)b*SEQ + SEQ-1)*DMODEL;
  float s = 0.f;
  #pragma unroll
  for (int q=0;q<4;q++){ const int k = lane + q*64; s += bf2f(r[k])*W[k*10+o]; }
  #pragma unroll
  for (int o2=32;o2;o2>>=1) s += __shfl_down(s, o2);
  if (lane == 0) out[wg] = s + bias[o];
}

extern "C" void kernel_launch(void* const* d_in, const int* in_sizes, int n_in,
                              void* d_out, int out_size, void* d_ws, size_t ws_size,
                              hipStream_t stream) {
  const float* x        = (const float*)d_in[0];
  const float* enc_w    = (const float*)d_in[1];
  const float* enc_b    = (const float*)d_in[2];
  const float* in_proj  = (const float*)d_in[3];
  const float* conv_w   = (const float*)d_in[4];
  const float* conv_b   = (const float*)d_in[5];
  const float* dt_bias  = (const float*)d_in[6];
  const float* A_log    = (const float*)d_in[7];
  const float* Dp       = (const float*)d_in[8];
  const float* norm_w   = (const float*)d_in[9];
  const float* out_proj = (const float*)d_in[10];
  const float* ln_w     = (const float*)d_in[11];
  const float* ln_b     = (const float*)d_in[12];
  const float* dec_w    = (const float*)d_in[13];
  const float* dec_b    = (const float*)d_in[14];
  float* out = (float*)d_out;

  float* ws = (float*)d_ws;
  u16* WtIn  = (u16*)ws;                       // 2*NPAD*256 shorts = 655360
  u16* WtOut = WtIn + (long)2*NPAD*DMODEL;     // 2*256*512 shorts = 262144
  float* gbase = ws + 327680 + 131072;         // = ws + 458752 floats

  // Per-token fp32-equivalents: hb 128 + z 256 + xbc 320 + xsx 256 + yg 256
  //                             + Bb 32 + Cb 32 + dtb 8 + lab 8 = 1296
  int NB = 8;
  while (NB > 1) {
    const long Mb = (long)NB * SEQ;
    const long bytes = (458752L + Mb * 1296L + 4096) * 4;
    if ((size_t)bytes <= ws_size) break;
    NB >>= 1;
  }
  const long Mb = (long)NB * SEQ;

  u16*   hb   = (u16*)gbase;              // Mb*256 u16 (residual stream, bf16 only)
  u16*   zbuf = hb + Mb*DMODEL;           // Mb*512 u16
  u16*   xbc  = zbuf + Mb*DIN;            // Mb*640 u16 ; aliased by Sloc (Mb*256 u16)
  u16*   xsx  = xbc + Mb*CONVDIM;         // Mb*512 u16
  u16*   yg   = xsx + Mb*DIN;             // Mb*512 u16 (y)
  u16*   Bb   = yg + Mb*DIN;              // Mb*64 u16
  u16*   Cb   = Bb + Mb*DSTATE;           // Mb*64 u16
  float* dtb  = (float*)(Cb + Mb*DSTATE); // Mb*8 f
  float* lab  = dtb + Mb*NH;              // Mb*8 f (log dA)
  float* Pb   = lab + Mb*NH;              // <= 2048
  u16*   Sloc = xbc;                      // alias: xbc dead after conv; Mb*256 u16

  cvt_inw <<<dim3(2*NPAD),   dim3(256), 0, stream>>>(in_proj,  WtIn);
  cvt_outw<<<dim3(2*DMODEL), dim3(256), 0, stream>>>(out_proj, WtOut);

  const int ngroups = B_SZ / NB;
  for (int g = 0; g < ngroups; ++g) {
    const float* xg = x + (long)g*NB*SEQ*64;

    enc_kernel<<<dim3((int)(Mb/32)), dim3(256), 0, stream>>>(xg, enc_w, enc_b, hb);

    for (int l = 0; l < 2; ++l) {
      inproj_mfma<<<dim3((int)(Mb/128), NPAD/128), dim3(256), 0, stream>>>(
          hb, WtIn + (long)l*NPAD*DMODEL, zbuf, xbc, dtb, lab,
          dt_bias + l*NH, A_log + l*NH);
      conv_kernel<<<dim3((int)(Mb*20/256)), dim3(256), 0, stream>>>(
          xbc, conv_w + (long)l*CONVDIM*4, conv_b + (long)l*CONVDIM, xsx, Bb, Cb);
      scanS_kernel<<<dim3(NB*8*NCHUNK), dim3(256), 0, stream>>>(xsx, Bb, lab, dtb, Sloc, Pb);
      scanMid_kernel<<<dim3(NB*8, 64), dim3(64), 0, stream>>>(Sloc, Pb);
      scanY_kernel<<<dim3(NB*8*NCHUNK), dim3(512), 0, stream>>>(xsx, yg, Bb, Cb, lab, dtb, Sloc, Dp + l*NH);
      outproj_fused<<<dim3((int)(Mb/128)), dim3(512), 0, stream>>>(
          yg, zbuf, WtOut + (long)l*DMODEL*DIN, hb,
          norm_w + (long)l*DIN, ln_w + l*DMODEL, ln_b + l*DMODEL);
    }

    dec_kernel<<<dim3(NB*10), dim3(64), 0, stream>>>(hb, dec_w, dec_b, out + (long)g*NB*10);
  }
}

// Round 22
// 465.200 us; speedup vs baseline: 1.5498x; 1.0081x over previous
//
#include <hip/hip_runtime.h>
#include <hip/hip_bf16.h>
#include <math.h>

// ---- model constants ----
#define B_SZ    8
#define SEQ     4096
#define DMODEL  256
#define DIN     512     // d_inner
#define DSTATE  64
#define NH      8
#define HD      64
#define CONVDIM 640
#define DPROJ   1160
#define NPAD    1280    // DPROJ padded to 10*128
#define NCHUNK  32      // scan chunks per (b,h)
#define CLEN    128     // SEQ / NCHUNK
#define STR64   68      // LDS row stride (shorts) for K=64 tiles
#define STR128  132     // LDS row stride (shorts) for K=128 tiles
#define EPSTR   140     // epilogue bounce stride (64*EPSTR = 8960 shorts <= 17408 pool: in bounds)

typedef unsigned long long u64;
typedef unsigned int u32;
typedef unsigned short u16;
typedef __attribute__((ext_vector_type(8))) short bf16x8;
typedef __attribute__((ext_vector_type(4))) float f32x4;

__device__ __forceinline__ float siluf(float v){ return v / (1.f + __expf(-v)); }   // native v_exp
__device__ __forceinline__ u16 f2bf(float f){ __hip_bfloat16 h = __float2bfloat16(f); return *(u16*)&h; }
__device__ __forceinline__ float bf2f(u16 u){ union{u32 i; float f;} t; t.i = ((u32)u)<<16; return t.f; }
__device__ __forceinline__ bf16x8 ldfrag(const u16* base){
  union { u64 u[2]; bf16x8 v; } t;
  const u64* p = (const u64*)base;
  t.u[0] = p[0]; t.u[1] = p[1];
  return t.v;
}

// ---------------- weight conversion (once per launch) ----------------
__global__ __launch_bounds__(256) void cvt_inw(const float* __restrict__ W, u16* __restrict__ Wt)
{
  const int blk = blockIdx.x;
  const int l = blk / NPAD, n = blk % NPAD;
  const int k = threadIdx.x;
  float v = 0.f;
  if (n < DPROJ) v = W[((long)l*DMODEL + k)*DPROJ + n];
  Wt[((long)l*NPAD + n)*DMODEL + k] = f2bf(v);
}

__global__ __launch_bounds__(256) void cvt_outw(const float* __restrict__ W, u16* __restrict__ Wt)
{
  const int blk = blockIdx.x;
  const int l = blk / DMODEL, n = blk % DMODEL;
  #pragma unroll
  for (int q = 0; q < 2; ++q) {
    const int k = threadIdx.x + q*256;
    const float v = W[((long)l*DIN + k)*DMODEL + n];
    Wt[((long)l*DMODEL + n)*DIN + k] = f2bf(v);
  }
}

// ---------------- encoder GEMM; writes hb bf16 ----------------
__global__ __launch_bounds__(256) void enc_kernel(const float* __restrict__ x,
    const float* __restrict__ W, const float* __restrict__ bias, u16* __restrict__ hb)
{
  __shared__ float xl[32*64];
  const int tid = threadIdx.x;
  const long t0 = (long)blockIdx.x * 32;
  for (int i = tid; i < 32*64; i += 256) xl[i] = x[t0*64 + i];
  __syncthreads();
  float acc[32];
  const float bv = bias[tid];
  #pragma unroll
  for (int tok = 0; tok < 32; ++tok) acc[tok] = bv;
  for (int k = 0; k < 64; ++k) {
    const float wv = W[k*DMODEL + tid];
    #pragma unroll
    for (int tok = 0; tok < 32; ++tok) acc[tok] += xl[tok*64 + k] * wv;
  }
  #pragma unroll
  for (int tok = 0; tok < 32; ++tok)
    hb[(t0 + tok)*DMODEL + tid] = f2bf(acc[tok]);
}

// ---------------- in_proj MFMA GEMM 128x128 tile, BK=64 (2 MFMA k-steps per stage, 8 barriers) ----------------
// Grid (Mb/128, 10), m fastest: XCD = m%8 -> col-tiles of one m-strip share L2-cached A.
__global__ __launch_bounds__(256) void inproj_mfma(const u16* __restrict__ hb,
    const u16* __restrict__ Wt, u16* __restrict__ zbuf, u16* __restrict__ xbc,
    float* __restrict__ dtb, float* __restrict__ lab,
    const float* __restrict__ dt_bias, const float* __restrict__ A_log)
{
  __shared__ __align__(16) u16 pool[2*128*STR64];  // Asl | Bsl, stride 68; epilogue bounce aliases
  u16* Asl = pool;
  u16* Bsl = pool + 128*STR64;
  u16* Ep  = pool;                                 // [64][EPSTR] per mi-half (8960 <= 17408)
  const int tid = threadIdx.x;
  const long m0 = (long)blockIdx.x * 128;
  const int n0 = blockIdx.y * 128;
  const int w = tid >> 6, lane = tid & 63;
  const int q = lane >> 4, l16 = lane & 15;
  const int srow = tid >> 1, sseg = tid & 1;   // 2 lanes/row, 32 shorts (64 B) each
  f32x4 acc[2][8] = {{{0.f,0.f,0.f,0.f}}};
  for (int k0 = 0; k0 < DMODEL; k0 += 64) {
    {
      const u64* s = (const u64*)(hb + (m0 + srow)*DMODEL + k0 + sseg*32);
      u64 v0=s[0], v1=s[1], v2=s[2], v3=s[3], v4=s[4], v5=s[5], v6=s[6], v7=s[7];
      u64* dst = (u64*)(&Asl[srow*STR64 + sseg*32]);
      dst[0]=v0; dst[1]=v1; dst[2]=v2; dst[3]=v3; dst[4]=v4; dst[5]=v5; dst[6]=v6; dst[7]=v7;
    }
    {
      const u64* s = (const u64*)(Wt + (long)(n0 + srow)*DMODEL + k0 + sseg*32);
      u64 v0=s[0], v1=s[1], v2=s[2], v3=s[3], v4=s[4], v5=s[5], v6=s[6], v7=s[7];
      u64* dst = (u64*)(&Bsl[srow*STR64 + sseg*32]);
      dst[0]=v0; dst[1]=v1; dst[2]=v2; dst[3]=v3; dst[4]=v4; dst[5]=v5; dst[6]=v6; dst[7]=v7;
    }
    __syncthreads();
    #pragma unroll
    for (int ks = 0; ks < 2; ++ks) {
      bf16x8 af[2], bfr[8];
      #pragma unroll
      for (int mi=0;mi<2;mi++) af[mi] = ldfrag(&Asl[(w*32 + mi*16 + l16)*STR64 + ks*32 + q*8]);
      #pragma unroll
      for (int nj=0;nj<8;nj++) bfr[nj] = ldfrag(&Bsl[(nj*16 + l16)*STR64 + ks*32 + q*8]);
      #pragma unroll
      for (int mi=0;mi<2;mi++)
        #pragma unroll
        for (int nj=0;nj<8;nj++)
          acc[mi][nj] = __builtin_amdgcn_mfma_f32_16x16x32_bf16(af[mi], bfr[nj], acc[mi][nj], 0,0,0);
    }
    __syncthreads();
  }
  if (n0 < DIN + CONVDIM) {
    // bounce each 64-row half through LDS, then full-line stores (4 thr/row x 32 shorts = 128)
    #pragma unroll
    for (int mi=0;mi<2;mi++){
      if (mi) __syncthreads();
      #pragma unroll
      for (int nj=0;nj<8;nj++){
        const int col = nj*16 + l16;
        #pragma unroll
        for (int r=0;r<4;r++){
          const int er = w*16 + q*4 + r;
          Ep[er*EPSTR + col] = f2bf(acc[mi][nj][r]);
        }
      }
      __syncthreads();
      {
        const int er2 = tid >> 2, seg = tid & 3;
        const long grow = m0 + (er2>>4)*32 + mi*16 + (er2&15);
        const u64* s = (const u64*)(Ep + er2*EPSTR + seg*32);
        u64 v0=s[0], v1=s[1], v2=s[2], v3=s[3], v4=s[4], v5=s[5], v6=s[6], v7=s[7];
        u64* dptr;
        if (n0 < DIN) dptr = (u64*)(zbuf + grow*DIN + n0 + seg*32);
        else          dptr = (u64*)(xbc + grow*CONVDIM + (n0 - DIN) + seg*32);
        dptr[0]=v0; dptr[1]=v1; dptr[2]=v2; dptr[3]=v3;
        dptr[4]=v4; dptr[5]=v5; dptr[6]=v6; dptr[7]=v7;
      }
    }
  } else {
    // dt tile: only cols 1152..1159 valid
    #pragma unroll
    for (int mi=0;mi<2;mi++){
      #pragma unroll
      for (int nj=0;nj<8;nj++){
        const int col = n0 + nj*16 + l16;
        if (col < DPROJ) {
          const int hh = col - (DIN + CONVDIM);
          #pragma unroll
          for (int r=0;r<4;r++){
            const long row = m0 + w*32 + mi*16 + q*4 + r;
            const float dv = acc[mi][nj][r] + dt_bias[hh];
            const float sp = dv > 20.f ? dv : log1pf(expf(dv));
            dtb[row*NH + hh] = sp;
            lab[row*NH + hh] = sp * (-expf(A_log[hh]));   // log dA
          }
        }
      }
    }
  }
}

// ---------------- out_proj fused: gnorm (y*silu(z), RMS) + GEMM + residual + LayerNorm ----------------
// RMS scale commutes through GEMM: out = scale_row * ((g*nw) @ W). 512 threads; A staged by all 512.
__global__ __launch_bounds__(512) void outproj_fused(const u16* __restrict__ yb,
    const u16* __restrict__ zb, const u16* __restrict__ Wt, u16* __restrict__ hb,
    const float* __restrict__ nw, const float* __restrict__ lnw, const float* __restrict__ lnb)
{
  __shared__ __align__(16) u16 Asl[128*36];
  __shared__ __align__(16) u16 Bsl[256*36];
  __shared__ float red[128][2][2];     // [row][colgroup][sum, sumsq] for LN
  __shared__ float red2[128][4];       // [row][seg] partial sum g^2 for RMS
  __shared__ float nwl[512];
  const int tid = threadIdx.x;
  const long m0 = (long)blockIdx.x * 128;
  const int w = tid >> 6, lane = tid & 63;
  const int q = lane >> 4, l16 = lane & 15;
  const int wr = (w >> 1) * 32;        // wave row base (0/32/64/96)
  const int wc = (w & 1) * 128;        // wave col base (0/128)
  const int arow = tid >> 2, aseg = tid & 3;   // A staging: 128 rows x 4 segs x 8 shorts
  const int brow = tid >> 1, bseg = tid & 1;   // B staging: 256 rows x 2 segs x 16 shorts
  if (tid < 512) nwl[tid] = nw[tid];
  __syncthreads();
  float sq = 0.f;
  f32x4 acc[2][8] = {{{0.f,0.f,0.f,0.f}}};
  for (int kk = 0; kk < 16; ++kk) {
    const int k0 = kk*32;
    {   // A staging (all 512): g = y*silu(z); stage g*nw bf16; accumulate g^2
      const u64* yp = (const u64*)(yb + (m0 + arow)*DIN + k0 + aseg*8);
      const u64* zp = (const u64*)(zb + (m0 + arow)*DIN + k0 + aseg*8);
      const u64 ys[2] = {yp[0], yp[1]};
      const u64 zs[2] = {zp[0], zp[1]};
      u16 gv[8];
      #pragma unroll
      for (int u=0;u<2;u++){
        #pragma unroll
        for (int j=0;j<4;j++){
          const float yv = bf2f((u16)(ys[u] >> (16*j)));
          const float zv = bf2f((u16)(zs[u] >> (16*j)));
          const float g = yv * siluf(zv);
          sq += g*g;
          gv[u*4+j] = f2bf(g * nwl[k0 + aseg*8 + u*4 + j]);
        }
      }
      const u64* gp = (const u64*)gv;
      u64* dst = (u64*)(&Asl[arow*36 + aseg*8]);
      dst[0]=gp[0]; dst[1]=gp[1];
    }
    {
      const u64* s = (const u64*)(Wt + (long)brow*DIN + k0 + bseg*16);
      u64 a=s[0], b=s[1], c=s[2], d=s[3];
      u64* dst = (u64*)(&Bsl[brow*36 + bseg*16]);
      dst[0]=a; dst[1]=b; dst[2]=c; dst[3]=d;
    }
    __syncthreads();
    bf16x8 af[2], bfr[8];
    #pragma unroll
    for (int mi=0;mi<2;mi++) af[mi] = ldfrag(&Asl[(wr + mi*16 + l16)*36 + q*8]);
    #pragma unroll
    for (int nj=0;nj<8;nj++) bfr[nj] = ldfrag(&Bsl[(wc + nj*16 + l16)*36 + q*8]);
    #pragma unroll
    for (int mi=0;mi<2;mi++)
      #pragma unroll
      for (int nj=0;nj<8;nj++)
        acc[mi][nj] = __builtin_amdgcn_mfma_f32_16x16x32_bf16(af[mi], bfr[nj], acc[mi][nj], 0,0,0);
    __syncthreads();
  }
  red2[arow][aseg] = sq;
  __syncthreads();
  // o = acc*rms_scale + resid(bf16) ; per-row LN stats via 16-lane shuffle + LDS combine
  #pragma unroll
  for (int mi=0;mi<2;mi++){
    #pragma unroll
    for (int r=0;r<4;r++){
      const int lrow = wr + mi*16 + q*4 + r;
      const float S2 = red2[lrow][0] + red2[lrow][1] + red2[lrow][2] + red2[lrow][3];
      const float rscale = rsqrtf(S2*(1.f/512.f) + 1e-5f);
      float s = 0.f, ss = 0.f;
      #pragma unroll
      for (int nj=0;nj<8;nj++){
        const int col = wc + nj*16 + l16;
        const float o = acc[mi][nj][r]*rscale + bf2f(hb[(m0+lrow)*DMODEL + col]);
        acc[mi][nj][r] = o;
        s += o; ss += o*o;
      }
      #pragma unroll
      for (int o2=1;o2<16;o2<<=1){ s += __shfl_xor(s,o2); ss += __shfl_xor(ss,o2); }
      if (l16 == 0) { red[lrow][w&1][0] = s; red[lrow][w&1][1] = ss; }
    }
  }
  __syncthreads();
  #pragma unroll
  for (int mi=0;mi<2;mi++){
    #pragma unroll
    for (int r=0;r<4;r++){
      const int lrow = wr + mi*16 + q*4 + r;
      const float S  = red[lrow][0][0] + red[lrow][1][0];
      const float SS = red[lrow][0][1] + red[lrow][1][1];
      const float mu = S * (1.f/256.f);
      const float var = SS * (1.f/256.f) - mu*mu;
      const float rs = rsqrtf(var + 1e-5f);
      #pragma unroll
      for (int nj=0;nj<8;nj++){
        const int col = wc + nj*16 + l16;
        const float v = (acc[mi][nj][r] - mu)*rs*lnw[col] + lnb[col];
        hb[(m0+lrow)*DMODEL + col] = f2bf(v);
      }
    }
  }
}

// ---------------- depthwise causal conv + SiLU: strip kernel ----------------
__global__ __launch_bounds__(256) void conv_kernel(const u16* __restrict__ xbc,
    const float* __restrict__ cw, const float* __restrict__ cb,
    u16* __restrict__ xsx, u16* __restrict__ Bb, u16* __restrict__ Cb)
{
  const long idx = (long)blockIdx.x * 256 + threadIdx.x;   // Mb*20 threads
  const int c4 = (int)(idx % 160) * 4;
  const long bt0 = (idx / 160) * 8;          // strip start (strips never cross batch)
  const int tseq = (int)(bt0 & (SEQ-1));
  const float4 b4 = *(const float4*)(cb + c4);
  const float4 w0v = *(const float4*)(cw + (c4+0)*4);
  const float4 w1v = *(const float4*)(cw + (c4+1)*4);
  const float4 w2v = *(const float4*)(cw + (c4+2)*4);
  const float4 w3v = *(const float4*)(cw + (c4+3)*4);
  const float W0[4] = {w0v.x,w0v.y,w0v.z,w0v.w};
  const float W1[4] = {w1v.x,w1v.y,w1v.z,w1v.w};
  const float W2[4] = {w2v.x,w2v.y,w2v.z,w2v.w};
  const float W3[4] = {w3v.x,w3v.y,w3v.z,w3v.w};
  float i0[11], i1[11], i2[11], i3[11];
  #pragma unroll
  for (int k = 0; k < 11; ++k) {
    u64 v = 0;
    if (tseq - 3 + k >= 0) v = *(const u64*)(xbc + (bt0 - 3 + k)*CONVDIM + c4);
    i0[k]=bf2f((u16)v); i1[k]=bf2f((u16)(v>>16)); i2[k]=bf2f((u16)(v>>32)); i3[k]=bf2f((u16)(v>>48));
  }
  u16* dst; long base; int stride;
  if (c4 < DIN)              { dst = xsx; base = bt0*DIN + c4;              stride = DIN; }
  else if (c4 < DIN+DSTATE)  { dst = Bb;  base = bt0*DSTATE + (c4-DIN);     stride = DSTATE; }
  else                       { dst = Cb;  base = bt0*DSTATE + (c4-DIN-DSTATE); stride = DSTATE; }
  #pragma unroll
  for (int j = 0; j < 8; ++j) {
    float a0=b4.x, a1=b4.y, a2=b4.z, a3=b4.w;
    #pragma unroll
    for (int k = 0; k < 4; ++k) {
      a0 += W0[k]*i0[j+k]; a1 += W1[k]*i1[j+k];
      a2 += W2[k]*i2[j+k]; a3 += W3[k]*i3[j+k];
    }
    a0=siluf(a0); a1=siluf(a1); a2=siluf(a2); a3=siluf(a3);
    const u64 r = (u64)f2bf(a0) | ((u64)f2bf(a1)<<16) | ((u64)f2bf(a2)<<32) | ((u64)f2bf(a3)<<48);
    *(u64*)(dst + base + (long)j*stride) = r;
  }
}

// ---------------- SSD phase A: per chunk-head local state via MFMA; Sloc bf16 ----------------
__global__ __launch_bounds__(256) void scanS_kernel(const u16* __restrict__ xsx,
    const u16* __restrict__ Bb, const float* __restrict__ lab, const float* __restrict__ dtb,
    u16* __restrict__ Sloc, float* __restrict__ Pb)
{
  __shared__ __align__(16) u16 Btr[64*STR128];   // [n][s]
  __shared__ __align__(16) u16 Uw[64*STR128];    // [p][s]
  __shared__ float cexpL[128];
  const int wg = blockIdx.x;
  const int c = wg & (NCHUNK-1), bh = wg >> 5, hh = bh & (NH-1), b = bh >> 3;
  const int tid = threadIdx.x;
  const long bt0 = (long)b*SEQ + c*CLEN;
  if (tid < 64) {   // wave 0: inclusive prefix of log dA over 128 steps
    float a0 = lab[(bt0+tid)*NH + hh];
    float a1 = lab[(bt0+64+tid)*NH + hh];
    const float d0 = dtb[(bt0+tid)*NH + hh];
    const float d1 = dtb[(bt0+64+tid)*NH + hh];
    #pragma unroll
    for (int o=1;o<64;o<<=1){
      const float t0=__shfl_up(a0,o), t1=__shfl_up(a1,o);
      if (tid>=o){a0+=t0;a1+=t1;}
    }
    a1 += __shfl(a0,63);
    const float ctot = __shfl(a1,63);
    cexpL[tid]    = d0*__expf(ctot - a0);
    cexpL[tid+64] = d1*__expf(ctot - a1);
    if (tid==0) Pb[wg] = __expf(ctot);
  }
  __syncthreads();
  {
    const int v = tid & 63, r0 = tid >> 6;
    #pragma unroll 4
    for (int k=0;k<32;k++){
      const int s = r0 + k*4;
      Btr[v*STR128 + s] = Bb[(bt0+s)*DSTATE + v];
      Uw[v*STR128 + s]  = f2bf(cexpL[s]*bf2f(xsx[(bt0+s)*DIN + hh*HD + v]));
    }
  }
  __syncthreads();
  const int w = tid>>6, lane = tid&63, q = lane>>4, l16 = lane&15;
  f32x4 acc[4] = {};
  #pragma unroll
  for (int ks=0;ks<4;ks++){
    const bf16x8 af = ldfrag(&Uw[(w*16+l16)*STR128 + ks*32 + q*8]);
    #pragma unroll
    for (int nj=0;nj<4;nj++){
      const bf16x8 bf = ldfrag(&Btr[(nj*16+l16)*STR128 + ks*32 + q*8]);
      acc[nj] = __builtin_amdgcn_mfma_f32_16x16x32_bf16(af, bf, acc[nj], 0,0,0);
    }
  }
  const long sb = (long)wg*4096;   // [wg][p][n] bf16
  #pragma unroll
  for (int nj=0;nj<4;nj++)
    #pragma unroll
    for (int r=0;r<4;r++)
      Sloc[sb + (w*16+q*4+r)*64 + nj*16 + l16] = f2bf(acc[nj][r]);
}

// Parallel combine over bf16 Sloc: run stays fp32 in registers
__global__ __launch_bounds__(64) void scanMid_kernel(u16* __restrict__ Sloc, const float* __restrict__ Pb)
{
  const int bh = blockIdx.x;
  const int rr = blockIdx.y;
  const int p  = threadIdx.x;
  float run = 0.f;
  for (int c = 0; c < NCHUNK; ++c) {
    const long base = ((long)(bh*NCHUNK + c))*4096 + rr*64 + p;
    const float Pc = Pb[bh*NCHUNK + c];
    const float tmp = bf2f(Sloc[base]);
    Sloc[base] = f2bf(run);
    run = run*Pc + tmp;
  }
}

// ---------------- SSD phase C: Y = ((C Bt) o L) U + diag(exp(cum)) (C h0) + D*x ; coalesced y out ----------------
// Epilogue recovers x = Ut/dt from LDS (Ut = bf16(dt*x), dt = softplus > 0) -> no 2nd global xsx read.
__global__ __launch_bounds__(512) void scanY_kernel(const u16* __restrict__ xsx,
    u16* __restrict__ yg, const u16* __restrict__ Bb, const u16* __restrict__ Cb,
    const float* __restrict__ lab, const float* __restrict__ dtb,
    const u16* __restrict__ Sinit, const float* __restrict__ Dp)
{
  __shared__ __align__(16) u16 pool[2*128*STR64];  // Bs | Cs; overlaid by Ms[t][s]; then by y-bounce
  __shared__ __align__(16) u16 Ut[64*STR128];      // [p][s]
  __shared__ __align__(16) u16 h0t[64*STR64];      // [p][n]
  __shared__ float cumL[128];
  __shared__ float dtL[128];
  u16* Bs = pool;
  u16* Cs = pool + 128*STR64;
  u16* Ms = pool;

  const int wg = blockIdx.x;
  const int c = wg & (NCHUNK-1), bh = wg >> 5, hh = bh & (NH-1), b = bh >> 3;
  const int tid = threadIdx.x;
  const long bt0 = (long)b*SEQ + c*CLEN;

  if (tid < 64) {
    float a0 = lab[(bt0+tid)*NH + hh];
    float a1 = lab[(bt0+64+tid)*NH + hh];
    dtL[tid]    = dtb[(bt0+tid)*NH + hh];
    dtL[tid+64] = dtb[(bt0+64+tid)*NH + hh];
    #pragma unroll
    for (int o=1;o<64;o<<=1){
      const float t0=__shfl_up(a0,o), t1=__shfl_up(a1,o);
      if (tid>=o){a0+=t0;a1+=t1;}
    }
    a1 += __shfl(a0,63);
    cumL[tid]=a0; cumL[tid+64]=a1;
  }
  __syncthreads();
  {
    const int n = tid & 63, r0 = tid >> 6;   // 512 threads: r0 in 0..7
    #pragma unroll 4
    for (int k=0;k<16;k++){
      const int s = r0 + k*8;
      Bs[s*STR64 + n] = Bb[(bt0+s)*DSTATE + n];
      Cs[s*STR64 + n] = Cb[(bt0+s)*DSTATE + n];
      Ut[n*STR128 + s] = f2bf(dtL[s]*bf2f(xsx[(bt0+s)*DIN + hh*HD + n]));
    }
    const int n0 = r0*8;
    // h0 bf16: 8 states = 16 B = two u64 copies
    const u64* sp = (const u64*)(Sinit + (long)wg*4096 + n*64 + n0);
    u64* dp = (u64*)(h0t + n*STR64 + n0);
    dp[0] = sp[0]; dp[1] = sp[1];
  }
  __syncthreads();

  const int w = tid>>6, lane = tid&63, q = lane>>4, l16 = lane&15;
  f32x4 accG[8] = {};
  f32x4 accI[4] = {};
  #pragma unroll
  for (int ks=0;ks<2;ks++){
    const bf16x8 af = ldfrag(&Cs[(w*16+l16)*STR64 + ks*32 + q*8]);
    #pragma unroll
    for (int nj=0;nj<8;nj++)
      accG[nj] = __builtin_amdgcn_mfma_f32_16x16x32_bf16(af, ldfrag(&Bs[(nj*16+l16)*STR64 + ks*32 + q*8]), accG[nj], 0,0,0);
    #pragma unroll
    for (int nj=0;nj<4;nj++)
      accI[nj] = __builtin_amdgcn_mfma_f32_16x16x32_bf16(af, ldfrag(&h0t[(nj*16+l16)*STR64 + ks*32 + q*8]), accI[nj], 0,0,0);
  }
  __syncthreads();
  #pragma unroll
  for (int nj=0;nj<8;nj++){
    const int s = nj*16 + l16;
    #pragma unroll
    for (int r=0;r<4;r++){
      const int t = w*16 + q*4 + r;
      const float v = (s<=t) ? accG[nj][r]*__expf(cumL[t]-cumL[s]) : 0.f;
      Ms[t*STR128 + s] = f2bf(v);
    }
  }
  __syncthreads();
  f32x4 accY[4] = {};
  #pragma unroll
  for (int ks=0;ks<4;ks++){
    const bf16x8 af = ldfrag(&Ms[(w*16+l16)*STR128 + ks*32 + q*8]);
    #pragma unroll
    for (int nj=0;nj<4;nj++)
      accY[nj] = __builtin_amdgcn_mfma_f32_16x16x32_bf16(af, ldfrag(&Ut[(nj*16+l16)*STR128 + ks*32 + q*8]), accY[nj], 0,0,0);
  }
  const float Dv = Dp[hh];
  float rdt[4], ec[4];
  #pragma unroll
  for (int r=0;r<4;r++){
    const int t = w*16 + q*4 + r;
    rdt[r] = 1.f / dtL[t];           // dt = softplus(..) > 0
    ec[r]  = __expf(cumL[t]);
  }
  __syncthreads();   // Ms reads done; reuse pool as y-bounce [128][STR64]
  #pragma unroll
  for (int nj=0;nj<4;nj++){
    const int p = nj*16 + l16;
    #pragma unroll
    for (int r=0;r<4;r++){
      const int t = w*16 + q*4 + r;
      const float xv = bf2f(Ut[p*STR128 + t]) * rdt[r];   // x = (dt*x)/dt
      pool[t*STR64 + p] = f2bf(accY[nj][r] + ec[r]*accI[nj][r] + Dv*xv);
    }
  }
  __syncthreads();
  {
    const int row = tid >> 2, seg = tid & 3;
    const u64* s = (const u64*)(pool + row*STR64 + seg*16);
    u64 a=s[0], b2=s[1], c2=s[2], d=s[3];
    u64* dptr = (u64*)(yg + (bt0+row)*DIN + hh*HD + seg*16);
    dptr[0]=a; dptr[1]=b2; dptr[2]=c2; dptr[3]=d;
  }
}

// ---------------- decoder: hb bf16 in, fp32 out ----------------
__global__ __launch_bounds__(64) void dec_kernel(const u16* __restrict__ hb,
    const float* __restrict__ W, const float* __restrict__ bias, float* __restrict__ out)
{
  const int wg = blockIdx.x;
  const int b = wg / 10, o = wg % 10;
  const int lane = threadIdx.x;
  const u16* r = hb + ((long)b*SEQ + SEQ-1)*DMODEL;
  float s = 0.f;
  #pragma unroll
  for (int q=0;q<4;q++){ const int k = lane + q*64; s += bf2f(r[k])*W[k*10+o]; }
  #pragma unroll
  for (int o2=32;o2;o2>>=1) s += __shfl_down(s, o2);
  if (lane == 0) out[wg] = s + bias[o];
}

extern "C" void kernel_launch(void* const* d_in, const int* in_sizes, int n_in,
                              void* d_out, int out_size, void* d_ws, size_t ws_size,
                              hipStream_t stream) {
  const float* x        = (const float*)d_in[0];
  const float* enc_w    = (const float*)d_in[1];
  const float* enc_b    = (const float*)d_in[2];
  const float* in_proj  = (const float*)d_in[3];
  const float* conv_w   = (const float*)d_in[4];
  const float* conv_b   = (const float*)d_in[5];
  const float* dt_bias  = (const float*)d_in[6];
  const float* A_log    = (const float*)d_in[7];
  const float* Dp       = (const float*)d_in[8];
  const float* norm_w   = (const float*)d_in[9];
  const float* out_proj = (const float*)d_in[10];
  const float* ln_w     = (const float*)d_in[11];
  const float* ln_b     = (const float*)d_in[12];
  const float* dec_w    = (const float*)d_in[13];
  const float* dec_b    = (const float*)d_in[14];
  float* out = (float*)d_out;

  float* ws = (float*)d_ws;
  u16* WtIn  = (u16*)ws;                       // 2*NPAD*256 shorts = 655360
  u16* WtOut = WtIn + (long)2*NPAD*DMODEL;     // 2*256*512 shorts = 262144
  float* gbase = ws + 327680 + 131072;         // = ws + 458752 floats

  // Per-token fp32-equivalents: hb 128 + z 256 + xbc 320 + xsx 256 + yg 256
  //                             + Bb 32 + Cb 32 + dtb 8 + lab 8 = 1296
  int NB = 8;
  while (NB > 1) {
    const long Mb = (long)NB * SEQ;
    const long bytes = (458752L + Mb * 1296L + 4096) * 4;
    if ((size_t)bytes <= ws_size) break;
    NB >>= 1;
  }
  const long Mb = (long)NB * SEQ;

  u16*   hb   = (u16*)gbase;              // Mb*256 u16 (residual stream, bf16 only)
  u16*   zbuf = hb + Mb*DMODEL;           // Mb*512 u16
  u16*   xbc  = zbuf + Mb*DIN;            // Mb*640 u16 ; aliased by Sloc (Mb*256 u16)
  u16*   xsx  = xbc + Mb*CONVDIM;         // Mb*512 u16
  u16*   yg   = xsx + Mb*DIN;             // Mb*512 u16 (y)
  u16*   Bb   = yg + Mb*DIN;              // Mb*64 u16
  u16*   Cb   = Bb + Mb*DSTATE;           // Mb*64 u16
  float* dtb  = (float*)(Cb + Mb*DSTATE); // Mb*8 f
  float* lab  = dtb + Mb*NH;              // Mb*8 f (log dA)
  float* Pb   = lab + Mb*NH;              // <= 2048
  u16*   Sloc = xbc;                      // alias: xbc dead after conv; Mb*256 u16

  cvt_inw <<<dim3(2*NPAD),   dim3(256), 0, stream>>>(in_proj,  WtIn);
  cvt_outw<<<dim3(2*DMODEL), dim3(256), 0, stream>>>(out_proj, WtOut);

  const int ngroups = B_SZ / NB;
  for (int g = 0; g < ngroups; ++g) {
    const float* xg = x + (long)g*NB*SEQ*64;

    enc_kernel<<<dim3((int)(Mb/32)), dim3(256), 0, stream>>>(xg, enc_w, enc_b, hb);

    for (int l = 0; l < 2; ++l) {
      inproj_mfma<<<dim3((int)(Mb/128), NPAD/128), dim3(256), 0, stream>>>(
          hb, WtIn + (long)l*NPAD*DMODEL, zbuf, xbc, dtb, lab,
          dt_bias + l*NH, A_log + l*NH);
      conv_kernel<<<dim3((int)(Mb*20/256)), dim3(256), 0, stream>>>(
          xbc, conv_w + (long)l*CONVDIM*4, conv_b + (long)l*CONVDIM, xsx, Bb, Cb);
      scanS_kernel<<<dim3(NB*8*NCHUNK), dim3(256), 0, stream>>>(xsx, Bb, lab, dtb, Sloc, Pb);
      scanMid_kernel<<<dim3(NB*8, 64), dim3(64), 0, stream>>>(Sloc, Pb);
      scanY_kernel<<<dim3(NB*8*NCHUNK), dim3(512), 0, stream>>>(xsx, yg, Bb, Cb, lab, dtb, Sloc, Dp + l*NH);
      outproj_fused<<<dim3((int)(Mb/128)), dim3(512), 0, stream>>>(
          yg, zbuf, WtOut + (long)l*DMODEL*DIN, hb,
          norm_w + (long)l*DIN, ln_w + l*DMODEL, ln_b + l*DMODEL);
    }

    dec_kernel<<<dim3(NB*10), dim3(64), 0, stream>>>(hb, dec_w, dec_b, out + (long)g*NB*10);
  }
}